// Round 4
// baseline (1096.495 us; speedup 1.0000x reference)
//
#include <hip/hip_runtime.h>
#include <hip/hip_bf16.h>

// WaveOperator: Fourier-domain 3-term recurrence + per-row inverse FFT sampling.
// A_{t+1}(p,q) = (2-4*fil(p,q)) * A_t - A_{t-1};  y[b,j,t] = Re(ifft2(A_{t+1})[u_j,v_j])
// R20: dual-FFT interleave for ILP. R19's barrier/publish cut was neutral (dur 917->906,
// VALUBusy stuck at 64%): the limiter is the serial dependency chain of a single wave's FFT
// (DPP->cndmask->DFT stages), not barrier count. fft(A_{t+1}) and fft(A_{t+2}) are mutually
// independent (the recurrence needs only the state, not the FFT), so each loop body now runs
// BOTH recurrences, then both FFTs interleaved stage-by-stage -> 2 independent chains per wave.
// Publish/gather keeps the 2-parity-buffer scheme, 1 barrier per step. Epoch race audit:
//   E0: pubA(t)@buf0                       | bar k
//   E1: pubB(t+1)@buf1, gathA(t)@buf0      | bar k+1
//   E2: gathB(t+1)@buf1, [next iter] recs+FFTs, pubA(t+2)@buf0   | bar k(i+1)
// every buffer's write and read are in barrier-separated epochs; writes to one buf never share
// an epoch with reads of the same buf.
// launch_bounds(384,3): VGPR budget ~168 for the doubled FFT state (GA+GB), 2 blocks/CU.

#define NOUT 512
#define NB 16
#define NPHI 256
#define NT 240
#define RPB 6             // rows per block (= waves per block)
#define NGRP 43           // row groups: 43*6 = 258 = rows 0..257 (257 gets zero phase)

#define WREG 5184         // per-wave LDS publish region (pitch 80; lane uses 2x32B parity bufs)

typedef float v2f __attribute__((ext_vector_type(2)));
typedef float v4f __attribute__((ext_vector_type(4)));
typedef unsigned int v2u __attribute__((ext_vector_type(2)));

__device__ __forceinline__ v2f cmulv(v2f a, v2f b) {
    return v2f{fmaf(a.x, b.x, -a.y * b.y), fmaf(a.x, b.y, a.y * b.x)};
}
__device__ __forceinline__ v2f cmuliv(v2f a) { return v2f{-a.y, a.x}; }
__device__ __forceinline__ v2f cmulw8v(v2f a) {
    const float s = 0.70710678118654752f; return v2f{s * (a.x - a.y), s * (a.x + a.y)};
}
__device__ __forceinline__ v2f cmulw83v(v2f a) {
    const float s = 0.70710678118654752f; return v2f{-s * (a.x + a.y), s * (a.x - a.y)};
}

// 8-pt DFT, positive exponent: Y[k] = sum_r y[r] * exp(+2pi i rk/8)
__device__ __forceinline__ void dft8p(const v2f y[8], v2f Y[8]) {
    v2f t0 = y[0] + y[4], t4 = y[0] - y[4];
    v2f t1 = y[1] + y[5], t5 = cmulw8v(y[1] - y[5]);
    v2f t2 = y[2] + y[6], t6 = cmuliv(y[2] - y[6]);
    v2f t3 = y[3] + y[7], t7 = cmulw83v(y[3] - y[7]);
    v2f u0 = t0 + t2, u2 = t0 - t2;
    v2f u1 = t1 + t3, u3 = cmuliv(t1 - t3);
    Y[0] = u0 + u1; Y[4] = u0 - u1;
    Y[2] = u2 + u3; Y[6] = u2 - u3;
    v2f v0 = t4 + t6, v2 = t4 - t6;
    v2f v1 = t5 + t7, v3 = cmuliv(t5 - t7);
    Y[1] = v0 + v1; Y[5] = v0 - v1;
    Y[3] = v2 + v3; Y[7] = v2 - v3;
}

// in-place variant (t-layer fully buffers the inputs before any write)
__device__ __forceinline__ void dft8p_ip(v2f y[8]) {
    v2f t0 = y[0] + y[4], t4 = y[0] - y[4];
    v2f t1 = y[1] + y[5], t5 = cmulw8v(y[1] - y[5]);
    v2f t2 = y[2] + y[6], t6 = cmuliv(y[2] - y[6]);
    v2f t3 = y[3] + y[7], t7 = cmulw83v(y[3] - y[7]);
    v2f u0 = t0 + t2, u2 = t0 - t2;
    v2f u1 = t1 + t3, u3 = cmuliv(t1 - t3);
    y[0] = u0 + u1; y[4] = u0 - u1;
    y[2] = u2 + u3; y[6] = u2 - u3;
    v2f v0 = t4 + t6, v2 = t4 - t6;
    v2f v1 = t5 + t7, v3 = cmuliv(t5 - t7);
    y[1] = v0 + v1; y[5] = v0 - v1;
    y[3] = v2 + v3; y[7] = v2 - v3;
}

// final-layer DFT producing only outputs Y2,Y3,Y4,Y5 (the sensor v>>6 range)
__device__ __forceinline__ void dft8p_mid4(const v2f y[8], v2f o[4]) {
    v2f t0 = y[0] + y[4], t4 = y[0] - y[4];
    v2f t1 = y[1] + y[5], t5 = cmulw8v(y[1] - y[5]);
    v2f t2 = y[2] + y[6], t6 = cmuliv(y[2] - y[6]);
    v2f t3 = y[3] + y[7], t7 = cmulw83v(y[3] - y[7]);
    v2f u0 = t0 + t2, u2 = t0 - t2;
    v2f u1 = t1 + t3, u3 = cmuliv(t1 - t3);
    v2f w0 = t4 + t6, w2 = t4 - t6;
    v2f w1 = t5 + t7, w3 = cmuliv(t5 - t7);
    o[0] = u2 + u3;    // Y2
    o[1] = w2 + w3;    // Y3
    o[2] = u0 - u1;    // Y4
    o[3] = w0 - w1;    // Y5
}

// W512^m from half-table
__device__ __forceinline__ v2f wlookup(const float2* trig, int m) {
    m &= 511;
    float2 ph = trig[m & 255];
    return (m & 256) ? v2f{-ph.x, -ph.y} : v2f{ph.x, ph.y};
}

// ---- in-register lane exchanges (transpose building blocks) -------------------------------------
template<int CTRL>
__device__ __forceinline__ float dppx(float x) {
    return __int_as_float(__builtin_amdgcn_mov_dpp(__float_as_int(x), CTRL, 0xF, 0xF, true));
}
__device__ __forceinline__ float swzx4(float x) {
    // BitMode swizzle: and=0x1F, or=0, xor=4  -> lane ^ 4
    return __int_as_float(__builtin_amdgcn_ds_swizzle(__float_as_int(x), 0x101F));
}

template<int CTRL>
__device__ __forceinline__ void xchg_dpp(v2f& a, v2f& b, bool bit) {
    float sx = bit ? a.x : b.x;
    float sy = bit ? a.y : b.y;
    float tx = dppx<CTRL>(sx);
    float ty = dppx<CTRL>(sy);
    a.x = bit ? tx : a.x;   a.y = bit ? ty : a.y;
    b.x = bit ? b.x : tx;   b.y = bit ? b.y : ty;
}
__device__ __forceinline__ void xchg_swz4(v2f& a, v2f& b, bool bit) {
    float sx = bit ? a.x : b.x;
    float sy = bit ? a.y : b.y;
    float tx = swzx4(sx);
    float ty = swzx4(sy);
    a.x = bit ? tx : a.x;   a.y = bit ? ty : a.y;
    b.x = bit ? b.x : tx;   b.y = bit ? b.y : ty;
}

#if __has_builtin(__builtin_amdgcn_permlane16_swap)
__device__ __forceinline__ void pl16x(v2f& a, v2f& b) {
    v2u rx = __builtin_amdgcn_permlane16_swap(__float_as_uint(a.x), __float_as_uint(b.x), false, false);
    a.x = __uint_as_float(rx.x); b.x = __uint_as_float(rx.y);
    v2u ry = __builtin_amdgcn_permlane16_swap(__float_as_uint(a.y), __float_as_uint(b.y), false, false);
    a.y = __uint_as_float(ry.x); b.y = __uint_as_float(ry.y);
}
#else
__device__ __forceinline__ void pl16x(v2f& a, v2f& b) {
    bool bit = (threadIdx.x & 16) != 0;
    float sx = bit ? a.x : b.x, sy = bit ? a.y : b.y;
    float tx = __shfl_xor(sx, 16), ty = __shfl_xor(sy, 16);
    a.x = bit ? tx : a.x; a.y = bit ? ty : a.y;
    b.x = bit ? b.x : tx; b.y = bit ? b.y : ty;
}
#endif

#if __has_builtin(__builtin_amdgcn_permlane32_swap)
__device__ __forceinline__ void pl32x(v2f& a, v2f& b) {
    v2u rx = __builtin_amdgcn_permlane32_swap(__float_as_uint(a.x), __float_as_uint(b.x), false, false);
    a.x = __uint_as_float(rx.x); b.x = __uint_as_float(rx.y);
    v2u ry = __builtin_amdgcn_permlane32_swap(__float_as_uint(a.y), __float_as_uint(b.y), false, false);
    a.y = __uint_as_float(ry.x); b.y = __uint_as_float(ry.y);
}
#else
__device__ __forceinline__ void pl32x(v2f& a, v2f& b) {
    bool bit = (threadIdx.x & 32) != 0;
    float sx = bit ? a.x : b.x, sy = bit ? a.y : b.y;
    float tx = __shfl_xor(sx, 32), ty = __shfl_xor(sy, 32);
    a.x = bit ? tx : a.x; a.y = bit ? ty : a.y;
    b.x = bit ? b.x : tx; b.y = bit ? b.y : ty;
}
#endif

// TWO independent 512-pt inverse DFTs, interleaved stage-by-stage so the scheduler can
// co-issue the two dependency chains. No LDS publish/barrier in here.
__device__ __forceinline__ void fft_compute2(
    const v2f yA[8], const v2f yB[8], const v2f tA[8], const v2f tB[8],
    bool b0, bool b1, bool b2, bool b3, v2f oA[4], v2f oB[4])
{
    v2f GA[8], GB[8];
    dft8p(yA, GA);
    dft8p(yB, GB);
#pragma unroll
    for (int k1 = 1; k1 < 8; ++k1) { GA[k1] = cmulv(GA[k1], tA[k1]); GB[k1] = cmulv(GB[k1], tA[k1]); }
    // T1: reg digit (v0) <-> lane-high digit (q1)
    xchg_dpp<0x128>(GA[0], GA[1], b3);  xchg_dpp<0x128>(GB[0], GB[1], b3);   // row_ror:8 == xor8
    xchg_dpp<0x128>(GA[2], GA[3], b3);  xchg_dpp<0x128>(GB[2], GB[3], b3);
    xchg_dpp<0x128>(GA[4], GA[5], b3);  xchg_dpp<0x128>(GB[4], GB[5], b3);
    xchg_dpp<0x128>(GA[6], GA[7], b3);  xchg_dpp<0x128>(GB[6], GB[7], b3);
    pl16x(GA[0], GA[2]);  pl16x(GB[0], GB[2]);                               // xor16
    pl16x(GA[1], GA[3]);  pl16x(GB[1], GB[3]);
    pl16x(GA[4], GA[6]);  pl16x(GB[4], GB[6]);
    pl16x(GA[5], GA[7]);  pl16x(GB[5], GB[7]);
    pl32x(GA[0], GA[4]);  pl32x(GB[0], GB[4]);                               // xor32
    pl32x(GA[1], GA[5]);  pl32x(GB[1], GB[5]);
    pl32x(GA[2], GA[6]);  pl32x(GB[2], GB[6]);
    pl32x(GA[3], GA[7]);  pl32x(GB[3], GB[7]);
    dft8p_ip(GA);
    dft8p_ip(GB);
#pragma unroll
    for (int m1 = 1; m1 < 8; ++m1) { GA[m1] = cmulv(GA[m1], tB[m1]); GB[m1] = cmulv(GB[m1], tB[m1]); }
    // T2: reg digit (v1) <-> lane-low digit (q0)
    xchg_dpp<0xB1>(GA[0], GA[1], b0);  xchg_dpp<0xB1>(GB[0], GB[1], b0);     // quad_perm xor1
    xchg_dpp<0xB1>(GA[2], GA[3], b0);  xchg_dpp<0xB1>(GB[2], GB[3], b0);
    xchg_dpp<0xB1>(GA[4], GA[5], b0);  xchg_dpp<0xB1>(GB[4], GB[5], b0);
    xchg_dpp<0xB1>(GA[6], GA[7], b0);  xchg_dpp<0xB1>(GB[6], GB[7], b0);
    xchg_dpp<0x4E>(GA[0], GA[2], b1);  xchg_dpp<0x4E>(GB[0], GB[2], b1);     // quad_perm xor2
    xchg_dpp<0x4E>(GA[1], GA[3], b1);  xchg_dpp<0x4E>(GB[1], GB[3], b1);
    xchg_dpp<0x4E>(GA[4], GA[6], b1);  xchg_dpp<0x4E>(GB[4], GB[6], b1);
    xchg_dpp<0x4E>(GA[5], GA[7], b1);  xchg_dpp<0x4E>(GB[5], GB[7], b1);
    xchg_swz4(GA[0], GA[4], b2);  xchg_swz4(GB[0], GB[4], b2);               // ds_swizzle xor4
    xchg_swz4(GA[1], GA[5], b2);  xchg_swz4(GB[1], GB[5], b2);
    xchg_swz4(GA[2], GA[6], b2);  xchg_swz4(GB[2], GB[6], b2);
    xchg_swz4(GA[3], GA[7], b2);  xchg_swz4(GB[3], GB[7], b2);
    dft8p_mid4(GA, oA);
    dft8p_mid4(GB, oB);
}

// ---------------- init kernels (run once, shuffle FFT) -------------------------------------------
__device__ __forceinline__ void cbfly(float& ar, float& ai, float& br, float& bi,
                                      float wr, float wi) {
    float dr = ar - br, di = ai - bi;
    ar = ar + br; ai = ai + bi;
    br = fmaf(dr, wr, -di * wi);
    bi = fmaf(dr, wi,  di * wr);
}

__device__ __forceinline__ void init_trig(float2* trig, int tid) {
    if (tid < 256) {
        float ang = (float)tid * (6.283185307179586f / 512.0f);
        float s, c;
        sincosf(ang, &s, &c);
        trig[tid] = make_float2(c, s);
    }
}

__device__ __forceinline__ void fft512_inv_lds(float* xr, float* xi, const float2* trig, int L) {
#pragma unroll
    for (int r = 0; r < 4; ++r) {
        float2 w = trig[(r << 6) + L];
        cbfly(xr[r], xi[r], xr[r + 4], xi[r + 4], w.x, w.y);
    }
    {
        float2 w0 = trig[L << 1];
        float2 w1 = trig[(64 + L) << 1];
        cbfly(xr[0], xi[0], xr[2], xi[2], w0.x, w0.y);
        cbfly(xr[1], xi[1], xr[3], xi[3], w1.x, w1.y);
        cbfly(xr[4], xi[4], xr[6], xi[6], w0.x, w0.y);
        cbfly(xr[5], xi[5], xr[7], xi[7], w1.x, w1.y);
    }
    {
        float2 w = trig[L << 2];
        cbfly(xr[0], xi[0], xr[1], xi[1], w.x, w.y);
        cbfly(xr[2], xi[2], xr[3], xi[3], w.x, w.y);
        cbfly(xr[4], xi[4], xr[5], xi[5], w.x, w.y);
        cbfly(xr[6], xi[6], xr[7], xi[7], w.x, w.y);
    }
#pragma unroll
    for (int s = 3; s <= 8; ++s) {
        const int half = 512 >> (s + 1);
        const int ex = (L & (half - 1)) << s;
        float2 w = trig[ex];
        const bool hi = (L & half) != 0;
        float wr = hi ? w.x : 1.0f;
        float wi = hi ? w.y : 0.0f;
        float sg = hi ? -1.0f : 1.0f;
#pragma unroll
        for (int r = 0; r < 8; ++r) {
            float orv = __shfl_xor(xr[r], half);
            float oiv = __shfl_xor(xi[r], half);
            float tr = fmaf(sg, xr[r], orv);
            float ti = fmaf(sg, xi[r], oiv);
            xr[r] = fmaf(tr, wr, -ti * wi);
            xi[r] = fmaf(tr, wi,  ti * wr);
        }
    }
}

__global__ __launch_bounds__(256) void f1_kernel(const float* __restrict__ f,
                                                 float2* __restrict__ R) {
    __shared__ float2 trig[256];
    const int tid = threadIdx.x;
    init_trig(trig, tid);
    __syncthreads();
    const int w = tid >> 6, L = tid & 63;
    const int x = 128 + blockIdx.x * 4 + w;   // nonzero rows only: [128, 384)
    const int b = blockIdx.y;
    const float* frow = f + ((size_t)b * 256 + (x - 128)) * 256;
    float xr[8], xi[8];
#pragma unroll
    for (int r = 0; r < 8; ++r) {
        int e = r * 64 + L;
        xr[r] = (e >= 128 && e < 384) ? frow[e - 128] : 0.0f;
        xi[r] = 0.0f;
    }
    fft512_inv_lds(xr, xi, trig, L);
    float2* Rrow = R + ((size_t)b * NOUT + x) * NOUT;
#pragma unroll
    for (int r = 0; r < 8; ++r) {
        int e = r * 64 + L;
        int k = __brev((unsigned)e) >> 23;
        Rrow[k] = make_float2(xr[r], -xi[r]);
    }
}

// f2: rows x outside [128,384) of R were never written (and are not zeroed) — treat as 0.
// e = r*64 + L is in [128,384) exactly for r in [2,6).
__global__ __launch_bounds__(256) void f2_kernel(const float2* __restrict__ R,
                                                 float2* __restrict__ A0) {
    __shared__ float2 trig[256];
    const int tid = threadIdx.x;
    init_trig(trig, tid);
    __syncthreads();
    const int w = tid >> 6, L = tid & 63;
    const int q = blockIdx.x * 4 + w;
    const int b = blockIdx.y;
    float xr[8], xi[8];
#pragma unroll
    for (int r = 0; r < 8; ++r) {
        if (r >= 2 && r < 6) {
            int e = r * 64 + L;
            float2 v = R[((size_t)b * NOUT + e) * NOUT + q];
            xr[r] = v.x;
            xi[r] = -v.y;
        } else {
            xr[r] = 0.0f;
            xi[r] = 0.0f;
        }
    }
    fft512_inv_lds(xr, xi, trig, L);
#pragma unroll
    for (int r = 0; r < 8; ++r) {
        int e = r * 64 + L;
        int p = __brev((unsigned)e) >> 23;
        A0[((size_t)b * NOUT + p) * NOUT + q] = make_float2(xr[r], -xi[r]);
    }
}

// ---------------- time-chunk simulation ----------------------------------------------------------
// block = (row group g of RPB rows, batch b); wave w owns row p = RPB*g + w, p in 0..257.
// Threads 0..255 each own one sensor, summing the block's RPB rows after the step barrier.
__global__ __launch_bounds__(384, 3) void sim_kernel(
    const float* __restrict__ fil,
    const int* __restrict__ idx0, const int* __restrict__ idx1,
    float2* __restrict__ stateCur, float2* __restrict__ statePrev,
    float* __restrict__ partial, int Tc, int firstChunk, int lastChunk)
{
    __shared__ __align__(16) char waveMem[RPB * WREG];   // 31104 B
    __shared__ float2 trig[256];                         //  2048 B -> 33152 B total

    const int tid = threadIdx.x;              // 0..383
    const int w = tid >> 6, L = tid & 63;
    const int g = blockIdx.x, b = blockIdx.y;
    const int p = g * RPB + w;                // 0..257

    if (tid < 256) {
        float ang = (float)tid * (6.283185307179586f / 512.0f);
        float s, c;
        sincosf(ang, &s, &c);
        trig[tid] = make_float2(c, s);
    }
    __syncthreads();

    // --- per-lane constant twiddles ---
    v2f tA[8], tB[8];
#pragma unroll
    for (int k1 = 1; k1 < 8; ++k1) tA[k1] = wlookup(trig, L * k1);
#pragma unroll
    for (int m1 = 1; m1 < 8; ++m1) tB[m1] = wlookup(trig, 8 * (L & 7) * m1);

    // --- transpose predicates (loop-invariant; land in SGPR masks) ---
    const bool b0 = (L & 1) != 0;
    const bool b1 = (L & 2) != 0;
    const bool b2 = (L & 4) != 0;
    const bool b3 = (L & 8) != 0;

    // --- sensor constants: thread tid<256 owns sensor j=tid ---
    const bool active = tid < 256;
    int spos = 0;
    v2f ph[RPB];
    if (active) {
        int u = idx0[tid];
        int v = idx1[tid];
        // published regs are v>>6 in {2..5} at lane-local offsets 0,8,16,24 (parity 0)
        spos = ((v & 7) * 8 + ((v >> 3) & 7)) * 80 + ((v >> 6) * 8 - 16);
        // Hermitian fold phase: p==0 -> 1, p==256 -> (-1)^u, p==257 -> 0, else 2*W512^{pu}
#pragma unroll
        for (int ww = 0; ww < RPB; ++ww) {
            int prow = g * RPB + ww;
            v2f a0;
            if (prow == 0)        a0 = v2f{1.0f, 0.0f};
            else if (prow == 256) a0 = v2f{(u & 1) ? -1.0f : 1.0f, 0.0f};
            else if (prow == 257) a0 = v2f{0.0f, 0.0f};
            else                  a0 = 2.0f * wlookup(trig, prow * u);
            ph[ww] = a0;
        }
    } else {
#pragma unroll
        for (int ww = 0; ww < RPB; ++ww) ph[ww] = v2f{0.0f, 0.0f};
    }

    // --- per-lane LDS publish base; parity buffer offsets 0 / 32 within the pitch-80 slot ---
    char* myA    = waveMem + w * WREG;
    char* awBase = myA + L * 80;

    // --- load state + filter into registers ---
    v2f a[8], bb[8];
    float C[8];
    {
        const size_t rowBase = ((size_t)b * NOUT + p) * NOUT;
        const float* filRow = fil + (size_t)p * NOUT;
#pragma unroll
        for (int r = 0; r < 8; ++r) {
            int e = r * 64 + L;
            float2 a0 = stateCur[rowBase + e];
            a[r] = v2f{a0.x, a0.y};
            if (firstChunk) {
                bb[r] = a[r];
            } else {
                float2 a1 = statePrev[rowBase + e];
                bb[r] = v2f{a1.x, a1.y};
            }
            C[r] = fmaf(-4.0f, filRow[e], 2.0f);
        }
    }

    float* pOut = partial + ((size_t)g * Tc * NB + b) * NPHI + tid;

    for (int tl = 0; tl < Tc; tl += 2) {
        // both recurrences up front (rec B depends only on rec A's state, not its FFT)
#pragma unroll
        for (int r = 0; r < 8; ++r) bb[r] = v2f{C[r], C[r]} * a[r] - bb[r];   // A_{t+1}
#pragma unroll
        for (int r = 0; r < 8; ++r) a[r] = v2f{C[r], C[r]} * bb[r] - a[r];    // A_{t+2}
        v2f oA[4], oB[4];
        fft_compute2(bb, a, tA, tB, b0, b1, b2, b3, oA, oB);
        // publish A -> parity buf 0
        *(v4f*)(awBase +  0) = v4f{oA[0].x, oA[0].y, oA[1].x, oA[1].y};
        *(v4f*)(awBase + 16) = v4f{oA[2].x, oA[2].y, oA[3].x, oA[3].y};
        __syncthreads();   // barrier k: bufA visible; prior epoch's bufB gathers done
        // publish B -> parity buf 1; gather A
        *(v4f*)(awBase + 32) = v4f{oB[0].x, oB[0].y, oB[1].x, oB[1].y};
        *(v4f*)(awBase + 48) = v4f{oB[2].x, oB[2].y, oB[3].x, oB[3].y};
        if (active) {
            float acc = 0.0f;
#pragma unroll
            for (int ww = 0; ww < RPB; ++ww) {
                v2f q = *(const v2f*)(waveMem + ww * WREG + spos);
                acc = fmaf(q.x, ph[ww].x, fmaf(-q.y, ph[ww].y, acc));
            }
            pOut[0] = acc;
        }
        __syncthreads();   // barrier k+1: bufB visible; bufA gathers done
        if (active) {
            float acc = 0.0f;
#pragma unroll
            for (int ww = 0; ww < RPB; ++ww) {
                v2f q = *(const v2f*)(waveMem + 32 + ww * WREG + spos);
                acc = fmaf(q.x, ph[ww].x, fmaf(-q.y, ph[ww].y, acc));
            }
            pOut[NB * NPHI] = acc;
        }
        pOut += 2 * NB * NPHI;
    }

    // --- save state for the next chunk (skipped when this is the last chunk) ---
    if (!lastChunk) {
        const size_t rowBase = ((size_t)b * NOUT + p) * NOUT;
#pragma unroll
        for (int r = 0; r < 8; ++r) {
            int e = r * 64 + L;
            stateCur[rowBase + e]  = make_float2(a[r].x, a[r].y);
            statePrev[rowBase + e] = make_float2(bb[r].x, bb[r].y);
        }
    }
}

// ---------------- reduce NGRP row-group partials -> out[b][j][t] ----------------------------------
__global__ __launch_bounds__(256) void reduce_kernel(const float* __restrict__ partial,
                                                     float* __restrict__ out,
                                                     int Tc, int tStart) {
    int id = blockIdx.x * 256 + threadIdx.x;   // over Tc*16*256, exact
    int j = id & 255;
    int b = (id >> 8) & 15;
    int tl = id >> 12;
    float s = 0.0f;
#pragma unroll
    for (int gg = 0; gg < NGRP; ++gg)
        s += partial[(((size_t)gg * Tc + tl) * NB + b) * NPHI + j];
    out[((size_t)b * NPHI + j) * NT + (tStart + tl)] = s * (1.0f / (512.0f * 512.0f));
}

extern "C" void kernel_launch(void* const* d_in, const int* in_sizes, int n_in,
                              void* d_out, int out_size, void* d_ws, size_t ws_size,
                              hipStream_t stream) {
    (void)in_sizes; (void)n_in; (void)out_size;
    const float* f   = (const float*)d_in[0];   // [16,1,256,256]
    const float* fil = (const float*)d_in[1];   // [512,512]
    const int* idx0  = (const int*)d_in[2];     // [256]
    const int* idx1  = (const int*)d_in[3];     // [256]
    float* out = (float*)d_out;                 // [16,1,256,240]

    char* ws = (char*)d_ws;
    const size_t stateBytes = (size_t)NB * NOUT * NOUT * sizeof(float2);  // 33.55 MB
    float2* stateCur  = (float2*)ws;
    float2* statePrev = (float2*)(ws + stateBytes);   // also reused as R scratch for f1/f2
    float*  partial   = (float*)(ws + 2 * stateBytes);
    size_t remain = (ws_size > 2 * stateBytes) ? ws_size - 2 * stateBytes : 0;

    // largest even time chunk whose partial buffer fits (even: the sim loop is 2-step unrolled)
    static const int tcs[] = {240, 120, 80, 60, 48, 40, 30, 24, 20, 16, 12, 10, 8, 6, 4, 2};
    int Tc = 2;
    for (int i = 0; i < 16; ++i) {
        size_t need = (size_t)NGRP * tcs[i] * NB * NPHI * sizeof(float);
        if (need <= remain) { Tc = tcs[i]; break; }
    }

    // no memset: f1 writes rows [128,384) of the R scratch; f2 skips the rest as known-zero
    f1_kernel<<<dim3(64, NB), 256, 0, stream>>>(f, statePrev);        // rows x in [128,384)
    f2_kernel<<<dim3(128, NB), 256, 0, stream>>>(statePrev, stateCur);
    for (int t0 = 0; t0 < NT; t0 += Tc) {
        int last = (t0 + Tc) >= NT ? 1 : 0;
        sim_kernel<<<dim3(NGRP, NB), RPB * 64, 0, stream>>>(fil, idx0, idx1, stateCur, statePrev,
                                                            partial, Tc, t0 == 0 ? 1 : 0, last);
        reduce_kernel<<<dim3(Tc * NB), 256, 0, stream>>>(partial, out, Tc, t0);
    }
}

// Round 5
// 1022.400 us; speedup vs baseline: 1.0725x; 1.0725x over previous
//
#include <hip/hip_runtime.h>
#include <hip/hip_bf16.h>

// WaveOperator: Fourier-domain 3-term recurrence + per-row inverse FFT sampling.
// A_{t+1}(p,q) = (2-4*fil(p,q)) * A_t - A_{t-1};  y[b,j,t] = Re(ifft2(A_{t+1})[u_j,v_j])
// R21: R19 structure (proven 906us) + instruction-count cuts in the exchange/twiddle stages.
// R20 post-mortem: dual-FFT ILP failed -- compiler kept VGPR=76 (refused the ~120-reg dual
// chain), serializing the chains; occupancy 26->16%, dur 906->1025. Reverted.
// R21 changes (all bit-exact same routing/arithmetic as R19):
//  1. xor8 exchange via __builtin_amdgcn_update_dpp merge (row_ror:8, bank_mask 0xC/0x3):
//     masked-write DPP replaces all cndmasks for that stage.
//  2. xor1/xor2/xor4 exchanges: shuffle-first select-last form (a' = bit ? dpp(b) : a) so
//     mov_dpp can fuse into v_cndmask_b32_dpp (GCNDPPCombine); never worse than R19 form.
//  3. Twiddle cmul as splat-mul+splat-fma with precomputed swap-neg twiddles tsn={-t.y,t.x}
//     (loop-invariant, +28 VGPR) -> v_pk_fma_f32-friendly (2 packed vs 4 scalar ops).
// VGPR ~64->~100: drops residency cap 4->3 blocks/CU == the workload's natural max (688 blocks
// on 256 CUs -> max 3/CU), so the critical path is unchanged.

#define NOUT 512
#define NB 16
#define NPHI 256
#define NT 240
#define RPB 6             // rows per block (= waves per block)
#define NGRP 43           // row groups: 43*6 = 258 = rows 0..257 (257 gets zero phase)

#define WREG 5184         // per-wave LDS publish region (pitch 80; lane uses 2x32B parity bufs)

typedef float v2f __attribute__((ext_vector_type(2)));
typedef float v4f __attribute__((ext_vector_type(4)));
typedef unsigned int v2u __attribute__((ext_vector_type(2)));

__device__ __forceinline__ v2f cmuliv(v2f a) { return v2f{-a.y, a.x}; }
__device__ __forceinline__ v2f cmulw8v(v2f a) {
    const float s = 0.70710678118654752f; return v2f{s * (a.x - a.y), s * (a.x + a.y)};
}
__device__ __forceinline__ v2f cmulw83v(v2f a) {
    const float s = 0.70710678118654752f; return v2f{-s * (a.x + a.y), s * (a.x - a.y)};
}

// twiddle complex-mul with precomputed swap-neg partner: t={c,s}, tsn={-s,c}
// G*t = t*G.x + tsn*G.y  (splat ops -> v_pk_fma_f32-friendly)
__device__ __forceinline__ v2f cmul_tw(v2f g, v2f t, v2f tsn) {
    return t * g.x + tsn * g.y;
}

// 8-pt DFT, positive exponent: Y[k] = sum_r y[r] * exp(+2pi i rk/8)
__device__ __forceinline__ void dft8p(const v2f y[8], v2f Y[8]) {
    v2f t0 = y[0] + y[4], t4 = y[0] - y[4];
    v2f t1 = y[1] + y[5], t5 = cmulw8v(y[1] - y[5]);
    v2f t2 = y[2] + y[6], t6 = cmuliv(y[2] - y[6]);
    v2f t3 = y[3] + y[7], t7 = cmulw83v(y[3] - y[7]);
    v2f u0 = t0 + t2, u2 = t0 - t2;
    v2f u1 = t1 + t3, u3 = cmuliv(t1 - t3);
    Y[0] = u0 + u1; Y[4] = u0 - u1;
    Y[2] = u2 + u3; Y[6] = u2 - u3;
    v2f v0 = t4 + t6, v2 = t4 - t6;
    v2f v1 = t5 + t7, v3 = cmuliv(t5 - t7);
    Y[1] = v0 + v1; Y[5] = v0 - v1;
    Y[3] = v2 + v3; Y[7] = v2 - v3;
}

// in-place variant (t-layer fully buffers the inputs before any write)
__device__ __forceinline__ void dft8p_ip(v2f y[8]) {
    v2f t0 = y[0] + y[4], t4 = y[0] - y[4];
    v2f t1 = y[1] + y[5], t5 = cmulw8v(y[1] - y[5]);
    v2f t2 = y[2] + y[6], t6 = cmuliv(y[2] - y[6]);
    v2f t3 = y[3] + y[7], t7 = cmulw83v(y[3] - y[7]);
    v2f u0 = t0 + t2, u2 = t0 - t2;
    v2f u1 = t1 + t3, u3 = cmuliv(t1 - t3);
    y[0] = u0 + u1; y[4] = u0 - u1;
    y[2] = u2 + u3; y[6] = u2 - u3;
    v2f v0 = t4 + t6, v2 = t4 - t6;
    v2f v1 = t5 + t7, v3 = cmuliv(t5 - t7);
    y[1] = v0 + v1; y[5] = v0 - v1;
    y[3] = v2 + v3; y[7] = v2 - v3;
}

// final-layer DFT producing only outputs Y2,Y3,Y4,Y5 (the sensor v>>6 range)
__device__ __forceinline__ void dft8p_mid4(const v2f y[8], v2f o[4]) {
    v2f t0 = y[0] + y[4], t4 = y[0] - y[4];
    v2f t1 = y[1] + y[5], t5 = cmulw8v(y[1] - y[5]);
    v2f t2 = y[2] + y[6], t6 = cmuliv(y[2] - y[6]);
    v2f t3 = y[3] + y[7], t7 = cmulw83v(y[3] - y[7]);
    v2f u0 = t0 + t2, u2 = t0 - t2;
    v2f u1 = t1 + t3, u3 = cmuliv(t1 - t3);
    v2f w0 = t4 + t6, w2 = t4 - t6;
    v2f w1 = t5 + t7, w3 = cmuliv(t5 - t7);
    o[0] = u2 + u3;    // Y2
    o[1] = w2 + w3;    // Y3
    o[2] = u0 - u1;    // Y4
    o[3] = w0 - w1;    // Y5
}

// W512^m from half-table
__device__ __forceinline__ v2f wlookup(const float2* trig, int m) {
    m &= 511;
    float2 ph = trig[m & 255];
    return (m & 256) ? v2f{-ph.x, -ph.y} : v2f{ph.x, ph.y};
}

// ---- in-register lane exchanges (transpose building blocks) -------------------------------------
template<int CTRL>
__device__ __forceinline__ float dppx(float x) {
    return __int_as_float(__builtin_amdgcn_mov_dpp(__float_as_int(x), CTRL, 0xF, 0xF, true));
}
__device__ __forceinline__ float swzx4(float x) {
    // BitMode swizzle: and=0x1F, or=0, xor=4  -> lane ^ 4
    return __int_as_float(__builtin_amdgcn_ds_swizzle(__float_as_int(x), 0x101F));
}

// xor1/xor2 exchange: unconditional DPP shuffles, select-last (fusable into cndmask_dpp).
// a' = bit ? b[^m] : a ; b' = bit ? b : a[^m]   (identical routing to R19)
template<int CTRL>
__device__ __forceinline__ void xchg_dpp(v2f& a, v2f& b, bool bit) {
    float dbx = dppx<CTRL>(b.x);
    float dby = dppx<CTRL>(b.y);
    float dax = dppx<CTRL>(a.x);
    float day = dppx<CTRL>(a.y);
    a.x = bit ? dbx : a.x;   a.y = bit ? dby : a.y;
    b.x = bit ? b.x : dax;   b.y = bit ? b.y : day;
}
// xor4 exchange via ds_swizzle, same select-last form (LDS pipe has headroom)
__device__ __forceinline__ void xchg_swz4(v2f& a, v2f& b, bool bit) {
    float dbx = swzx4(b.x);
    float dby = swzx4(b.y);
    float dax = swzx4(a.x);
    float day = swzx4(a.y);
    a.x = bit ? dbx : a.x;   a.y = bit ? dby : a.y;
    b.x = bit ? b.x : dax;   b.y = bit ? b.y : day;
}

// xor8 exchange via masked-merge DPP: row_ror:8 == lane^8 within each 16-lane row;
// bank_mask 0xC writes only lanes with (lane&8)!=0, 0x3 only (lane&8)==0. No cndmasks.
#if __has_builtin(__builtin_amdgcn_update_dpp)
__device__ __forceinline__ void xchg8(v2f& a, v2f& b, bool /*bit*/) {
    int ax = __float_as_int(a.x), ay = __float_as_int(a.y);
    int bx = __float_as_int(b.x), by = __float_as_int(b.y);
    a.x = __int_as_float(__builtin_amdgcn_update_dpp(ax, bx, 0x128, 0xF, 0xC, false));
    a.y = __int_as_float(__builtin_amdgcn_update_dpp(ay, by, 0x128, 0xF, 0xC, false));
    b.x = __int_as_float(__builtin_amdgcn_update_dpp(bx, ax, 0x128, 0xF, 0x3, false));
    b.y = __int_as_float(__builtin_amdgcn_update_dpp(by, ay, 0x128, 0xF, 0x3, false));
}
#else
__device__ __forceinline__ void xchg8(v2f& a, v2f& b, bool bit) {
    xchg_dpp<0x128>(a, b, bit);
}
#endif

#if __has_builtin(__builtin_amdgcn_permlane16_swap)
__device__ __forceinline__ void pl16x(v2f& a, v2f& b) {
    v2u rx = __builtin_amdgcn_permlane16_swap(__float_as_uint(a.x), __float_as_uint(b.x), false, false);
    a.x = __uint_as_float(rx.x); b.x = __uint_as_float(rx.y);
    v2u ry = __builtin_amdgcn_permlane16_swap(__float_as_uint(a.y), __float_as_uint(b.y), false, false);
    a.y = __uint_as_float(ry.x); b.y = __uint_as_float(ry.y);
}
#else
__device__ __forceinline__ void pl16x(v2f& a, v2f& b) {
    bool bit = (threadIdx.x & 16) != 0;
    float sx = bit ? a.x : b.x, sy = bit ? a.y : b.y;
    float tx = __shfl_xor(sx, 16), ty = __shfl_xor(sy, 16);
    a.x = bit ? tx : a.x; a.y = bit ? ty : a.y;
    b.x = bit ? b.x : tx; b.y = bit ? b.y : ty;
}
#endif

#if __has_builtin(__builtin_amdgcn_permlane32_swap)
__device__ __forceinline__ void pl32x(v2f& a, v2f& b) {
    v2u rx = __builtin_amdgcn_permlane32_swap(__float_as_uint(a.x), __float_as_uint(b.x), false, false);
    a.x = __uint_as_float(rx.x); b.x = __uint_as_float(rx.y);
    v2u ry = __builtin_amdgcn_permlane32_swap(__float_as_uint(a.y), __float_as_uint(b.y), false, false);
    a.y = __uint_as_float(ry.x); b.y = __uint_as_float(ry.y);
}
#else
__device__ __forceinline__ void pl32x(v2f& a, v2f& b) {
    bool bit = (threadIdx.x & 32) != 0;
    float sx = bit ? a.x : b.x, sy = bit ? a.y : b.y;
    float tx = __shfl_xor(sx, 32), ty = __shfl_xor(sy, 32);
    a.x = bit ? tx : a.x; a.y = bit ? ty : a.y;
    b.x = bit ? b.x : tx; b.y = bit ? b.y : ty;
}
#endif

// hot-loop step: in-register 512-pt inverse DFT (8x8x8 four-step; transposes via
// permlane/DPP/swizzle), publish G2..G5 to this step's parity buffer, ONE barrier, gather.
// awBase/ldsBase carry the parity offset (0 or 32) folded in by the caller.
__device__ __forceinline__ void fft_sample(
    const v2f y[8], const v2f tA[8], const v2f tAn[8], const v2f tB[8], const v2f tBn[8],
    bool b0, bool b1, bool b2, bool b3,
    char* awBase, const char* ldsBase, int spos, const v2f ph[RPB], bool active,
    float* pA)
{
    v2f G[8];
    dft8p(y, G);                                   // DFT over q2 (reg digit) -> v0
#pragma unroll
    for (int k1 = 1; k1 < 8; ++k1) G[k1] = cmul_tw(G[k1], tA[k1], tAn[k1]);   // W512^{L*v0}
    // T1: reg digit (v0) <-> lane-high digit (q1)
    xchg8(G[0], G[1], b3);  xchg8(G[2], G[3], b3);                       // xor8 (merge-DPP)
    xchg8(G[4], G[5], b3);  xchg8(G[6], G[7], b3);
    pl16x(G[0], G[2]);  pl16x(G[1], G[3]);  pl16x(G[4], G[6]);  pl16x(G[5], G[7]);   // xor16
    pl32x(G[0], G[4]);  pl32x(G[1], G[5]);  pl32x(G[2], G[6]);  pl32x(G[3], G[7]);   // xor32
    dft8p_ip(G);                                   // DFT over q1 -> v1
#pragma unroll
    for (int m1 = 1; m1 < 8; ++m1) G[m1] = cmul_tw(G[m1], tB[m1], tBn[m1]);   // W512^{8*q0*v1}
    // T2: reg digit (v1) <-> lane-low digit (q0)
    xchg_dpp<0xB1>(G[0], G[1], b0);  xchg_dpp<0xB1>(G[2], G[3], b0);     // quad_perm xor1
    xchg_dpp<0xB1>(G[4], G[5], b0);  xchg_dpp<0xB1>(G[6], G[7], b0);
    xchg_dpp<0x4E>(G[0], G[2], b1);  xchg_dpp<0x4E>(G[1], G[3], b1);     // quad_perm xor2
    xchg_dpp<0x4E>(G[4], G[6], b1);  xchg_dpp<0x4E>(G[5], G[7], b1);
    xchg_swz4(G[0], G[4], b2);  xchg_swz4(G[1], G[5], b2);               // ds_swizzle xor4
    xchg_swz4(G[2], G[6], b2);  xchg_swz4(G[3], G[7], b2);
    v2f o[4];
    dft8p_mid4(G, o);                              // DFT over q0 -> v2 (only outputs 2..5)
    *(v4f*)(awBase +  0) = v4f{o[0].x, o[0].y, o[1].x, o[1].y};   // G2,G3
    *(v4f*)(awBase + 16) = v4f{o[2].x, o[2].y, o[3].x, o[3].y};   // G4,G5
    __syncthreads();   // single barrier: publish visible; orders prev gather vs buffer reuse
    if (active) {
        float acc = 0.0f;
#pragma unroll
        for (int ww = 0; ww < RPB; ++ww) {
            v2f q = *(const v2f*)(ldsBase + ww * WREG + spos);
            acc = fmaf(q.x, ph[ww].x, fmaf(-q.y, ph[ww].y, acc));
        }
        pA[0] = acc;
    }
}

// ---------------- init kernels (run once, shuffle FFT) -------------------------------------------
__device__ __forceinline__ void cbfly(float& ar, float& ai, float& br, float& bi,
                                      float wr, float wi) {
    float dr = ar - br, di = ai - bi;
    ar = ar + br; ai = ai + bi;
    br = fmaf(dr, wr, -di * wi);
    bi = fmaf(dr, wi,  di * wr);
}

__device__ __forceinline__ void init_trig(float2* trig, int tid) {
    if (tid < 256) {
        float ang = (float)tid * (6.283185307179586f / 512.0f);
        float s, c;
        sincosf(ang, &s, &c);
        trig[tid] = make_float2(c, s);
    }
}

__device__ __forceinline__ void fft512_inv_lds(float* xr, float* xi, const float2* trig, int L) {
#pragma unroll
    for (int r = 0; r < 4; ++r) {
        float2 w = trig[(r << 6) + L];
        cbfly(xr[r], xi[r], xr[r + 4], xi[r + 4], w.x, w.y);
    }
    {
        float2 w0 = trig[L << 1];
        float2 w1 = trig[(64 + L) << 1];
        cbfly(xr[0], xi[0], xr[2], xi[2], w0.x, w0.y);
        cbfly(xr[1], xi[1], xr[3], xi[3], w1.x, w1.y);
        cbfly(xr[4], xi[4], xr[6], xi[6], w0.x, w0.y);
        cbfly(xr[5], xi[5], xr[7], xi[7], w1.x, w1.y);
    }
    {
        float2 w = trig[L << 2];
        cbfly(xr[0], xi[0], xr[1], xi[1], w.x, w.y);
        cbfly(xr[2], xi[2], xr[3], xi[3], w.x, w.y);
        cbfly(xr[4], xi[4], xr[5], xi[5], w.x, w.y);
        cbfly(xr[6], xi[6], xr[7], xi[7], w.x, w.y);
    }
#pragma unroll
    for (int s = 3; s <= 8; ++s) {
        const int half = 512 >> (s + 1);
        const int ex = (L & (half - 1)) << s;
        float2 w = trig[ex];
        const bool hi = (L & half) != 0;
        float wr = hi ? w.x : 1.0f;
        float wi = hi ? w.y : 0.0f;
        float sg = hi ? -1.0f : 1.0f;
#pragma unroll
        for (int r = 0; r < 8; ++r) {
            float orv = __shfl_xor(xr[r], half);
            float oiv = __shfl_xor(xi[r], half);
            float tr = fmaf(sg, xr[r], orv);
            float ti = fmaf(sg, xi[r], oiv);
            xr[r] = fmaf(tr, wr, -ti * wi);
            xi[r] = fmaf(tr, wi,  ti * wr);
        }
    }
}

__global__ __launch_bounds__(256) void f1_kernel(const float* __restrict__ f,
                                                 float2* __restrict__ R) {
    __shared__ float2 trig[256];
    const int tid = threadIdx.x;
    init_trig(trig, tid);
    __syncthreads();
    const int w = tid >> 6, L = tid & 63;
    const int x = 128 + blockIdx.x * 4 + w;   // nonzero rows only: [128, 384)
    const int b = blockIdx.y;
    const float* frow = f + ((size_t)b * 256 + (x - 128)) * 256;
    float xr[8], xi[8];
#pragma unroll
    for (int r = 0; r < 8; ++r) {
        int e = r * 64 + L;
        xr[r] = (e >= 128 && e < 384) ? frow[e - 128] : 0.0f;
        xi[r] = 0.0f;
    }
    fft512_inv_lds(xr, xi, trig, L);
    float2* Rrow = R + ((size_t)b * NOUT + x) * NOUT;
#pragma unroll
    for (int r = 0; r < 8; ++r) {
        int e = r * 64 + L;
        int k = __brev((unsigned)e) >> 23;
        Rrow[k] = make_float2(xr[r], -xi[r]);
    }
}

// f2: rows x outside [128,384) of R were never written (and are not zeroed) — treat as 0.
// e = r*64 + L is in [128,384) exactly for r in [2,6).
__global__ __launch_bounds__(256) void f2_kernel(const float2* __restrict__ R,
                                                 float2* __restrict__ A0) {
    __shared__ float2 trig[256];
    const int tid = threadIdx.x;
    init_trig(trig, tid);
    __syncthreads();
    const int w = tid >> 6, L = tid & 63;
    const int q = blockIdx.x * 4 + w;
    const int b = blockIdx.y;
    float xr[8], xi[8];
#pragma unroll
    for (int r = 0; r < 8; ++r) {
        if (r >= 2 && r < 6) {
            int e = r * 64 + L;
            float2 v = R[((size_t)b * NOUT + e) * NOUT + q];
            xr[r] = v.x;
            xi[r] = -v.y;
        } else {
            xr[r] = 0.0f;
            xi[r] = 0.0f;
        }
    }
    fft512_inv_lds(xr, xi, trig, L);
#pragma unroll
    for (int r = 0; r < 8; ++r) {
        int e = r * 64 + L;
        int p = __brev((unsigned)e) >> 23;
        A0[((size_t)b * NOUT + p) * NOUT + q] = make_float2(xr[r], -xi[r]);
    }
}

// ---------------- time-chunk simulation ----------------------------------------------------------
// block = (row group g of RPB rows, batch b); wave w owns row p = RPB*g + w, p in 0..257.
// Threads 0..255 each own one sensor, summing the block's RPB rows after the step barrier.
__global__ __launch_bounds__(384, 4) void sim_kernel(
    const float* __restrict__ fil,
    const int* __restrict__ idx0, const int* __restrict__ idx1,
    float2* __restrict__ stateCur, float2* __restrict__ statePrev,
    float* __restrict__ partial, int Tc, int firstChunk, int lastChunk)
{
    __shared__ __align__(16) char waveMem[RPB * WREG];   // 31104 B
    __shared__ float2 trig[256];                         //  2048 B -> 33152 B total

    const int tid = threadIdx.x;              // 0..383
    const int w = tid >> 6, L = tid & 63;
    const int g = blockIdx.x, b = blockIdx.y;
    const int p = g * RPB + w;                // 0..257

    if (tid < 256) {
        float ang = (float)tid * (6.283185307179586f / 512.0f);
        float s, c;
        sincosf(ang, &s, &c);
        trig[tid] = make_float2(c, s);
    }
    __syncthreads();

    // --- per-lane constant twiddles (+ swap-neg partners for pk-fma cmul) ---
    v2f tA[8], tAn[8], tB[8], tBn[8];
#pragma unroll
    for (int k1 = 1; k1 < 8; ++k1) {
        tA[k1] = wlookup(trig, L * k1);
        tAn[k1] = v2f{-tA[k1].y, tA[k1].x};
    }
#pragma unroll
    for (int m1 = 1; m1 < 8; ++m1) {
        tB[m1] = wlookup(trig, 8 * (L & 7) * m1);
        tBn[m1] = v2f{-tB[m1].y, tB[m1].x};
    }

    // --- transpose predicates (loop-invariant; land in SGPR masks) ---
    const bool b0 = (L & 1) != 0;
    const bool b1 = (L & 2) != 0;
    const bool b2 = (L & 4) != 0;
    const bool b3 = (L & 8) != 0;

    // --- sensor constants: thread tid<256 owns sensor j=tid ---
    const bool active = tid < 256;
    int spos = 0;
    v2f ph[RPB];
    if (active) {
        int u = idx0[tid];
        int v = idx1[tid];
        // published regs are v>>6 in {2..5} at lane-local offsets 0,8,16,24 (parity 0)
        spos = ((v & 7) * 8 + ((v >> 3) & 7)) * 80 + ((v >> 6) * 8 - 16);
        // Hermitian fold phase: p==0 -> 1, p==256 -> (-1)^u, p==257 -> 0, else 2*W512^{pu}
#pragma unroll
        for (int ww = 0; ww < RPB; ++ww) {
            int prow = g * RPB + ww;
            v2f a0;
            if (prow == 0)        a0 = v2f{1.0f, 0.0f};
            else if (prow == 256) a0 = v2f{(u & 1) ? -1.0f : 1.0f, 0.0f};
            else if (prow == 257) a0 = v2f{0.0f, 0.0f};
            else                  a0 = 2.0f * wlookup(trig, prow * u);
            ph[ww] = a0;
        }
    } else {
#pragma unroll
        for (int ww = 0; ww < RPB; ++ww) ph[ww] = v2f{0.0f, 0.0f};
    }

    // --- per-lane LDS publish base; parity buffer offsets 0 / 32 within the pitch-80 slot ---
    char* myA    = waveMem + w * WREG;
    char* awBase = myA + L * 80;

    // --- load state + filter into registers ---
    v2f a[8], bb[8];
    float C[8];
    {
        const size_t rowBase = ((size_t)b * NOUT + p) * NOUT;
        const float* filRow = fil + (size_t)p * NOUT;
#pragma unroll
        for (int r = 0; r < 8; ++r) {
            int e = r * 64 + L;
            float2 a0 = stateCur[rowBase + e];
            a[r] = v2f{a0.x, a0.y};
            if (firstChunk) {
                bb[r] = a[r];
            } else {
                float2 a1 = statePrev[rowBase + e];
                bb[r] = v2f{a1.x, a1.y};
            }
            C[r] = fmaf(-4.0f, filRow[e], 2.0f);
        }
    }

    float* pOut = partial + ((size_t)g * Tc * NB + b) * NPHI + tid;

    for (int tl = 0; tl < Tc; tl += 2) {
        // step A (parity 0): bb becomes A_{t+1}
#pragma unroll
        for (int r = 0; r < 8; ++r) bb[r] = v2f{C[r], C[r]} * a[r] - bb[r];
        fft_sample(bb, tA, tAn, tB, tBn, b0, b1, b2, b3, awBase, waveMem,
                   spos, ph, active, pOut);
        pOut += NB * NPHI;
        // step B (parity 1): a becomes A_{t+2}
#pragma unroll
        for (int r = 0; r < 8; ++r) a[r] = v2f{C[r], C[r]} * bb[r] - a[r];
        fft_sample(a, tA, tAn, tB, tBn, b0, b1, b2, b3, awBase + 32, waveMem + 32,
                   spos, ph, active, pOut);
        pOut += NB * NPHI;
    }

    // --- save state for the next chunk (skipped when this is the last chunk) ---
    if (!lastChunk) {
        const size_t rowBase = ((size_t)b * NOUT + p) * NOUT;
#pragma unroll
        for (int r = 0; r < 8; ++r) {
            int e = r * 64 + L;
            stateCur[rowBase + e]  = make_float2(a[r].x, a[r].y);
            statePrev[rowBase + e] = make_float2(bb[r].x, bb[r].y);
        }
    }
}

// ---------------- reduce NGRP row-group partials -> out[b][j][t] ----------------------------------
__global__ __launch_bounds__(256) void reduce_kernel(const float* __restrict__ partial,
                                                     float* __restrict__ out,
                                                     int Tc, int tStart) {
    int id = blockIdx.x * 256 + threadIdx.x;   // over Tc*16*256, exact
    int j = id & 255;
    int b = (id >> 8) & 15;
    int tl = id >> 12;
    float s = 0.0f;
#pragma unroll
    for (int gg = 0; gg < NGRP; ++gg)
        s += partial[(((size_t)gg * Tc + tl) * NB + b) * NPHI + j];
    out[((size_t)b * NPHI + j) * NT + (tStart + tl)] = s * (1.0f / (512.0f * 512.0f));
}

extern "C" void kernel_launch(void* const* d_in, const int* in_sizes, int n_in,
                              void* d_out, int out_size, void* d_ws, size_t ws_size,
                              hipStream_t stream) {
    (void)in_sizes; (void)n_in; (void)out_size;
    const float* f   = (const float*)d_in[0];   // [16,1,256,256]
    const float* fil = (const float*)d_in[1];   // [512,512]
    const int* idx0  = (const int*)d_in[2];     // [256]
    const int* idx1  = (const int*)d_in[3];     // [256]
    float* out = (float*)d_out;                 // [16,1,256,240]

    char* ws = (char*)d_ws;
    const size_t stateBytes = (size_t)NB * NOUT * NOUT * sizeof(float2);  // 33.55 MB
    float2* stateCur  = (float2*)ws;
    float2* statePrev = (float2*)(ws + stateBytes);   // also reused as R scratch for f1/f2
    float*  partial   = (float*)(ws + 2 * stateBytes);
    size_t remain = (ws_size > 2 * stateBytes) ? ws_size - 2 * stateBytes : 0;

    // largest even time chunk whose partial buffer fits (even: the sim loop is 2-step unrolled)
    static const int tcs[] = {240, 120, 80, 60, 48, 40, 30, 24, 20, 16, 12, 10, 8, 6, 4, 2};
    int Tc = 2;
    for (int i = 0; i < 16; ++i) {
        size_t need = (size_t)NGRP * tcs[i] * NB * NPHI * sizeof(float);
        if (need <= remain) { Tc = tcs[i]; break; }
    }

    // no memset: f1 writes rows [128,384) of the R scratch; f2 skips the rest as known-zero
    f1_kernel<<<dim3(64, NB), 256, 0, stream>>>(f, statePrev);        // rows x in [128,384)
    f2_kernel<<<dim3(128, NB), 256, 0, stream>>>(statePrev, stateCur);
    for (int t0 = 0; t0 < NT; t0 += Tc) {
        int last = (t0 + Tc) >= NT ? 1 : 0;
        sim_kernel<<<dim3(NGRP, NB), RPB * 64, 0, stream>>>(fil, idx0, idx1, stateCur, statePrev,
                                                            partial, Tc, t0 == 0 ? 1 : 0, last);
        reduce_kernel<<<dim3(Tc * NB), 256, 0, stream>>>(partial, out, Tc, t0);
    }
}

// Round 6
// 1017.121 us; speedup vs baseline: 1.0780x; 1.0052x over previous
//
#include <hip/hip_runtime.h>
#include <hip/hip_bf16.h>

// WaveOperator: Fourier-domain 3-term recurrence + per-row inverse FFT sampling.
// A_{t+1}(p,q) = (2-4*fil(p,q)) * A_t - A_{t-1};  y[b,j,t] = Re(ifft2(A_{t+1})[u_j,v_j])
// R22 = R19 core (proven 906us sim) + balanced gather.
// R20/R21 post-mortem: the allocator pins this kernel at VGPR=64; any added live state
// (dual-FFT chains, precomputed twiddle partners) is spilled/serialized, regressing 7-12%.
// -> only register-neutral changes are viable.
// R22 change: the per-step sensor gather (6 ds_read + 12 fma chain) ran only on waves 0-3;
// waves 4-5 idled and the barrier waited on the gather chain 240x. Now:
//   threads 0-255:   gather rows 0-3 of own sensor (4 reads + 8 fma)
//   threads 256-383: gather rows 4-5 for TWO sensors (4 reads + 8 fma), publish partials to
//                    pr45[parity][256] in LDS (2KB, parity-double-buffered)
//   thread j combines pr45[parity][j] one epoch later (1-step pipeline; flushed post-loop).
// Epoch audit (α=mid-iter barrier, β=end-iter barrier):
//   buf0: pub pre-α(i), read post-α(i) | next pub pre-α(i+1) -- separated by β(i).
//   buf1: pub pre-β(i), read post-β(i) | next pub pre-β(i+1) -- separated by α(i+1).
//   pr45[0]: write post-α(i), read post-β(i)  -- separated by β(i).
//   pr45[1]: write post-β(i), read post-α(i+1) or post-final-barrier -- separated by α(i+1).
// All write/read pairs barrier-separated; 1 barrier per step preserved.

#define NOUT 512
#define NB 16
#define NPHI 256
#define NT 240
#define RPB 6             // rows per block (= waves per block)
#define NGRP 43           // row groups: 43*6 = 258 = rows 0..257 (257 gets zero phase)

#define WREG 5184         // per-wave LDS publish region (pitch 80; lane uses 2x32B parity bufs)

typedef float v2f __attribute__((ext_vector_type(2)));
typedef float v4f __attribute__((ext_vector_type(4)));
typedef unsigned int v2u __attribute__((ext_vector_type(2)));

__device__ __forceinline__ v2f cmulv(v2f a, v2f b) {
    return v2f{fmaf(a.x, b.x, -a.y * b.y), fmaf(a.x, b.y, a.y * b.x)};
}
__device__ __forceinline__ v2f cmuliv(v2f a) { return v2f{-a.y, a.x}; }
__device__ __forceinline__ v2f cmulw8v(v2f a) {
    const float s = 0.70710678118654752f; return v2f{s * (a.x - a.y), s * (a.x + a.y)};
}
__device__ __forceinline__ v2f cmulw83v(v2f a) {
    const float s = 0.70710678118654752f; return v2f{-s * (a.x + a.y), s * (a.x - a.y)};
}

// 8-pt DFT, positive exponent: Y[k] = sum_r y[r] * exp(+2pi i rk/8)
__device__ __forceinline__ void dft8p(const v2f y[8], v2f Y[8]) {
    v2f t0 = y[0] + y[4], t4 = y[0] - y[4];
    v2f t1 = y[1] + y[5], t5 = cmulw8v(y[1] - y[5]);
    v2f t2 = y[2] + y[6], t6 = cmuliv(y[2] - y[6]);
    v2f t3 = y[3] + y[7], t7 = cmulw83v(y[3] - y[7]);
    v2f u0 = t0 + t2, u2 = t0 - t2;
    v2f u1 = t1 + t3, u3 = cmuliv(t1 - t3);
    Y[0] = u0 + u1; Y[4] = u0 - u1;
    Y[2] = u2 + u3; Y[6] = u2 - u3;
    v2f v0 = t4 + t6, v2 = t4 - t6;
    v2f v1 = t5 + t7, v3 = cmuliv(t5 - t7);
    Y[1] = v0 + v1; Y[5] = v0 - v1;
    Y[3] = v2 + v3; Y[7] = v2 - v3;
}

// in-place variant (t-layer fully buffers the inputs before any write)
__device__ __forceinline__ void dft8p_ip(v2f y[8]) {
    v2f t0 = y[0] + y[4], t4 = y[0] - y[4];
    v2f t1 = y[1] + y[5], t5 = cmulw8v(y[1] - y[5]);
    v2f t2 = y[2] + y[6], t6 = cmuliv(y[2] - y[6]);
    v2f t3 = y[3] + y[7], t7 = cmulw83v(y[3] - y[7]);
    v2f u0 = t0 + t2, u2 = t0 - t2;
    v2f u1 = t1 + t3, u3 = cmuliv(t1 - t3);
    y[0] = u0 + u1; y[4] = u0 - u1;
    y[2] = u2 + u3; y[6] = u2 - u3;
    v2f v0 = t4 + t6, v2 = t4 - t6;
    v2f v1 = t5 + t7, v3 = cmuliv(t5 - t7);
    y[1] = v0 + v1; y[5] = v0 - v1;
    y[3] = v2 + v3; y[7] = v2 - v3;
}

// final-layer DFT producing only outputs Y2,Y3,Y4,Y5 (the sensor v>>6 range)
__device__ __forceinline__ void dft8p_mid4(const v2f y[8], v2f o[4]) {
    v2f t0 = y[0] + y[4], t4 = y[0] - y[4];
    v2f t1 = y[1] + y[5], t5 = cmulw8v(y[1] - y[5]);
    v2f t2 = y[2] + y[6], t6 = cmuliv(y[2] - y[6]);
    v2f t3 = y[3] + y[7], t7 = cmulw83v(y[3] - y[7]);
    v2f u0 = t0 + t2, u2 = t0 - t2;
    v2f u1 = t1 + t3, u3 = cmuliv(t1 - t3);
    v2f w0 = t4 + t6, w2 = t4 - t6;
    v2f w1 = t5 + t7, w3 = cmuliv(t5 - t7);
    o[0] = u2 + u3;    // Y2
    o[1] = w2 + w3;    // Y3
    o[2] = u0 - u1;    // Y4
    o[3] = w0 - w1;    // Y5
}

// W512^m from half-table
__device__ __forceinline__ v2f wlookup(const float2* trig, int m) {
    m &= 511;
    float2 ph = trig[m & 255];
    return (m & 256) ? v2f{-ph.x, -ph.y} : v2f{ph.x, ph.y};
}

// ---- in-register lane exchanges (transpose building blocks) -------------------------------------
template<int CTRL>
__device__ __forceinline__ float dppx(float x) {
    return __int_as_float(__builtin_amdgcn_mov_dpp(__float_as_int(x), CTRL, 0xF, 0xF, true));
}
__device__ __forceinline__ float swzx4(float x) {
    // BitMode swizzle: and=0x1F, or=0, xor=4  -> lane ^ 4
    return __int_as_float(__builtin_amdgcn_ds_swizzle(__float_as_int(x), 0x101F));
}

template<int CTRL>
__device__ __forceinline__ void xchg_dpp(v2f& a, v2f& b, bool bit) {
    float sx = bit ? a.x : b.x;
    float sy = bit ? a.y : b.y;
    float tx = dppx<CTRL>(sx);
    float ty = dppx<CTRL>(sy);
    a.x = bit ? tx : a.x;   a.y = bit ? ty : a.y;
    b.x = bit ? b.x : tx;   b.y = bit ? b.y : ty;
}
__device__ __forceinline__ void xchg_swz4(v2f& a, v2f& b, bool bit) {
    float sx = bit ? a.x : b.x;
    float sy = bit ? a.y : b.y;
    float tx = swzx4(sx);
    float ty = swzx4(sy);
    a.x = bit ? tx : a.x;   a.y = bit ? ty : a.y;
    b.x = bit ? b.x : tx;   b.y = bit ? b.y : ty;
}

#if __has_builtin(__builtin_amdgcn_permlane16_swap)
__device__ __forceinline__ void pl16x(v2f& a, v2f& b) {
    v2u rx = __builtin_amdgcn_permlane16_swap(__float_as_uint(a.x), __float_as_uint(b.x), false, false);
    a.x = __uint_as_float(rx.x); b.x = __uint_as_float(rx.y);
    v2u ry = __builtin_amdgcn_permlane16_swap(__float_as_uint(a.y), __float_as_uint(b.y), false, false);
    a.y = __uint_as_float(ry.x); b.y = __uint_as_float(ry.y);
}
#else
__device__ __forceinline__ void pl16x(v2f& a, v2f& b) {
    bool bit = (threadIdx.x & 16) != 0;
    float sx = bit ? a.x : b.x, sy = bit ? a.y : b.y;
    float tx = __shfl_xor(sx, 16), ty = __shfl_xor(sy, 16);
    a.x = bit ? tx : a.x; a.y = bit ? ty : a.y;
    b.x = bit ? b.x : tx; b.y = bit ? b.y : ty;
}
#endif

#if __has_builtin(__builtin_amdgcn_permlane32_swap)
__device__ __forceinline__ void pl32x(v2f& a, v2f& b) {
    v2u rx = __builtin_amdgcn_permlane32_swap(__float_as_uint(a.x), __float_as_uint(b.x), false, false);
    a.x = __uint_as_float(rx.x); b.x = __uint_as_float(rx.y);
    v2u ry = __builtin_amdgcn_permlane32_swap(__float_as_uint(a.y), __float_as_uint(b.y), false, false);
    a.y = __uint_as_float(ry.x); b.y = __uint_as_float(ry.y);
}
#else
__device__ __forceinline__ void pl32x(v2f& a, v2f& b) {
    bool bit = (threadIdx.x & 32) != 0;
    float sx = bit ? a.x : b.x, sy = bit ? a.y : b.y;
    float tx = __shfl_xor(sx, 32), ty = __shfl_xor(sy, 32);
    a.x = bit ? tx : a.x; a.y = bit ? ty : a.y;
    b.x = bit ? b.x : tx; b.y = bit ? b.y : ty;
}
#endif

// in-register 512-pt inverse DFT (8x8x8 four-step; transposes via permlane/DPP/swizzle),
// publish G2..G5 to the given parity buffer. NO barrier, NO gather (moved to caller).
__device__ __forceinline__ void fft_publish(
    const v2f y[8], const v2f tA[8], const v2f tB[8],
    bool b0, bool b1, bool b2, bool b3, char* awBase)
{
    v2f G[8];
    dft8p(y, G);                                   // DFT over q2 (reg digit) -> v0
#pragma unroll
    for (int k1 = 1; k1 < 8; ++k1) G[k1] = cmulv(G[k1], tA[k1]);   // W512^{L*v0}
    // T1: reg digit (v0) <-> lane-high digit (q1)
    xchg_dpp<0x128>(G[0], G[1], b3);  xchg_dpp<0x128>(G[2], G[3], b3);   // row_ror:8 == xor8
    xchg_dpp<0x128>(G[4], G[5], b3);  xchg_dpp<0x128>(G[6], G[7], b3);
    pl16x(G[0], G[2]);  pl16x(G[1], G[3]);  pl16x(G[4], G[6]);  pl16x(G[5], G[7]);   // xor16
    pl32x(G[0], G[4]);  pl32x(G[1], G[5]);  pl32x(G[2], G[6]);  pl32x(G[3], G[7]);   // xor32
    dft8p_ip(G);                                   // DFT over q1 -> v1
#pragma unroll
    for (int m1 = 1; m1 < 8; ++m1) G[m1] = cmulv(G[m1], tB[m1]);   // W512^{8*q0*v1}
    // T2: reg digit (v1) <-> lane-low digit (q0)
    xchg_dpp<0xB1>(G[0], G[1], b0);  xchg_dpp<0xB1>(G[2], G[3], b0);     // quad_perm xor1
    xchg_dpp<0xB1>(G[4], G[5], b0);  xchg_dpp<0xB1>(G[6], G[7], b0);
    xchg_dpp<0x4E>(G[0], G[2], b1);  xchg_dpp<0x4E>(G[1], G[3], b1);     // quad_perm xor2
    xchg_dpp<0x4E>(G[4], G[6], b1);  xchg_dpp<0x4E>(G[5], G[7], b1);
    xchg_swz4(G[0], G[4], b2);  xchg_swz4(G[1], G[5], b2);               // ds_swizzle xor4
    xchg_swz4(G[2], G[6], b2);  xchg_swz4(G[3], G[7], b2);
    v2f o[4];
    dft8p_mid4(G, o);                              // DFT over q0 -> v2 (only outputs 2..5)
    *(v4f*)(awBase +  0) = v4f{o[0].x, o[0].y, o[1].x, o[1].y};   // G2,G3
    *(v4f*)(awBase + 16) = v4f{o[2].x, o[2].y, o[3].x, o[3].y};   // G4,G5
}

// ---------------- init kernels (run once, shuffle FFT) -------------------------------------------
__device__ __forceinline__ void cbfly(float& ar, float& ai, float& br, float& bi,
                                      float wr, float wi) {
    float dr = ar - br, di = ai - bi;
    ar = ar + br; ai = ai + bi;
    br = fmaf(dr, wr, -di * wi);
    bi = fmaf(dr, wi,  di * wr);
}

__device__ __forceinline__ void init_trig(float2* trig, int tid) {
    if (tid < 256) {
        float ang = (float)tid * (6.283185307179586f / 512.0f);
        float s, c;
        sincosf(ang, &s, &c);
        trig[tid] = make_float2(c, s);
    }
}

__device__ __forceinline__ void fft512_inv_lds(float* xr, float* xi, const float2* trig, int L) {
#pragma unroll
    for (int r = 0; r < 4; ++r) {
        float2 w = trig[(r << 6) + L];
        cbfly(xr[r], xi[r], xr[r + 4], xi[r + 4], w.x, w.y);
    }
    {
        float2 w0 = trig[L << 1];
        float2 w1 = trig[(64 + L) << 1];
        cbfly(xr[0], xi[0], xr[2], xi[2], w0.x, w0.y);
        cbfly(xr[1], xi[1], xr[3], xi[3], w1.x, w1.y);
        cbfly(xr[4], xi[4], xr[6], xi[6], w0.x, w0.y);
        cbfly(xr[5], xi[5], xr[7], xi[7], w1.x, w1.y);
    }
    {
        float2 w = trig[L << 2];
        cbfly(xr[0], xi[0], xr[1], xi[1], w.x, w.y);
        cbfly(xr[2], xi[2], xr[3], xi[3], w.x, w.y);
        cbfly(xr[4], xi[4], xr[5], xi[5], w.x, w.y);
        cbfly(xr[6], xi[6], xr[7], xi[7], w.x, w.y);
    }
#pragma unroll
    for (int s = 3; s <= 8; ++s) {
        const int half = 512 >> (s + 1);
        const int ex = (L & (half - 1)) << s;
        float2 w = trig[ex];
        const bool hi = (L & half) != 0;
        float wr = hi ? w.x : 1.0f;
        float wi = hi ? w.y : 0.0f;
        float sg = hi ? -1.0f : 1.0f;
#pragma unroll
        for (int r = 0; r < 8; ++r) {
            float orv = __shfl_xor(xr[r], half);
            float oiv = __shfl_xor(xi[r], half);
            float tr = fmaf(sg, xr[r], orv);
            float ti = fmaf(sg, xi[r], oiv);
            xr[r] = fmaf(tr, wr, -ti * wi);
            xi[r] = fmaf(tr, wi,  ti * wr);
        }
    }
}

__global__ __launch_bounds__(256) void f1_kernel(const float* __restrict__ f,
                                                 float2* __restrict__ R) {
    __shared__ float2 trig[256];
    const int tid = threadIdx.x;
    init_trig(trig, tid);
    __syncthreads();
    const int w = tid >> 6, L = tid & 63;
    const int x = 128 + blockIdx.x * 4 + w;   // nonzero rows only: [128, 384)
    const int b = blockIdx.y;
    const float* frow = f + ((size_t)b * 256 + (x - 128)) * 256;
    float xr[8], xi[8];
#pragma unroll
    for (int r = 0; r < 8; ++r) {
        int e = r * 64 + L;
        xr[r] = (e >= 128 && e < 384) ? frow[e - 128] : 0.0f;
        xi[r] = 0.0f;
    }
    fft512_inv_lds(xr, xi, trig, L);
    float2* Rrow = R + ((size_t)b * NOUT + x) * NOUT;
#pragma unroll
    for (int r = 0; r < 8; ++r) {
        int e = r * 64 + L;
        int k = __brev((unsigned)e) >> 23;
        Rrow[k] = make_float2(xr[r], -xi[r]);
    }
}

// f2: rows x outside [128,384) of R were never written (and are not zeroed) — treat as 0.
// e = r*64 + L is in [128,384) exactly for r in [2,6).
__global__ __launch_bounds__(256) void f2_kernel(const float2* __restrict__ R,
                                                 float2* __restrict__ A0) {
    __shared__ float2 trig[256];
    const int tid = threadIdx.x;
    init_trig(trig, tid);
    __syncthreads();
    const int w = tid >> 6, L = tid & 63;
    const int q = blockIdx.x * 4 + w;
    const int b = blockIdx.y;
    float xr[8], xi[8];
#pragma unroll
    for (int r = 0; r < 8; ++r) {
        if (r >= 2 && r < 6) {
            int e = r * 64 + L;
            float2 v = R[((size_t)b * NOUT + e) * NOUT + q];
            xr[r] = v.x;
            xi[r] = -v.y;
        } else {
            xr[r] = 0.0f;
            xi[r] = 0.0f;
        }
    }
    fft512_inv_lds(xr, xi, trig, L);
#pragma unroll
    for (int r = 0; r < 8; ++r) {
        int e = r * 64 + L;
        int p = __brev((unsigned)e) >> 23;
        A0[((size_t)b * NOUT + p) * NOUT + q] = make_float2(xr[r], -xi[r]);
    }
}

// ---------------- time-chunk simulation ----------------------------------------------------------
// block = (row group g of RPB rows, batch b); wave w owns row p = RPB*g + w, p in 0..257.
// Gather split: threads 0-255 sum rows 0-3 of own sensor; threads 256-383 sum rows 4-5 for
// two sensors each into pr45[parity][]; combined one epoch later (1-step pipeline).
__global__ __launch_bounds__(384, 4) void sim_kernel(
    const float* __restrict__ fil,
    const int* __restrict__ idx0, const int* __restrict__ idx1,
    float2* __restrict__ stateCur, float2* __restrict__ statePrev,
    float* __restrict__ partial, int Tc, int firstChunk, int lastChunk)
{
    __shared__ __align__(16) char waveMem[RPB * WREG];   // 31104 B
    __shared__ float2 trig[256];                         //  2048 B
    __shared__ float pr45[2][NPHI];                      //  2048 B -> ~35.2 KB total

    const int tid = threadIdx.x;              // 0..383
    const int w = tid >> 6, L = tid & 63;
    const int g = blockIdx.x, b = blockIdx.y;
    const int p = g * RPB + w;                // 0..257

    if (tid < 256) {
        float ang = (float)tid * (6.283185307179586f / 512.0f);
        float s, c;
        sincosf(ang, &s, &c);
        trig[tid] = make_float2(c, s);
    }
    __syncthreads();

    // --- per-lane constant twiddles ---
    v2f tA[8], tB[8];
#pragma unroll
    for (int k1 = 1; k1 < 8; ++k1) tA[k1] = wlookup(trig, L * k1);
#pragma unroll
    for (int m1 = 1; m1 < 8; ++m1) tB[m1] = wlookup(trig, 8 * (L & 7) * m1);

    // --- transpose predicates (loop-invariant; land in SGPR masks) ---
    const bool b0 = (L & 1) != 0;
    const bool b1 = (L & 2) != 0;
    const bool b2 = (L & 4) != 0;
    const bool b3 = (L & 8) != 0;

    // Hermitian fold phase for row prow, sensor col u:
    //   prow==0 -> 1 ; prow==256 -> (-1)^u ; prow==257 -> 0 ; else 2*W512^{prow*u}
    auto phase = [&](int prow, int u) -> v2f {
        if (prow == 0)   return v2f{1.0f, 0.0f};
        if (prow == 256) return v2f{(u & 1) ? -1.0f : 1.0f, 0.0f};
        if (prow == 257) return v2f{0.0f, 0.0f};
        return 2.0f * wlookup(trig, prow * u);
    };
    auto senspos = [&](int v) -> int {
        // published regs are v>>6 in {2..5} at lane-local offsets 0,8,16,24
        return ((v & 7) * 8 + ((v >> 3) & 7)) * 80 + ((v >> 6) * 8 - 16);
    };

    // --- gather constants, split by role ---
    const bool lowRole = tid < 256;
    int sposA = 0, sposB = 0;           // low: own sensor (sposA). high: two sensors.
    v2f ph0{0,0}, ph1{0,0}, ph2{0,0}, ph3{0,0};   // low: rows 0-3. high: {r4 s0, r5 s0, r4 s1, r5 s1}
    if (lowRole) {
        int u = idx0[tid];
        int v = idx1[tid];
        sposA = senspos(v);
        ph0 = phase(g * RPB + 0, u);
        ph1 = phase(g * RPB + 1, u);
        ph2 = phase(g * RPB + 2, u);
        ph3 = phase(g * RPB + 3, u);
    } else {
        int t2 = tid - 256;             // 0..127
        int j0 = 2 * t2, j1 = 2 * t2 + 1;
        int u0 = idx0[j0], v0 = idx1[j0];
        int u1 = idx0[j1], v1 = idx1[j1];
        sposA = senspos(v0);
        sposB = senspos(v1);
        ph0 = phase(g * RPB + 4, u0);
        ph1 = phase(g * RPB + 5, u0);
        ph2 = phase(g * RPB + 4, u1);
        ph3 = phase(g * RPB + 5, u1);
    }

    // --- per-lane LDS publish base; parity buffer offsets 0 / 32 within the pitch-80 slot ---
    char* myA    = waveMem + w * WREG;
    char* awBase = myA + L * 80;

    // --- load state + filter into registers ---
    v2f a[8], bb[8];
    float C[8];
    {
        const size_t rowBase = ((size_t)b * NOUT + p) * NOUT;
        const float* filRow = fil + (size_t)p * NOUT;
#pragma unroll
        for (int r = 0; r < 8; ++r) {
            int e = r * 64 + L;
            float2 a0 = stateCur[rowBase + e];
            a[r] = v2f{a0.x, a0.y};
            if (firstChunk) {
                bb[r] = a[r];
            } else {
                float2 a1 = statePrev[rowBase + e];
                bb[r] = v2f{a1.x, a1.y};
            }
            C[r] = fmaf(-4.0f, filRow[e], 2.0f);
        }
    }

    float* pOut = partial + ((size_t)g * Tc * NB + b) * NPHI + tid;   // valid store addr: tid<256
    float* pPrevB = pOut;      // (re)set each iter; guarded by tl>0 before first use
    float g03A = 0.0f, g03B = 0.0f;

    for (int tl = 0; tl < Tc; tl += 2) {
        // step A (parity 0): bb becomes A_{t+1}
#pragma unroll
        for (int r = 0; r < 8; ++r) bb[r] = v2f{C[r], C[r]} * a[r] - bb[r];
        fft_publish(bb, tA, tB, b0, b1, b2, b3, awBase);
        __syncthreads();   // barrier alpha: buf0 visible; prev epoch's buf1 gathers done
        if (lowRole) {
            const char* pb = waveMem + sposA;
            v2f q0 = *(const v2f*)(pb + 0 * WREG);
            v2f q1 = *(const v2f*)(pb + 1 * WREG);
            v2f q2 = *(const v2f*)(pb + 2 * WREG);
            v2f q3 = *(const v2f*)(pb + 3 * WREG);
            float acc = q0.x * ph0.x - q0.y * ph0.y;
            acc = fmaf(q1.x, ph1.x, fmaf(-q1.y, ph1.y, acc));
            acc = fmaf(q2.x, ph2.x, fmaf(-q2.y, ph2.y, acc));
            acc = fmaf(q3.x, ph3.x, fmaf(-q3.y, ph3.y, acc));
            if (tl > 0) pPrevB[0] = g03B + pr45[1][tid];   // finish prev iter's step B
            g03A = acc;
        } else {
            const char* pb = waveMem;
            v2f q4a = *(const v2f*)(pb + 4 * WREG + sposA);
            v2f q5a = *(const v2f*)(pb + 5 * WREG + sposA);
            v2f q4b = *(const v2f*)(pb + 4 * WREG + sposB);
            v2f q5b = *(const v2f*)(pb + 5 * WREG + sposB);
            float s0 = q4a.x * ph0.x - q4a.y * ph0.y;
            s0 = fmaf(q5a.x, ph1.x, fmaf(-q5a.y, ph1.y, s0));
            float s1 = q4b.x * ph2.x - q4b.y * ph2.y;
            s1 = fmaf(q5b.x, ph3.x, fmaf(-q5b.y, ph3.y, s1));
            *(v2f*)&pr45[0][2 * (tid - 256)] = v2f{s0, s1};
        }
        // step B (parity 1): a becomes A_{t+2}
#pragma unroll
        for (int r = 0; r < 8; ++r) a[r] = v2f{C[r], C[r]} * bb[r] - a[r];
        fft_publish(a, tA, tB, b0, b1, b2, b3, awBase + 32);
        __syncthreads();   // barrier beta: buf1 visible; buf0 gathers + pr45[0] writes done
        if (lowRole) {
            const char* pb = waveMem + 32 + sposA;
            v2f q0 = *(const v2f*)(pb + 0 * WREG);
            v2f q1 = *(const v2f*)(pb + 1 * WREG);
            v2f q2 = *(const v2f*)(pb + 2 * WREG);
            v2f q3 = *(const v2f*)(pb + 3 * WREG);
            float acc = q0.x * ph0.x - q0.y * ph0.y;
            acc = fmaf(q1.x, ph1.x, fmaf(-q1.y, ph1.y, acc));
            acc = fmaf(q2.x, ph2.x, fmaf(-q2.y, ph2.y, acc));
            acc = fmaf(q3.x, ph3.x, fmaf(-q3.y, ph3.y, acc));
            pOut[0] = g03A + pr45[0][tid];                  // finish this iter's step A
            g03B = acc;
        } else {
            const char* pb = waveMem + 32;
            v2f q4a = *(const v2f*)(pb + 4 * WREG + sposA);
            v2f q5a = *(const v2f*)(pb + 5 * WREG + sposA);
            v2f q4b = *(const v2f*)(pb + 4 * WREG + sposB);
            v2f q5b = *(const v2f*)(pb + 5 * WREG + sposB);
            float s0 = q4a.x * ph0.x - q4a.y * ph0.y;
            s0 = fmaf(q5a.x, ph1.x, fmaf(-q5a.y, ph1.y, s0));
            float s1 = q4b.x * ph2.x - q4b.y * ph2.y;
            s1 = fmaf(q5b.x, ph3.x, fmaf(-q5b.y, ph3.y, s1));
            *(v2f*)&pr45[1][2 * (tid - 256)] = v2f{s0, s1};
        }
        pPrevB = pOut + NB * NPHI;        // where this iter's step B result goes
        pOut += 2 * NB * NPHI;
    }
    // flush the final step B (pr45[1] written post-beta; ordered by this barrier)
    __syncthreads();
    if (lowRole) pPrevB[0] = g03B + pr45[1][tid];

    // --- save state for the next chunk (skipped when this is the last chunk) ---
    if (!lastChunk) {
        const size_t rowBase = ((size_t)b * NOUT + p) * NOUT;
#pragma unroll
        for (int r = 0; r < 8; ++r) {
            int e = r * 64 + L;
            stateCur[rowBase + e]  = make_float2(a[r].x, a[r].y);
            statePrev[rowBase + e] = make_float2(bb[r].x, bb[r].y);
        }
    }
}

// ---------------- reduce NGRP row-group partials -> out[b][j][t] ----------------------------------
__global__ __launch_bounds__(256) void reduce_kernel(const float* __restrict__ partial,
                                                     float* __restrict__ out,
                                                     int Tc, int tStart) {
    int id = blockIdx.x * 256 + threadIdx.x;   // over Tc*16*256, exact
    int j = id & 255;
    int b = (id >> 8) & 15;
    int tl = id >> 12;
    float s = 0.0f;
#pragma unroll
    for (int gg = 0; gg < NGRP; ++gg)
        s += partial[(((size_t)gg * Tc + tl) * NB + b) * NPHI + j];
    out[((size_t)b * NPHI + j) * NT + (tStart + tl)] = s * (1.0f / (512.0f * 512.0f));
}

extern "C" void kernel_launch(void* const* d_in, const int* in_sizes, int n_in,
                              void* d_out, int out_size, void* d_ws, size_t ws_size,
                              hipStream_t stream) {
    (void)in_sizes; (void)n_in; (void)out_size;
    const float* f   = (const float*)d_in[0];   // [16,1,256,256]
    const float* fil = (const float*)d_in[1];   // [512,512]
    const int* idx0  = (const int*)d_in[2];     // [256]
    const int* idx1  = (const int*)d_in[3];     // [256]
    float* out = (float*)d_out;                 // [16,1,256,240]

    char* ws = (char*)d_ws;
    const size_t stateBytes = (size_t)NB * NOUT * NOUT * sizeof(float2);  // 33.55 MB
    float2* stateCur  = (float2*)ws;
    float2* statePrev = (float2*)(ws + stateBytes);   // also reused as R scratch for f1/f2
    float*  partial   = (float*)(ws + 2 * stateBytes);
    size_t remain = (ws_size > 2 * stateBytes) ? ws_size - 2 * stateBytes : 0;

    // largest even time chunk whose partial buffer fits (even: the sim loop is 2-step unrolled)
    static const int tcs[] = {240, 120, 80, 60, 48, 40, 30, 24, 20, 16, 12, 10, 8, 6, 4, 2};
    int Tc = 2;
    for (int i = 0; i < 16; ++i) {
        size_t need = (size_t)NGRP * tcs[i] * NB * NPHI * sizeof(float);
        if (need <= remain) { Tc = tcs[i]; break; }
    }

    // no memset: f1 writes rows [128,384) of the R scratch; f2 skips the rest as known-zero
    f1_kernel<<<dim3(64, NB), 256, 0, stream>>>(f, statePrev);        // rows x in [128,384)
    f2_kernel<<<dim3(128, NB), 256, 0, stream>>>(statePrev, stateCur);
    for (int t0 = 0; t0 < NT; t0 += Tc) {
        int last = (t0 + Tc) >= NT ? 1 : 0;
        sim_kernel<<<dim3(NGRP, NB), RPB * 64, 0, stream>>>(fil, idx0, idx1, stateCur, statePrev,
                                                            partial, Tc, t0 == 0 ? 1 : 0, last);
        reduce_kernel<<<dim3(Tc * NB), 256, 0, stream>>>(partial, out, Tc, t0);
    }
}

// Round 7
// 931.334 us; speedup vs baseline: 1.1773x; 1.0921x over previous
//
#include <hip/hip_runtime.h>
#include <hip/hip_bf16.h>

// WaveOperator: Fourier-domain 3-term recurrence + per-row inverse FFT sampling.
// A_{t+1}(p,q) = (2-4*fil(p,q)) * A_t - A_{t-1};  y[b,j,t] = Re(ifft2(A_{t+1})[u_j,v_j])
// R23 = R19 (proven 906us sim / 950us total) + the two REGISTER-NEUTRAL exchange rewrites
// from R21, de-confounded from R21's twiddle-precompute (which spilled: FETCH 11.5->17GB).
//  1. xor8 exchange via __builtin_amdgcn_update_dpp merge (row_ror:8, bank_mask 0xC/0x3):
//     4 instr/exchange, no cndmasks.
//  2. xor1/xor2/xor4 exchanges in shuffle-first select-last form (a' = bit ? dpp(b) : a) so
//     GCNDPPCombine can fuse mov_dpp into v_cndmask_b32_dpp; never worse than R19's form.
// Both forms' routing is HW-validated (R21 passed with identical absmax).
// History: R20 dual-FFT ILP and R21 twiddle arrays both died on the allocator (pins VGPR=64,
// spills any added live state); R22 balanced-gather lengthened the inter-barrier critical
// path (sim 964). Only register-neutral instruction cuts remain viable.

#define NOUT 512
#define NB 16
#define NPHI 256
#define NT 240
#define RPB 6             // rows per block (= waves per block)
#define NGRP 43           // row groups: 43*6 = 258 = rows 0..257 (257 gets zero phase)

#define WREG 5184         // per-wave LDS publish region (pitch 80; lane uses 2x32B parity bufs)

typedef float v2f __attribute__((ext_vector_type(2)));
typedef float v4f __attribute__((ext_vector_type(4)));
typedef unsigned int v2u __attribute__((ext_vector_type(2)));

__device__ __forceinline__ v2f cmulv(v2f a, v2f b) {
    return v2f{fmaf(a.x, b.x, -a.y * b.y), fmaf(a.x, b.y, a.y * b.x)};
}
__device__ __forceinline__ v2f cmuliv(v2f a) { return v2f{-a.y, a.x}; }
__device__ __forceinline__ v2f cmulw8v(v2f a) {
    const float s = 0.70710678118654752f; return v2f{s * (a.x - a.y), s * (a.x + a.y)};
}
__device__ __forceinline__ v2f cmulw83v(v2f a) {
    const float s = 0.70710678118654752f; return v2f{-s * (a.x + a.y), s * (a.x - a.y)};
}

// 8-pt DFT, positive exponent: Y[k] = sum_r y[r] * exp(+2pi i rk/8)
__device__ __forceinline__ void dft8p(const v2f y[8], v2f Y[8]) {
    v2f t0 = y[0] + y[4], t4 = y[0] - y[4];
    v2f t1 = y[1] + y[5], t5 = cmulw8v(y[1] - y[5]);
    v2f t2 = y[2] + y[6], t6 = cmuliv(y[2] - y[6]);
    v2f t3 = y[3] + y[7], t7 = cmulw83v(y[3] - y[7]);
    v2f u0 = t0 + t2, u2 = t0 - t2;
    v2f u1 = t1 + t3, u3 = cmuliv(t1 - t3);
    Y[0] = u0 + u1; Y[4] = u0 - u1;
    Y[2] = u2 + u3; Y[6] = u2 - u3;
    v2f v0 = t4 + t6, v2 = t4 - t6;
    v2f v1 = t5 + t7, v3 = cmuliv(t5 - t7);
    Y[1] = v0 + v1; Y[5] = v0 - v1;
    Y[3] = v2 + v3; Y[7] = v2 - v3;
}

// in-place variant (t-layer fully buffers the inputs before any write)
__device__ __forceinline__ void dft8p_ip(v2f y[8]) {
    v2f t0 = y[0] + y[4], t4 = y[0] - y[4];
    v2f t1 = y[1] + y[5], t5 = cmulw8v(y[1] - y[5]);
    v2f t2 = y[2] + y[6], t6 = cmuliv(y[2] - y[6]);
    v2f t3 = y[3] + y[7], t7 = cmulw83v(y[3] - y[7]);
    v2f u0 = t0 + t2, u2 = t0 - t2;
    v2f u1 = t1 + t3, u3 = cmuliv(t1 - t3);
    y[0] = u0 + u1; y[4] = u0 - u1;
    y[2] = u2 + u3; y[6] = u2 - u3;
    v2f v0 = t4 + t6, v2 = t4 - t6;
    v2f v1 = t5 + t7, v3 = cmuliv(t5 - t7);
    y[1] = v0 + v1; y[5] = v0 - v1;
    y[3] = v2 + v3; y[7] = v2 - v3;
}

// final-layer DFT producing only outputs Y2,Y3,Y4,Y5 (the sensor v>>6 range)
__device__ __forceinline__ void dft8p_mid4(const v2f y[8], v2f o[4]) {
    v2f t0 = y[0] + y[4], t4 = y[0] - y[4];
    v2f t1 = y[1] + y[5], t5 = cmulw8v(y[1] - y[5]);
    v2f t2 = y[2] + y[6], t6 = cmuliv(y[2] - y[6]);
    v2f t3 = y[3] + y[7], t7 = cmulw83v(y[3] - y[7]);
    v2f u0 = t0 + t2, u2 = t0 - t2;
    v2f u1 = t1 + t3, u3 = cmuliv(t1 - t3);
    v2f w0 = t4 + t6, w2 = t4 - t6;
    v2f w1 = t5 + t7, w3 = cmuliv(t5 - t7);
    o[0] = u2 + u3;    // Y2
    o[1] = w2 + w3;    // Y3
    o[2] = u0 - u1;    // Y4
    o[3] = w0 - w1;    // Y5
}

// W512^m from half-table
__device__ __forceinline__ v2f wlookup(const float2* trig, int m) {
    m &= 511;
    float2 ph = trig[m & 255];
    return (m & 256) ? v2f{-ph.x, -ph.y} : v2f{ph.x, ph.y};
}

// ---- in-register lane exchanges (transpose building blocks) -------------------------------------
template<int CTRL>
__device__ __forceinline__ float dppx(float x) {
    return __int_as_float(__builtin_amdgcn_mov_dpp(__float_as_int(x), CTRL, 0xF, 0xF, true));
}
__device__ __forceinline__ float swzx4(float x) {
    // BitMode swizzle: and=0x1F, or=0, xor=4  -> lane ^ 4
    return __int_as_float(__builtin_amdgcn_ds_swizzle(__float_as_int(x), 0x101F));
}

// xor1/xor2 exchange: unconditional DPP shuffles, select-last (fusable into cndmask_dpp).
// a' = bit ? b[^m] : a ; b' = bit ? b : a[^m]   (identical routing to R19's form)
template<int CTRL>
__device__ __forceinline__ void xchg_dpp(v2f& a, v2f& b, bool bit) {
    float dbx = dppx<CTRL>(b.x);
    float dby = dppx<CTRL>(b.y);
    float dax = dppx<CTRL>(a.x);
    float day = dppx<CTRL>(a.y);
    a.x = bit ? dbx : a.x;   a.y = bit ? dby : a.y;
    b.x = bit ? b.x : dax;   b.y = bit ? b.y : day;
}
// xor4 exchange via ds_swizzle, same select-last form
__device__ __forceinline__ void xchg_swz4(v2f& a, v2f& b, bool bit) {
    float dbx = swzx4(b.x);
    float dby = swzx4(b.y);
    float dax = swzx4(a.x);
    float day = swzx4(a.y);
    a.x = bit ? dbx : a.x;   a.y = bit ? dby : a.y;
    b.x = bit ? b.x : dax;   b.y = bit ? b.y : day;
}

// xor8 exchange via masked-merge DPP: row_ror:8 == lane^8 within each 16-lane row;
// bank_mask 0xC writes only lanes with (lane&8)!=0, 0x3 only (lane&8)==0. No cndmasks.
#if __has_builtin(__builtin_amdgcn_update_dpp)
__device__ __forceinline__ void xchg8(v2f& a, v2f& b, bool /*bit*/) {
    int ax = __float_as_int(a.x), ay = __float_as_int(a.y);
    int bx = __float_as_int(b.x), by = __float_as_int(b.y);
    a.x = __int_as_float(__builtin_amdgcn_update_dpp(ax, bx, 0x128, 0xF, 0xC, false));
    a.y = __int_as_float(__builtin_amdgcn_update_dpp(ay, by, 0x128, 0xF, 0xC, false));
    b.x = __int_as_float(__builtin_amdgcn_update_dpp(bx, ax, 0x128, 0xF, 0x3, false));
    b.y = __int_as_float(__builtin_amdgcn_update_dpp(by, ay, 0x128, 0xF, 0x3, false));
}
#else
__device__ __forceinline__ void xchg8(v2f& a, v2f& b, bool bit) {
    xchg_dpp<0x128>(a, b, bit);
}
#endif

#if __has_builtin(__builtin_amdgcn_permlane16_swap)
__device__ __forceinline__ void pl16x(v2f& a, v2f& b) {
    v2u rx = __builtin_amdgcn_permlane16_swap(__float_as_uint(a.x), __float_as_uint(b.x), false, false);
    a.x = __uint_as_float(rx.x); b.x = __uint_as_float(rx.y);
    v2u ry = __builtin_amdgcn_permlane16_swap(__float_as_uint(a.y), __float_as_uint(b.y), false, false);
    a.y = __uint_as_float(ry.x); b.y = __uint_as_float(ry.y);
}
#else
__device__ __forceinline__ void pl16x(v2f& a, v2f& b) {
    bool bit = (threadIdx.x & 16) != 0;
    float sx = bit ? a.x : b.x, sy = bit ? a.y : b.y;
    float tx = __shfl_xor(sx, 16), ty = __shfl_xor(sy, 16);
    a.x = bit ? tx : a.x; a.y = bit ? ty : a.y;
    b.x = bit ? b.x : tx; b.y = bit ? b.y : ty;
}
#endif

#if __has_builtin(__builtin_amdgcn_permlane32_swap)
__device__ __forceinline__ void pl32x(v2f& a, v2f& b) {
    v2u rx = __builtin_amdgcn_permlane32_swap(__float_as_uint(a.x), __float_as_uint(b.x), false, false);
    a.x = __uint_as_float(rx.x); b.x = __uint_as_float(rx.y);
    v2u ry = __builtin_amdgcn_permlane32_swap(__float_as_uint(a.y), __float_as_uint(b.y), false, false);
    a.y = __uint_as_float(ry.x); b.y = __uint_as_float(ry.y);
}
#else
__device__ __forceinline__ void pl32x(v2f& a, v2f& b) {
    bool bit = (threadIdx.x & 32) != 0;
    float sx = bit ? a.x : b.x, sy = bit ? a.y : b.y;
    float tx = __shfl_xor(sx, 32), ty = __shfl_xor(sy, 32);
    a.x = bit ? tx : a.x; a.y = bit ? ty : a.y;
    b.x = bit ? b.x : tx; b.y = bit ? b.y : ty;
}
#endif

// hot-loop step: in-register 512-pt inverse DFT (8x8x8 four-step; transposes via
// permlane/DPP/swizzle), publish G2..G5 to this step's parity buffer, ONE barrier, gather.
// awBase/ldsBase carry the parity offset (0 or 32) folded in by the caller.
__device__ __forceinline__ void fft_sample(
    const v2f y[8], const v2f tA[8], const v2f tB[8],
    bool b0, bool b1, bool b2, bool b3,
    char* awBase, const char* ldsBase, int spos, const v2f ph[RPB], bool active,
    float* pA)
{
    v2f G[8];
    dft8p(y, G);                                   // DFT over q2 (reg digit) -> v0
#pragma unroll
    for (int k1 = 1; k1 < 8; ++k1) G[k1] = cmulv(G[k1], tA[k1]);   // W512^{L*v0}
    // T1: reg digit (v0) <-> lane-high digit (q1)
    xchg8(G[0], G[1], b3);  xchg8(G[2], G[3], b3);                       // xor8 (merge-DPP)
    xchg8(G[4], G[5], b3);  xchg8(G[6], G[7], b3);
    pl16x(G[0], G[2]);  pl16x(G[1], G[3]);  pl16x(G[4], G[6]);  pl16x(G[5], G[7]);   // xor16
    pl32x(G[0], G[4]);  pl32x(G[1], G[5]);  pl32x(G[2], G[6]);  pl32x(G[3], G[7]);   // xor32
    dft8p_ip(G);                                   // DFT over q1 -> v1
#pragma unroll
    for (int m1 = 1; m1 < 8; ++m1) G[m1] = cmulv(G[m1], tB[m1]);   // W512^{8*q0*v1}
    // T2: reg digit (v1) <-> lane-low digit (q0)
    xchg_dpp<0xB1>(G[0], G[1], b0);  xchg_dpp<0xB1>(G[2], G[3], b0);     // quad_perm xor1
    xchg_dpp<0xB1>(G[4], G[5], b0);  xchg_dpp<0xB1>(G[6], G[7], b0);
    xchg_dpp<0x4E>(G[0], G[2], b1);  xchg_dpp<0x4E>(G[1], G[3], b1);     // quad_perm xor2
    xchg_dpp<0x4E>(G[4], G[6], b1);  xchg_dpp<0x4E>(G[5], G[7], b1);
    xchg_swz4(G[0], G[4], b2);  xchg_swz4(G[1], G[5], b2);               // ds_swizzle xor4
    xchg_swz4(G[2], G[6], b2);  xchg_swz4(G[3], G[7], b2);
    v2f o[4];
    dft8p_mid4(G, o);                              // DFT over q0 -> v2 (only outputs 2..5)
    *(v4f*)(awBase +  0) = v4f{o[0].x, o[0].y, o[1].x, o[1].y};   // G2,G3
    *(v4f*)(awBase + 16) = v4f{o[2].x, o[2].y, o[3].x, o[3].y};   // G4,G5
    __syncthreads();   // single barrier: publish visible; orders prev gather vs buffer reuse
    if (active) {
        float acc = 0.0f;
#pragma unroll
        for (int ww = 0; ww < RPB; ++ww) {
            v2f q = *(const v2f*)(ldsBase + ww * WREG + spos);
            acc = fmaf(q.x, ph[ww].x, fmaf(-q.y, ph[ww].y, acc));
        }
        pA[0] = acc;
    }
}

// ---------------- init kernels (run once, shuffle FFT) -------------------------------------------
__device__ __forceinline__ void cbfly(float& ar, float& ai, float& br, float& bi,
                                      float wr, float wi) {
    float dr = ar - br, di = ai - bi;
    ar = ar + br; ai = ai + bi;
    br = fmaf(dr, wr, -di * wi);
    bi = fmaf(dr, wi,  di * wr);
}

__device__ __forceinline__ void init_trig(float2* trig, int tid) {
    if (tid < 256) {
        float ang = (float)tid * (6.283185307179586f / 512.0f);
        float s, c;
        sincosf(ang, &s, &c);
        trig[tid] = make_float2(c, s);
    }
}

__device__ __forceinline__ void fft512_inv_lds(float* xr, float* xi, const float2* trig, int L) {
#pragma unroll
    for (int r = 0; r < 4; ++r) {
        float2 w = trig[(r << 6) + L];
        cbfly(xr[r], xi[r], xr[r + 4], xi[r + 4], w.x, w.y);
    }
    {
        float2 w0 = trig[L << 1];
        float2 w1 = trig[(64 + L) << 1];
        cbfly(xr[0], xi[0], xr[2], xi[2], w0.x, w0.y);
        cbfly(xr[1], xi[1], xr[3], xi[3], w1.x, w1.y);
        cbfly(xr[4], xi[4], xr[6], xi[6], w0.x, w0.y);
        cbfly(xr[5], xi[5], xr[7], xi[7], w1.x, w1.y);
    }
    {
        float2 w = trig[L << 2];
        cbfly(xr[0], xi[0], xr[1], xi[1], w.x, w.y);
        cbfly(xr[2], xi[2], xr[3], xi[3], w.x, w.y);
        cbfly(xr[4], xi[4], xr[5], xi[5], w.x, w.y);
        cbfly(xr[6], xi[6], xr[7], xi[7], w.x, w.y);
    }
#pragma unroll
    for (int s = 3; s <= 8; ++s) {
        const int half = 512 >> (s + 1);
        const int ex = (L & (half - 1)) << s;
        float2 w = trig[ex];
        const bool hi = (L & half) != 0;
        float wr = hi ? w.x : 1.0f;
        float wi = hi ? w.y : 0.0f;
        float sg = hi ? -1.0f : 1.0f;
#pragma unroll
        for (int r = 0; r < 8; ++r) {
            float orv = __shfl_xor(xr[r], half);
            float oiv = __shfl_xor(xi[r], half);
            float tr = fmaf(sg, xr[r], orv);
            float ti = fmaf(sg, xi[r], oiv);
            xr[r] = fmaf(tr, wr, -ti * wi);
            xi[r] = fmaf(tr, wi,  ti * wr);
        }
    }
}

__global__ __launch_bounds__(256) void f1_kernel(const float* __restrict__ f,
                                                 float2* __restrict__ R) {
    __shared__ float2 trig[256];
    const int tid = threadIdx.x;
    init_trig(trig, tid);
    __syncthreads();
    const int w = tid >> 6, L = tid & 63;
    const int x = 128 + blockIdx.x * 4 + w;   // nonzero rows only: [128, 384)
    const int b = blockIdx.y;
    const float* frow = f + ((size_t)b * 256 + (x - 128)) * 256;
    float xr[8], xi[8];
#pragma unroll
    for (int r = 0; r < 8; ++r) {
        int e = r * 64 + L;
        xr[r] = (e >= 128 && e < 384) ? frow[e - 128] : 0.0f;
        xi[r] = 0.0f;
    }
    fft512_inv_lds(xr, xi, trig, L);
    float2* Rrow = R + ((size_t)b * NOUT + x) * NOUT;
#pragma unroll
    for (int r = 0; r < 8; ++r) {
        int e = r * 64 + L;
        int k = __brev((unsigned)e) >> 23;
        Rrow[k] = make_float2(xr[r], -xi[r]);
    }
}

// f2: rows x outside [128,384) of R were never written (and are not zeroed) — treat as 0.
// e = r*64 + L is in [128,384) exactly for r in [2,6).
__global__ __launch_bounds__(256) void f2_kernel(const float2* __restrict__ R,
                                                 float2* __restrict__ A0) {
    __shared__ float2 trig[256];
    const int tid = threadIdx.x;
    init_trig(trig, tid);
    __syncthreads();
    const int w = tid >> 6, L = tid & 63;
    const int q = blockIdx.x * 4 + w;
    const int b = blockIdx.y;
    float xr[8], xi[8];
#pragma unroll
    for (int r = 0; r < 8; ++r) {
        if (r >= 2 && r < 6) {
            int e = r * 64 + L;
            float2 v = R[((size_t)b * NOUT + e) * NOUT + q];
            xr[r] = v.x;
            xi[r] = -v.y;
        } else {
            xr[r] = 0.0f;
            xi[r] = 0.0f;
        }
    }
    fft512_inv_lds(xr, xi, trig, L);
#pragma unroll
    for (int r = 0; r < 8; ++r) {
        int e = r * 64 + L;
        int p = __brev((unsigned)e) >> 23;
        A0[((size_t)b * NOUT + p) * NOUT + q] = make_float2(xr[r], -xi[r]);
    }
}

// ---------------- time-chunk simulation ----------------------------------------------------------
// block = (row group g of RPB rows, batch b); wave w owns row p = RPB*g + w, p in 0..257.
// Threads 0..255 each own one sensor, summing the block's RPB rows after the step barrier.
__global__ __launch_bounds__(384, 4) void sim_kernel(
    const float* __restrict__ fil,
    const int* __restrict__ idx0, const int* __restrict__ idx1,
    float2* __restrict__ stateCur, float2* __restrict__ statePrev,
    float* __restrict__ partial, int Tc, int firstChunk, int lastChunk)
{
    __shared__ __align__(16) char waveMem[RPB * WREG];   // 31104 B
    __shared__ float2 trig[256];                         //  2048 B -> 33152 B total

    const int tid = threadIdx.x;              // 0..383
    const int w = tid >> 6, L = tid & 63;
    const int g = blockIdx.x, b = blockIdx.y;
    const int p = g * RPB + w;                // 0..257

    if (tid < 256) {
        float ang = (float)tid * (6.283185307179586f / 512.0f);
        float s, c;
        sincosf(ang, &s, &c);
        trig[tid] = make_float2(c, s);
    }
    __syncthreads();

    // --- per-lane constant twiddles ---
    v2f tA[8], tB[8];
#pragma unroll
    for (int k1 = 1; k1 < 8; ++k1) tA[k1] = wlookup(trig, L * k1);
#pragma unroll
    for (int m1 = 1; m1 < 8; ++m1) tB[m1] = wlookup(trig, 8 * (L & 7) * m1);

    // --- transpose predicates (loop-invariant; land in SGPR masks) ---
    const bool b0 = (L & 1) != 0;
    const bool b1 = (L & 2) != 0;
    const bool b2 = (L & 4) != 0;
    const bool b3 = (L & 8) != 0;

    // --- sensor constants: thread tid<256 owns sensor j=tid ---
    const bool active = tid < 256;
    int spos = 0;
    v2f ph[RPB];
    if (active) {
        int u = idx0[tid];
        int v = idx1[tid];
        // published regs are v>>6 in {2..5} at lane-local offsets 0,8,16,24 (parity 0)
        spos = ((v & 7) * 8 + ((v >> 3) & 7)) * 80 + ((v >> 6) * 8 - 16);
        // Hermitian fold phase: p==0 -> 1, p==256 -> (-1)^u, p==257 -> 0, else 2*W512^{pu}
#pragma unroll
        for (int ww = 0; ww < RPB; ++ww) {
            int prow = g * RPB + ww;
            v2f a0;
            if (prow == 0)        a0 = v2f{1.0f, 0.0f};
            else if (prow == 256) a0 = v2f{(u & 1) ? -1.0f : 1.0f, 0.0f};
            else if (prow == 257) a0 = v2f{0.0f, 0.0f};
            else                  a0 = 2.0f * wlookup(trig, prow * u);
            ph[ww] = a0;
        }
    } else {
#pragma unroll
        for (int ww = 0; ww < RPB; ++ww) ph[ww] = v2f{0.0f, 0.0f};
    }

    // --- per-lane LDS publish base; parity buffer offsets 0 / 32 within the pitch-80 slot ---
    char* myA    = waveMem + w * WREG;
    char* awBase = myA + L * 80;

    // --- load state + filter into registers ---
    v2f a[8], bb[8];
    float C[8];
    {
        const size_t rowBase = ((size_t)b * NOUT + p) * NOUT;
        const float* filRow = fil + (size_t)p * NOUT;
#pragma unroll
        for (int r = 0; r < 8; ++r) {
            int e = r * 64 + L;
            float2 a0 = stateCur[rowBase + e];
            a[r] = v2f{a0.x, a0.y};
            if (firstChunk) {
                bb[r] = a[r];
            } else {
                float2 a1 = statePrev[rowBase + e];
                bb[r] = v2f{a1.x, a1.y};
            }
            C[r] = fmaf(-4.0f, filRow[e], 2.0f);
        }
    }

    float* pOut = partial + ((size_t)g * Tc * NB + b) * NPHI + tid;

    for (int tl = 0; tl < Tc; tl += 2) {
        // step A (parity 0): bb becomes A_{t+1}
#pragma unroll
        for (int r = 0; r < 8; ++r) bb[r] = v2f{C[r], C[r]} * a[r] - bb[r];
        fft_sample(bb, tA, tB, b0, b1, b2, b3, awBase, waveMem,
                   spos, ph, active, pOut);
        pOut += NB * NPHI;
        // step B (parity 1): a becomes A_{t+2}
#pragma unroll
        for (int r = 0; r < 8; ++r) a[r] = v2f{C[r], C[r]} * bb[r] - a[r];
        fft_sample(a, tA, tB, b0, b1, b2, b3, awBase + 32, waveMem + 32,
                   spos, ph, active, pOut);
        pOut += NB * NPHI;
    }

    // --- save state for the next chunk (skipped when this is the last chunk) ---
    if (!lastChunk) {
        const size_t rowBase = ((size_t)b * NOUT + p) * NOUT;
#pragma unroll
        for (int r = 0; r < 8; ++r) {
            int e = r * 64 + L;
            stateCur[rowBase + e]  = make_float2(a[r].x, a[r].y);
            statePrev[rowBase + e] = make_float2(bb[r].x, bb[r].y);
        }
    }
}

// ---------------- reduce NGRP row-group partials -> out[b][j][t] ----------------------------------
__global__ __launch_bounds__(256) void reduce_kernel(const float* __restrict__ partial,
                                                     float* __restrict__ out,
                                                     int Tc, int tStart) {
    int id = blockIdx.x * 256 + threadIdx.x;   // over Tc*16*256, exact
    int j = id & 255;
    int b = (id >> 8) & 15;
    int tl = id >> 12;
    float s = 0.0f;
#pragma unroll
    for (int gg = 0; gg < NGRP; ++gg)
        s += partial[(((size_t)gg * Tc + tl) * NB + b) * NPHI + j];
    out[((size_t)b * NPHI + j) * NT + (tStart + tl)] = s * (1.0f / (512.0f * 512.0f));
}

extern "C" void kernel_launch(void* const* d_in, const int* in_sizes, int n_in,
                              void* d_out, int out_size, void* d_ws, size_t ws_size,
                              hipStream_t stream) {
    (void)in_sizes; (void)n_in; (void)out_size;
    const float* f   = (const float*)d_in[0];   // [16,1,256,256]
    const float* fil = (const float*)d_in[1];   // [512,512]
    const int* idx0  = (const int*)d_in[2];     // [256]
    const int* idx1  = (const int*)d_in[3];     // [256]
    float* out = (float*)d_out;                 // [16,1,256,240]

    char* ws = (char*)d_ws;
    const size_t stateBytes = (size_t)NB * NOUT * NOUT * sizeof(float2);  // 33.55 MB
    float2* stateCur  = (float2*)ws;
    float2* statePrev = (float2*)(ws + stateBytes);   // also reused as R scratch for f1/f2
    float*  partial   = (float*)(ws + 2 * stateBytes);
    size_t remain = (ws_size > 2 * stateBytes) ? ws_size - 2 * stateBytes : 0;

    // largest even time chunk whose partial buffer fits (even: the sim loop is 2-step unrolled)
    static const int tcs[] = {240, 120, 80, 60, 48, 40, 30, 24, 20, 16, 12, 10, 8, 6, 4, 2};
    int Tc = 2;
    for (int i = 0; i < 16; ++i) {
        size_t need = (size_t)NGRP * tcs[i] * NB * NPHI * sizeof(float);
        if (need <= remain) { Tc = tcs[i]; break; }
    }

    // no memset: f1 writes rows [128,384) of the R scratch; f2 skips the rest as known-zero
    f1_kernel<<<dim3(64, NB), 256, 0, stream>>>(f, statePrev);        // rows x in [128,384)
    f2_kernel<<<dim3(128, NB), 256, 0, stream>>>(statePrev, stateCur);
    for (int t0 = 0; t0 < NT; t0 += Tc) {
        int last = (t0 + Tc) >= NT ? 1 : 0;
        sim_kernel<<<dim3(NGRP, NB), RPB * 64, 0, stream>>>(fil, idx0, idx1, stateCur, statePrev,
                                                            partial, Tc, t0 == 0 ? 1 : 0, last);
        reduce_kernel<<<dim3(Tc * NB), 256, 0, stream>>>(partial, out, Tc, t0);
    }
}

// Round 8
// 829.054 us; speedup vs baseline: 1.3226x; 1.1234x over previous
//
#include <hip/hip_runtime.h>
#include <hip/hip_bf16.h>

// WaveOperator: Fourier-domain 3-term recurrence + per-row inverse FFT sampling.
// A_{t+1}(p,q) = (2-4*fil(p,q)) * A_t - A_{t-1};  y[b,j,t] = Re(ifft2(A_{t+1})[u_j,v_j])
// R24 = R23 (proven 873us sim / 931us total) + VOP3P packed-fp32 rewrite of the DFT and
// twiddle arithmetic. CDNA4's fp32 peak requires v_pk_*_f32 (2 ops/instr); complex butterflies
// are exactly 2-wide. The scalar-component cmulv could not be auto-vectorized (op_sel swizzle
// needed), and R21 showed precomputing swap-neg twiddle ARRAYS spills (VGPR pinned at 64).
// Zero-register fix: fold the conjugate-swap/negate into VOP3P op_sel/neg modifiers via asm:
//   cmulv       = v_pk_mul + v_pk_fma (op_sel)          4 -> 2 instr (x14 per FFT)
//   dft8p adds  = pk_add/pk_sub; x(+-i) rotations folded into pkaddi/pksubi consumers
//   w8/w83      = 1 pk combine + 2 scalar muls
//   gather      = 6 pk_fma + horizontal add (was 12 fma)
// Routing/LDS/barriers/exchanges byte-identical to R23. Reassociation within tolerance.
// History: VGPR=64 is allocator-pinned (R20/R21 spills); gather re-balance hurts (R22);
// register-neutral instruction cuts are the only working lever (R18, R23).

#define NOUT 512
#define NB 16
#define NPHI 256
#define NT 240
#define RPB 6             // rows per block (= waves per block)
#define NGRP 43           // row groups: 43*6 = 258 = rows 0..257 (257 gets zero phase)

#define WREG 5184         // per-wave LDS publish region (pitch 80; lane uses 2x32B parity bufs)

typedef float v2f __attribute__((ext_vector_type(2)));
typedef float v4f __attribute__((ext_vector_type(4)));
typedef unsigned int v2u __attribute__((ext_vector_type(2)));

// ---- VOP3P packed-fp32 primitives (register-neutral; modifiers do the swizzles) -----------------
__device__ __forceinline__ v2f pkadd(v2f a, v2f b) {
    v2f d; asm("v_pk_add_f32 %0, %1, %2" : "=v"(d) : "v"(a), "v"(b)); return d;
}
__device__ __forceinline__ v2f pksub(v2f a, v2f b) {
    v2f d; asm("v_pk_add_f32 %0, %1, %2 neg_lo:[0,1] neg_hi:[0,1]" : "=v"(d) : "v"(a), "v"(b)); return d;
}
// a + i*w = {a.x - w.y, a.y + w.x}
__device__ __forceinline__ v2f pkaddi(v2f a, v2f w) {
    v2f d; asm("v_pk_add_f32 %0, %1, %2 op_sel:[0,1] op_sel_hi:[1,0] neg_lo:[0,1]"
               : "=v"(d) : "v"(a), "v"(w)); return d;
}
// a - i*w = {a.x + w.y, a.y - w.x}
__device__ __forceinline__ v2f pksubi(v2f a, v2f w) {
    v2f d; asm("v_pk_add_f32 %0, %1, %2 op_sel:[0,1] op_sel_hi:[1,0] neg_hi:[0,1]"
               : "=v"(d) : "v"(a), "v"(w)); return d;
}
// s * {a.x - a.y, a.x + a.y}   (w8 twiddle)
__device__ __forceinline__ v2f pkw8(v2f a) {
    v2f d; asm("v_pk_add_f32 %0, %1, %1 op_sel:[0,1] op_sel_hi:[0,1] neg_lo:[0,1]"
               : "=v"(d) : "v"(a));
    const float s = 0.70710678118654752f;
    return v2f{s * d.x, s * d.y};
}
// {-s*(a.x + a.y), s*(a.x - a.y)}   (w8^3 twiddle)
__device__ __forceinline__ v2f pkw83(v2f a) {
    v2f d; asm("v_pk_add_f32 %0, %1, %1 op_sel:[0,1] op_sel_hi:[0,1] neg_hi:[0,1]"
               : "=v"(d) : "v"(a));
    const float s = 0.70710678118654752f;
    return v2f{-s * d.x, s * d.y};
}
// complex mul g*t: {g.x*t.x - g.y*t.y, g.x*t.y + g.y*t.x} in 2 VOP3P ops
__device__ __forceinline__ v2f cmulv(v2f g, v2f t) {
    v2f p, d;
    asm("v_pk_mul_f32 %0, %1, %2 op_sel:[0,0] op_sel_hi:[0,1]" : "=v"(p) : "v"(g), "v"(t));
    // p = {g.x*t.x, g.x*t.y}
    asm("v_pk_fma_f32 %0, %1, %2, %3 op_sel:[1,1,0] op_sel_hi:[1,0,1] neg_lo:[1,0,0]"
        : "=v"(d) : "v"(g), "v"(t), "v"(p));
    // d = {-g.y*t.y + p.x, g.y*t.x + p.y}
    return d;
}

// 8-pt DFT, positive exponent: Y[k] = sum_r y[r] * exp(+2pi i rk/8)  (packed form)
__device__ __forceinline__ void dft8p(const v2f y[8], v2f Y[8]) {
    v2f t0 = pkadd(y[0], y[4]), t4 = pksub(y[0], y[4]);
    v2f t1 = pkadd(y[1], y[5]), t5 = pkw8(pksub(y[1], y[5]));
    v2f t2 = pkadd(y[2], y[6]), d26 = pksub(y[2], y[6]);   // t6 = i*d26 folded into consumers
    v2f t3 = pkadd(y[3], y[7]), t7 = pkw83(pksub(y[3], y[7]));
    v2f u0 = pkadd(t0, t2), u2 = pksub(t0, t2);
    v2f u1 = pkadd(t1, t3), w13 = pksub(t1, t3);           // u3 = i*w13 folded
    Y[0] = pkadd(u0, u1); Y[4] = pksub(u0, u1);
    Y[2] = pkaddi(u2, w13); Y[6] = pksubi(u2, w13);
    v2f v0 = pkaddi(t4, d26), v2 = pksubi(t4, d26);        // t4 +- i*d26
    v2f v1 = pkadd(t5, t7), w57 = pksub(t5, t7);           // v3 = i*w57 folded
    Y[1] = pkadd(v0, v1); Y[5] = pksub(v0, v1);
    Y[3] = pkaddi(v2, w57); Y[7] = pksubi(v2, w57);
}

// in-place variant (reads of y[] only in the t-layer; all writes after) 
__device__ __forceinline__ void dft8p_ip(v2f y[8]) {
    v2f t0 = pkadd(y[0], y[4]), t4 = pksub(y[0], y[4]);
    v2f t1 = pkadd(y[1], y[5]), t5 = pkw8(pksub(y[1], y[5]));
    v2f t2 = pkadd(y[2], y[6]), d26 = pksub(y[2], y[6]);
    v2f t3 = pkadd(y[3], y[7]), t7 = pkw83(pksub(y[3], y[7]));
    v2f u0 = pkadd(t0, t2), u2 = pksub(t0, t2);
    v2f u1 = pkadd(t1, t3), w13 = pksub(t1, t3);
    y[0] = pkadd(u0, u1); y[4] = pksub(u0, u1);
    y[2] = pkaddi(u2, w13); y[6] = pksubi(u2, w13);
    v2f v0 = pkaddi(t4, d26), v2 = pksubi(t4, d26);
    v2f v1 = pkadd(t5, t7), w57 = pksub(t5, t7);
    y[1] = pkadd(v0, v1); y[5] = pksub(v0, v1);
    y[3] = pkaddi(v2, w57); y[7] = pksubi(v2, w57);
}

// final-layer DFT producing only outputs Y2,Y3,Y4,Y5 (the sensor v>>6 range)
__device__ __forceinline__ void dft8p_mid4(const v2f y[8], v2f o[4]) {
    v2f t0 = pkadd(y[0], y[4]), t4 = pksub(y[0], y[4]);
    v2f t1 = pkadd(y[1], y[5]), t5 = pkw8(pksub(y[1], y[5]));
    v2f t2 = pkadd(y[2], y[6]), d26 = pksub(y[2], y[6]);
    v2f t3 = pkadd(y[3], y[7]), t7 = pkw83(pksub(y[3], y[7]));
    v2f u0 = pkadd(t0, t2), u2 = pksub(t0, t2);
    v2f u1 = pkadd(t1, t3), w13 = pksub(t1, t3);
    v2f v0 = pkaddi(t4, d26), v2 = pksubi(t4, d26);
    v2f v1 = pkadd(t5, t7), w57 = pksub(t5, t7);
    o[0] = pkaddi(u2, w13);    // Y2
    o[1] = pkaddi(v2, w57);    // Y3
    o[2] = pksub(u0, u1);      // Y4
    o[3] = pksub(v0, v1);      // Y5
}

// W512^m from half-table
__device__ __forceinline__ v2f wlookup(const float2* trig, int m) {
    m &= 511;
    float2 ph = trig[m & 255];
    return (m & 256) ? v2f{-ph.x, -ph.y} : v2f{ph.x, ph.y};
}

// ---- in-register lane exchanges (transpose building blocks) -------------------------------------
template<int CTRL>
__device__ __forceinline__ float dppx(float x) {
    return __int_as_float(__builtin_amdgcn_mov_dpp(__float_as_int(x), CTRL, 0xF, 0xF, true));
}
__device__ __forceinline__ float swzx4(float x) {
    // BitMode swizzle: and=0x1F, or=0, xor=4  -> lane ^ 4
    return __int_as_float(__builtin_amdgcn_ds_swizzle(__float_as_int(x), 0x101F));
}

// xor1/xor2 exchange: unconditional DPP shuffles, select-last (fusable into cndmask_dpp).
template<int CTRL>
__device__ __forceinline__ void xchg_dpp(v2f& a, v2f& b, bool bit) {
    float dbx = dppx<CTRL>(b.x);
    float dby = dppx<CTRL>(b.y);
    float dax = dppx<CTRL>(a.x);
    float day = dppx<CTRL>(a.y);
    a.x = bit ? dbx : a.x;   a.y = bit ? dby : a.y;
    b.x = bit ? b.x : dax;   b.y = bit ? b.y : day;
}
// xor4 exchange via ds_swizzle, same select-last form
__device__ __forceinline__ void xchg_swz4(v2f& a, v2f& b, bool bit) {
    float dbx = swzx4(b.x);
    float dby = swzx4(b.y);
    float dax = swzx4(a.x);
    float day = swzx4(a.y);
    a.x = bit ? dbx : a.x;   a.y = bit ? dby : a.y;
    b.x = bit ? b.x : dax;   b.y = bit ? b.y : day;
}

// xor8 exchange via masked-merge DPP: row_ror:8 == lane^8 within each 16-lane row;
// bank_mask 0xC writes only lanes with (lane&8)!=0, 0x3 only (lane&8)==0. No cndmasks.
#if __has_builtin(__builtin_amdgcn_update_dpp)
__device__ __forceinline__ void xchg8(v2f& a, v2f& b, bool /*bit*/) {
    int ax = __float_as_int(a.x), ay = __float_as_int(a.y);
    int bx = __float_as_int(b.x), by = __float_as_int(b.y);
    a.x = __int_as_float(__builtin_amdgcn_update_dpp(ax, bx, 0x128, 0xF, 0xC, false));
    a.y = __int_as_float(__builtin_amdgcn_update_dpp(ay, by, 0x128, 0xF, 0xC, false));
    b.x = __int_as_float(__builtin_amdgcn_update_dpp(bx, ax, 0x128, 0xF, 0x3, false));
    b.y = __int_as_float(__builtin_amdgcn_update_dpp(by, ay, 0x128, 0xF, 0x3, false));
}
#else
__device__ __forceinline__ void xchg8(v2f& a, v2f& b, bool bit) {
    xchg_dpp<0x128>(a, b, bit);
}
#endif

#if __has_builtin(__builtin_amdgcn_permlane16_swap)
__device__ __forceinline__ void pl16x(v2f& a, v2f& b) {
    v2u rx = __builtin_amdgcn_permlane16_swap(__float_as_uint(a.x), __float_as_uint(b.x), false, false);
    a.x = __uint_as_float(rx.x); b.x = __uint_as_float(rx.y);
    v2u ry = __builtin_amdgcn_permlane16_swap(__float_as_uint(a.y), __float_as_uint(b.y), false, false);
    a.y = __uint_as_float(ry.x); b.y = __uint_as_float(ry.y);
}
#else
__device__ __forceinline__ void pl16x(v2f& a, v2f& b) {
    bool bit = (threadIdx.x & 16) != 0;
    float sx = bit ? a.x : b.x, sy = bit ? a.y : b.y;
    float tx = __shfl_xor(sx, 16), ty = __shfl_xor(sy, 16);
    a.x = bit ? tx : a.x; a.y = bit ? ty : a.y;
    b.x = bit ? b.x : tx; b.y = bit ? b.y : ty;
}
#endif

#if __has_builtin(__builtin_amdgcn_permlane32_swap)
__device__ __forceinline__ void pl32x(v2f& a, v2f& b) {
    v2u rx = __builtin_amdgcn_permlane32_swap(__float_as_uint(a.x), __float_as_uint(b.x), false, false);
    a.x = __uint_as_float(rx.x); b.x = __uint_as_float(rx.y);
    v2u ry = __builtin_amdgcn_permlane32_swap(__float_as_uint(a.y), __float_as_uint(b.y), false, false);
    a.y = __uint_as_float(ry.x); b.y = __uint_as_float(ry.y);
}
#else
__device__ __forceinline__ void pl32x(v2f& a, v2f& b) {
    bool bit = (threadIdx.x & 32) != 0;
    float sx = bit ? a.x : b.x, sy = bit ? a.y : b.y;
    float tx = __shfl_xor(sx, 32), ty = __shfl_xor(sy, 32);
    a.x = bit ? tx : a.x; a.y = bit ? ty : a.y;
    b.x = bit ? b.x : tx; b.y = bit ? b.y : ty;
}
#endif

// hot-loop step: in-register 512-pt inverse DFT (8x8x8 four-step; transposes via
// permlane/DPP/swizzle), publish G2..G5 to this step's parity buffer, ONE barrier, gather.
// awBase/ldsBase carry the parity offset (0 or 32) folded in by the caller.
__device__ __forceinline__ void fft_sample(
    const v2f y[8], const v2f tA[8], const v2f tB[8],
    bool b0, bool b1, bool b2, bool b3,
    char* awBase, const char* ldsBase, int spos, const v2f ph[RPB], bool active,
    float* pA)
{
    v2f G[8];
    dft8p(y, G);                                   // DFT over q2 (reg digit) -> v0
#pragma unroll
    for (int k1 = 1; k1 < 8; ++k1) G[k1] = cmulv(G[k1], tA[k1]);   // W512^{L*v0}
    // T1: reg digit (v0) <-> lane-high digit (q1)
    xchg8(G[0], G[1], b3);  xchg8(G[2], G[3], b3);                       // xor8 (merge-DPP)
    xchg8(G[4], G[5], b3);  xchg8(G[6], G[7], b3);
    pl16x(G[0], G[2]);  pl16x(G[1], G[3]);  pl16x(G[4], G[6]);  pl16x(G[5], G[7]);   // xor16
    pl32x(G[0], G[4]);  pl32x(G[1], G[5]);  pl32x(G[2], G[6]);  pl32x(G[3], G[7]);   // xor32
    dft8p_ip(G);                                   // DFT over q1 -> v1
#pragma unroll
    for (int m1 = 1; m1 < 8; ++m1) G[m1] = cmulv(G[m1], tB[m1]);   // W512^{8*q0*v1}
    // T2: reg digit (v1) <-> lane-low digit (q0)
    xchg_dpp<0xB1>(G[0], G[1], b0);  xchg_dpp<0xB1>(G[2], G[3], b0);     // quad_perm xor1
    xchg_dpp<0xB1>(G[4], G[5], b0);  xchg_dpp<0xB1>(G[6], G[7], b0);
    xchg_dpp<0x4E>(G[0], G[2], b1);  xchg_dpp<0x4E>(G[1], G[3], b1);     // quad_perm xor2
    xchg_dpp<0x4E>(G[4], G[6], b1);  xchg_dpp<0x4E>(G[5], G[7], b1);
    xchg_swz4(G[0], G[4], b2);  xchg_swz4(G[1], G[5], b2);               // ds_swizzle xor4
    xchg_swz4(G[2], G[6], b2);  xchg_swz4(G[3], G[7], b2);
    v2f o[4];
    dft8p_mid4(G, o);                              // DFT over q0 -> v2 (only outputs 2..5)
    *(v4f*)(awBase +  0) = v4f{o[0].x, o[0].y, o[1].x, o[1].y};   // G2,G3
    *(v4f*)(awBase + 16) = v4f{o[2].x, o[2].y, o[3].x, o[3].y};   // G4,G5
    __syncthreads();   // single barrier: publish visible; orders prev gather vs buffer reuse
    if (active) {
        v2f accv = v2f{0.0f, 0.0f};
#pragma unroll
        for (int ww = 0; ww < RPB; ++ww) {
            v2f q = *(const v2f*)(ldsBase + ww * WREG + spos);
            // accv += {q.x*ph.x, -q.y*ph.y}
            asm("v_pk_fma_f32 %0, %1, %2, %0 neg_hi:[1,0,0]" : "+v"(accv) : "v"(q), "v"(ph[ww]));
        }
        pA[0] = accv.x + accv.y;
    }
}

// ---------------- init kernels (run once, shuffle FFT; cold path stays scalar) -------------------
__device__ __forceinline__ void cbfly(float& ar, float& ai, float& br, float& bi,
                                      float wr, float wi) {
    float dr = ar - br, di = ai - bi;
    ar = ar + br; ai = ai + bi;
    br = fmaf(dr, wr, -di * wi);
    bi = fmaf(dr, wi,  di * wr);
}

__device__ __forceinline__ void init_trig(float2* trig, int tid) {
    if (tid < 256) {
        float ang = (float)tid * (6.283185307179586f / 512.0f);
        float s, c;
        sincosf(ang, &s, &c);
        trig[tid] = make_float2(c, s);
    }
}

__device__ __forceinline__ void fft512_inv_lds(float* xr, float* xi, const float2* trig, int L) {
#pragma unroll
    for (int r = 0; r < 4; ++r) {
        float2 w = trig[(r << 6) + L];
        cbfly(xr[r], xi[r], xr[r + 4], xi[r + 4], w.x, w.y);
    }
    {
        float2 w0 = trig[L << 1];
        float2 w1 = trig[(64 + L) << 1];
        cbfly(xr[0], xi[0], xr[2], xi[2], w0.x, w0.y);
        cbfly(xr[1], xi[1], xr[3], xi[3], w1.x, w1.y);
        cbfly(xr[4], xi[4], xr[6], xi[6], w0.x, w0.y);
        cbfly(xr[5], xi[5], xr[7], xi[7], w1.x, w1.y);
    }
    {
        float2 w = trig[L << 2];
        cbfly(xr[0], xi[0], xr[1], xi[1], w.x, w.y);
        cbfly(xr[2], xi[2], xr[3], xi[3], w.x, w.y);
        cbfly(xr[4], xi[4], xr[5], xi[5], w.x, w.y);
        cbfly(xr[6], xi[6], xr[7], xi[7], w.x, w.y);
    }
#pragma unroll
    for (int s = 3; s <= 8; ++s) {
        const int half = 512 >> (s + 1);
        const int ex = (L & (half - 1)) << s;
        float2 w = trig[ex];
        const bool hi = (L & half) != 0;
        float wr = hi ? w.x : 1.0f;
        float wi = hi ? w.y : 0.0f;
        float sg = hi ? -1.0f : 1.0f;
#pragma unroll
        for (int r = 0; r < 8; ++r) {
            float orv = __shfl_xor(xr[r], half);
            float oiv = __shfl_xor(xi[r], half);
            float tr = fmaf(sg, xr[r], orv);
            float ti = fmaf(sg, xi[r], oiv);
            xr[r] = fmaf(tr, wr, -ti * wi);
            xi[r] = fmaf(tr, wi,  ti * wr);
        }
    }
}

__global__ __launch_bounds__(256) void f1_kernel(const float* __restrict__ f,
                                                 float2* __restrict__ R) {
    __shared__ float2 trig[256];
    const int tid = threadIdx.x;
    init_trig(trig, tid);
    __syncthreads();
    const int w = tid >> 6, L = tid & 63;
    const int x = 128 + blockIdx.x * 4 + w;   // nonzero rows only: [128, 384)
    const int b = blockIdx.y;
    const float* frow = f + ((size_t)b * 256 + (x - 128)) * 256;
    float xr[8], xi[8];
#pragma unroll
    for (int r = 0; r < 8; ++r) {
        int e = r * 64 + L;
        xr[r] = (e >= 128 && e < 384) ? frow[e - 128] : 0.0f;
        xi[r] = 0.0f;
    }
    fft512_inv_lds(xr, xi, trig, L);
    float2* Rrow = R + ((size_t)b * NOUT + x) * NOUT;
#pragma unroll
    for (int r = 0; r < 8; ++r) {
        int e = r * 64 + L;
        int k = __brev((unsigned)e) >> 23;
        Rrow[k] = make_float2(xr[r], -xi[r]);
    }
}

// f2: rows x outside [128,384) of R were never written (and are not zeroed) — treat as 0.
// e = r*64 + L is in [128,384) exactly for r in [2,6).
__global__ __launch_bounds__(256) void f2_kernel(const float2* __restrict__ R,
                                                 float2* __restrict__ A0) {
    __shared__ float2 trig[256];
    const int tid = threadIdx.x;
    init_trig(trig, tid);
    __syncthreads();
    const int w = tid >> 6, L = tid & 63;
    const int q = blockIdx.x * 4 + w;
    const int b = blockIdx.y;
    float xr[8], xi[8];
#pragma unroll
    for (int r = 0; r < 8; ++r) {
        if (r >= 2 && r < 6) {
            int e = r * 64 + L;
            float2 v = R[((size_t)b * NOUT + e) * NOUT + q];
            xr[r] = v.x;
            xi[r] = -v.y;
        } else {
            xr[r] = 0.0f;
            xi[r] = 0.0f;
        }
    }
    fft512_inv_lds(xr, xi, trig, L);
#pragma unroll
    for (int r = 0; r < 8; ++r) {
        int e = r * 64 + L;
        int p = __brev((unsigned)e) >> 23;
        A0[((size_t)b * NOUT + p) * NOUT + q] = make_float2(xr[r], -xi[r]);
    }
}

// ---------------- time-chunk simulation ----------------------------------------------------------
// block = (row group g of RPB rows, batch b); wave w owns row p = RPB*g + w, p in 0..257.
// Threads 0..255 each own one sensor, summing the block's RPB rows after the step barrier.
__global__ __launch_bounds__(384, 4) void sim_kernel(
    const float* __restrict__ fil,
    const int* __restrict__ idx0, const int* __restrict__ idx1,
    float2* __restrict__ stateCur, float2* __restrict__ statePrev,
    float* __restrict__ partial, int Tc, int firstChunk, int lastChunk)
{
    __shared__ __align__(16) char waveMem[RPB * WREG];   // 31104 B
    __shared__ float2 trig[256];                         //  2048 B -> 33152 B total

    const int tid = threadIdx.x;              // 0..383
    const int w = tid >> 6, L = tid & 63;
    const int g = blockIdx.x, b = blockIdx.y;
    const int p = g * RPB + w;                // 0..257

    if (tid < 256) {
        float ang = (float)tid * (6.283185307179586f / 512.0f);
        float s, c;
        sincosf(ang, &s, &c);
        trig[tid] = make_float2(c, s);
    }
    __syncthreads();

    // --- per-lane constant twiddles ---
    v2f tA[8], tB[8];
#pragma unroll
    for (int k1 = 1; k1 < 8; ++k1) tA[k1] = wlookup(trig, L * k1);
#pragma unroll
    for (int m1 = 1; m1 < 8; ++m1) tB[m1] = wlookup(trig, 8 * (L & 7) * m1);

    // --- transpose predicates (loop-invariant; land in SGPR masks) ---
    const bool b0 = (L & 1) != 0;
    const bool b1 = (L & 2) != 0;
    const bool b2 = (L & 4) != 0;
    const bool b3 = (L & 8) != 0;

    // --- sensor constants: thread tid<256 owns sensor j=tid ---
    const bool active = tid < 256;
    int spos = 0;
    v2f ph[RPB];
    if (active) {
        int u = idx0[tid];
        int v = idx1[tid];
        // published regs are v>>6 in {2..5} at lane-local offsets 0,8,16,24 (parity 0)
        spos = ((v & 7) * 8 + ((v >> 3) & 7)) * 80 + ((v >> 6) * 8 - 16);
        // Hermitian fold phase: p==0 -> 1, p==256 -> (-1)^u, p==257 -> 0, else 2*W512^{pu}
#pragma unroll
        for (int ww = 0; ww < RPB; ++ww) {
            int prow = g * RPB + ww;
            v2f a0;
            if (prow == 0)        a0 = v2f{1.0f, 0.0f};
            else if (prow == 256) a0 = v2f{(u & 1) ? -1.0f : 1.0f, 0.0f};
            else if (prow == 257) a0 = v2f{0.0f, 0.0f};
            else                  a0 = 2.0f * wlookup(trig, prow * u);
            ph[ww] = a0;
        }
    } else {
#pragma unroll
        for (int ww = 0; ww < RPB; ++ww) ph[ww] = v2f{0.0f, 0.0f};
    }

    // --- per-lane LDS publish base; parity buffer offsets 0 / 32 within the pitch-80 slot ---
    char* myA    = waveMem + w * WREG;
    char* awBase = myA + L * 80;

    // --- load state + filter into registers ---
    v2f a[8], bb[8];
    float C[8];
    {
        const size_t rowBase = ((size_t)b * NOUT + p) * NOUT;
        const float* filRow = fil + (size_t)p * NOUT;
#pragma unroll
        for (int r = 0; r < 8; ++r) {
            int e = r * 64 + L;
            float2 a0 = stateCur[rowBase + e];
            a[r] = v2f{a0.x, a0.y};
            if (firstChunk) {
                bb[r] = a[r];
            } else {
                float2 a1 = statePrev[rowBase + e];
                bb[r] = v2f{a1.x, a1.y};
            }
            C[r] = fmaf(-4.0f, filRow[e], 2.0f);
        }
    }

    float* pOut = partial + ((size_t)g * Tc * NB + b) * NPHI + tid;

    for (int tl = 0; tl < Tc; tl += 2) {
        // step A (parity 0): bb becomes A_{t+1}
#pragma unroll
        for (int r = 0; r < 8; ++r) bb[r] = v2f{C[r], C[r]} * a[r] - bb[r];
        fft_sample(bb, tA, tB, b0, b1, b2, b3, awBase, waveMem,
                   spos, ph, active, pOut);
        pOut += NB * NPHI;
        // step B (parity 1): a becomes A_{t+2}
#pragma unroll
        for (int r = 0; r < 8; ++r) a[r] = v2f{C[r], C[r]} * bb[r] - a[r];
        fft_sample(a, tA, tB, b0, b1, b2, b3, awBase + 32, waveMem + 32,
                   spos, ph, active, pOut);
        pOut += NB * NPHI;
    }

    // --- save state for the next chunk (skipped when this is the last chunk) ---
    if (!lastChunk) {
        const size_t rowBase = ((size_t)b * NOUT + p) * NOUT;
#pragma unroll
        for (int r = 0; r < 8; ++r) {
            int e = r * 64 + L;
            stateCur[rowBase + e]  = make_float2(a[r].x, a[r].y);
            statePrev[rowBase + e] = make_float2(bb[r].x, bb[r].y);
        }
    }
}

// ---------------- reduce NGRP row-group partials -> out[b][j][t] ----------------------------------
__global__ __launch_bounds__(256) void reduce_kernel(const float* __restrict__ partial,
                                                     float* __restrict__ out,
                                                     int Tc, int tStart) {
    int id = blockIdx.x * 256 + threadIdx.x;   // over Tc*16*256, exact
    int j = id & 255;
    int b = (id >> 8) & 15;
    int tl = id >> 12;
    float s = 0.0f;
#pragma unroll
    for (int gg = 0; gg < NGRP; ++gg)
        s += partial[(((size_t)gg * Tc + tl) * NB + b) * NPHI + j];
    out[((size_t)b * NPHI + j) * NT + (tStart + tl)] = s * (1.0f / (512.0f * 512.0f));
}

extern "C" void kernel_launch(void* const* d_in, const int* in_sizes, int n_in,
                              void* d_out, int out_size, void* d_ws, size_t ws_size,
                              hipStream_t stream) {
    (void)in_sizes; (void)n_in; (void)out_size;
    const float* f   = (const float*)d_in[0];   // [16,1,256,256]
    const float* fil = (const float*)d_in[1];   // [512,512]
    const int* idx0  = (const int*)d_in[2];     // [256]
    const int* idx1  = (const int*)d_in[3];     // [256]
    float* out = (float*)d_out;                 // [16,1,256,240]

    char* ws = (char*)d_ws;
    const size_t stateBytes = (size_t)NB * NOUT * NOUT * sizeof(float2);  // 33.55 MB
    float2* stateCur  = (float2*)ws;
    float2* statePrev = (float2*)(ws + stateBytes);   // also reused as R scratch for f1/f2
    float*  partial   = (float*)(ws + 2 * stateBytes);
    size_t remain = (ws_size > 2 * stateBytes) ? ws_size - 2 * stateBytes : 0;

    // largest even time chunk whose partial buffer fits (even: the sim loop is 2-step unrolled)
    static const int tcs[] = {240, 120, 80, 60, 48, 40, 30, 24, 20, 16, 12, 10, 8, 6, 4, 2};
    int Tc = 2;
    for (int i = 0; i < 16; ++i) {
        size_t need = (size_t)NGRP * tcs[i] * NB * NPHI * sizeof(float);
        if (need <= remain) { Tc = tcs[i]; break; }
    }

    // no memset: f1 writes rows [128,384) of the R scratch; f2 skips the rest as known-zero
    f1_kernel<<<dim3(64, NB), 256, 0, stream>>>(f, statePrev);        // rows x in [128,384)
    f2_kernel<<<dim3(128, NB), 256, 0, stream>>>(statePrev, stateCur);
    for (int t0 = 0; t0 < NT; t0 += Tc) {
        int last = (t0 + Tc) >= NT ? 1 : 0;
        sim_kernel<<<dim3(NGRP, NB), RPB * 64, 0, stream>>>(fil, idx0, idx1, stateCur, statePrev,
                                                            partial, Tc, t0 == 0 ? 1 : 0, last);
        reduce_kernel<<<dim3(Tc * NB), 256, 0, stream>>>(partial, out, Tc, t0);
    }
}

// Round 9
// 784.209 us; speedup vs baseline: 1.3982x; 1.0572x over previous
//
#include <hip/hip_runtime.h>
#include <hip/hip_bf16.h>

// WaveOperator: Fourier-domain 3-term recurrence + per-row inverse FFT sampling.
// A_{t+1}(p,q) = (2-4*fil(p,q)) * A_t - A_{t-1};  y[b,j,t] = Re(ifft2(A_{t+1})[u_j,v_j])
// R25 = R24 (proven 778us sim / 829us total) + fused v_cndmask_b32_dpp for the xor1/xor2
// exchange stages. R24's VALU breakdown: exchanges ~112/FFT are now the largest block; the
// xor1/xor2 form (4 mov_dpp + 4 cndmask = 8 VALU/pair) halves to 4 cndmask_dpp + 2 SALU
// s_mov_b64 vcc (constant lane masks 0xAAAA../0xCCCC.. -- compile-time since the exchange
// predicate is a lane-index bit). DPP hazard (VALU write -> DPP read needs 2 wait states)
// covered by s_mov + s_nop 0 before the first DPP of each block; outputs early-clobbered.
// Routing bit-identical to R24. Register-neutral (4 transient temps).
// History: VGPR=64 allocator-pinned (R20/R21 spills); register-neutral VALU-stream cuts are
// the only working lever (R18 +2%, R23 +4%, R24 +11%).

#define NOUT 512
#define NB 16
#define NPHI 256
#define NT 240
#define RPB 6             // rows per block (= waves per block)
#define NGRP 43           // row groups: 43*6 = 258 = rows 0..257 (257 gets zero phase)

#define WREG 5184         // per-wave LDS publish region (pitch 80; lane uses 2x32B parity bufs)

typedef float v2f __attribute__((ext_vector_type(2)));
typedef float v4f __attribute__((ext_vector_type(4)));
typedef unsigned int v2u __attribute__((ext_vector_type(2)));

// ---- VOP3P packed-fp32 primitives (register-neutral; modifiers do the swizzles) -----------------
__device__ __forceinline__ v2f pkadd(v2f a, v2f b) {
    v2f d; asm("v_pk_add_f32 %0, %1, %2" : "=v"(d) : "v"(a), "v"(b)); return d;
}
__device__ __forceinline__ v2f pksub(v2f a, v2f b) {
    v2f d; asm("v_pk_add_f32 %0, %1, %2 neg_lo:[0,1] neg_hi:[0,1]" : "=v"(d) : "v"(a), "v"(b)); return d;
}
// a + i*w = {a.x - w.y, a.y + w.x}
__device__ __forceinline__ v2f pkaddi(v2f a, v2f w) {
    v2f d; asm("v_pk_add_f32 %0, %1, %2 op_sel:[0,1] op_sel_hi:[1,0] neg_lo:[0,1]"
               : "=v"(d) : "v"(a), "v"(w)); return d;
}
// a - i*w = {a.x + w.y, a.y - w.x}
__device__ __forceinline__ v2f pksubi(v2f a, v2f w) {
    v2f d; asm("v_pk_add_f32 %0, %1, %2 op_sel:[0,1] op_sel_hi:[1,0] neg_hi:[0,1]"
               : "=v"(d) : "v"(a), "v"(w)); return d;
}
// s * {a.x - a.y, a.x + a.y}   (w8 twiddle)
__device__ __forceinline__ v2f pkw8(v2f a) {
    v2f d; asm("v_pk_add_f32 %0, %1, %1 op_sel:[0,1] op_sel_hi:[0,1] neg_lo:[0,1]"
               : "=v"(d) : "v"(a));
    const float s = 0.70710678118654752f;
    return v2f{s * d.x, s * d.y};
}
// {-s*(a.x + a.y), s*(a.x - a.y)}   (w8^3 twiddle)
__device__ __forceinline__ v2f pkw83(v2f a) {
    v2f d; asm("v_pk_add_f32 %0, %1, %1 op_sel:[0,1] op_sel_hi:[0,1] neg_hi:[0,1]"
               : "=v"(d) : "v"(a));
    const float s = 0.70710678118654752f;
    return v2f{-s * d.x, s * d.y};
}
// complex mul g*t: {g.x*t.x - g.y*t.y, g.x*t.y + g.y*t.x} in 2 VOP3P ops
__device__ __forceinline__ v2f cmulv(v2f g, v2f t) {
    v2f p, d;
    asm("v_pk_mul_f32 %0, %1, %2 op_sel:[0,0] op_sel_hi:[0,1]" : "=v"(p) : "v"(g), "v"(t));
    // p = {g.x*t.x, g.x*t.y}
    asm("v_pk_fma_f32 %0, %1, %2, %3 op_sel:[1,1,0] op_sel_hi:[1,0,1] neg_lo:[1,0,0]"
        : "=v"(d) : "v"(g), "v"(t), "v"(p));
    // d = {-g.y*t.y + p.x, g.y*t.x + p.y}
    return d;
}

// 8-pt DFT, positive exponent: Y[k] = sum_r y[r] * exp(+2pi i rk/8)  (packed form)
__device__ __forceinline__ void dft8p(const v2f y[8], v2f Y[8]) {
    v2f t0 = pkadd(y[0], y[4]), t4 = pksub(y[0], y[4]);
    v2f t1 = pkadd(y[1], y[5]), t5 = pkw8(pksub(y[1], y[5]));
    v2f t2 = pkadd(y[2], y[6]), d26 = pksub(y[2], y[6]);   // t6 = i*d26 folded into consumers
    v2f t3 = pkadd(y[3], y[7]), t7 = pkw83(pksub(y[3], y[7]));
    v2f u0 = pkadd(t0, t2), u2 = pksub(t0, t2);
    v2f u1 = pkadd(t1, t3), w13 = pksub(t1, t3);           // u3 = i*w13 folded
    Y[0] = pkadd(u0, u1); Y[4] = pksub(u0, u1);
    Y[2] = pkaddi(u2, w13); Y[6] = pksubi(u2, w13);
    v2f v0 = pkaddi(t4, d26), v2 = pksubi(t4, d26);        // t4 +- i*d26
    v2f v1 = pkadd(t5, t7), w57 = pksub(t5, t7);           // v3 = i*w57 folded
    Y[1] = pkadd(v0, v1); Y[5] = pksub(v0, v1);
    Y[3] = pkaddi(v2, w57); Y[7] = pksubi(v2, w57);
}

// in-place variant (reads of y[] only in the t-layer; all writes after)
__device__ __forceinline__ void dft8p_ip(v2f y[8]) {
    v2f t0 = pkadd(y[0], y[4]), t4 = pksub(y[0], y[4]);
    v2f t1 = pkadd(y[1], y[5]), t5 = pkw8(pksub(y[1], y[5]));
    v2f t2 = pkadd(y[2], y[6]), d26 = pksub(y[2], y[6]);
    v2f t3 = pkadd(y[3], y[7]), t7 = pkw83(pksub(y[3], y[7]));
    v2f u0 = pkadd(t0, t2), u2 = pksub(t0, t2);
    v2f u1 = pkadd(t1, t3), w13 = pksub(t1, t3);
    y[0] = pkadd(u0, u1); y[4] = pksub(u0, u1);
    y[2] = pkaddi(u2, w13); y[6] = pksubi(u2, w13);
    v2f v0 = pkaddi(t4, d26), v2 = pksubi(t4, d26);
    v2f v1 = pkadd(t5, t7), w57 = pksub(t5, t7);
    y[1] = pkadd(v0, v1); y[5] = pksub(v0, v1);
    y[3] = pkaddi(v2, w57); y[7] = pksubi(v2, w57);
}

// final-layer DFT producing only outputs Y2,Y3,Y4,Y5 (the sensor v>>6 range)
__device__ __forceinline__ void dft8p_mid4(const v2f y[8], v2f o[4]) {
    v2f t0 = pkadd(y[0], y[4]), t4 = pksub(y[0], y[4]);
    v2f t1 = pkadd(y[1], y[5]), t5 = pkw8(pksub(y[1], y[5]));
    v2f t2 = pkadd(y[2], y[6]), d26 = pksub(y[2], y[6]);
    v2f t3 = pkadd(y[3], y[7]), t7 = pkw83(pksub(y[3], y[7]));
    v2f u0 = pkadd(t0, t2), u2 = pksub(t0, t2);
    v2f u1 = pkadd(t1, t3), w13 = pksub(t1, t3);
    v2f v0 = pkaddi(t4, d26), v2 = pksubi(t4, d26);
    v2f v1 = pkadd(t5, t7), w57 = pksub(t5, t7);
    o[0] = pkaddi(u2, w13);    // Y2
    o[1] = pkaddi(v2, w57);    // Y3
    o[2] = pksub(u0, u1);      // Y4
    o[3] = pksub(v0, v1);      // Y5
}

// W512^m from half-table
__device__ __forceinline__ v2f wlookup(const float2* trig, int m) {
    m &= 511;
    float2 ph = trig[m & 255];
    return (m & 256) ? v2f{-ph.x, -ph.y} : v2f{ph.x, ph.y};
}

// ---- in-register lane exchanges (transpose building blocks) -------------------------------------
template<int CTRL>
__device__ __forceinline__ float dppx(float x) {
    return __int_as_float(__builtin_amdgcn_mov_dpp(__float_as_int(x), CTRL, 0xF, 0xF, true));
}
__device__ __forceinline__ float swzx4(float x) {
    // BitMode swizzle: and=0x1F, or=0, xor=4  -> lane ^ 4
    return __int_as_float(__builtin_amdgcn_ds_swizzle(__float_as_int(x), 0x101F));
}

// xor1 exchange via fused v_cndmask_b32_dpp (dst = vcc ? src1 : dpp(src0)); constant lane
// masks in vcc via SALU. keepA = lanes where (L&1)==0, keepB = complement.
// Hazard: s_mov + s_nop 0 = 2 wait states before the first DPP (covers external VALU write).
__device__ __forceinline__ void xchg_x1(v2f& a, v2f& b,
                                        unsigned long long kA, unsigned long long kB) {
    v2f na, nb;
    asm("s_mov_b64 vcc, %[ka]\n\t"
        "s_nop 0\n\t"
        "v_cndmask_b32_dpp %[nax], %[bx], %[ax], vcc quad_perm:[1,0,3,2] row_mask:0xf bank_mask:0xf\n\t"
        "v_cndmask_b32_dpp %[nay], %[by], %[ay], vcc quad_perm:[1,0,3,2] row_mask:0xf bank_mask:0xf\n\t"
        "s_mov_b64 vcc, %[kb]\n\t"
        "s_nop 0\n\t"
        "v_cndmask_b32_dpp %[nbx], %[ax], %[bx], vcc quad_perm:[1,0,3,2] row_mask:0xf bank_mask:0xf\n\t"
        "v_cndmask_b32_dpp %[nby], %[ay], %[by], vcc quad_perm:[1,0,3,2] row_mask:0xf bank_mask:0xf"
        : [nax]"=&v"(na.x), [nay]"=&v"(na.y), [nbx]"=&v"(nb.x), [nby]"=&v"(nb.y)
        : [ax]"v"(a.x), [ay]"v"(a.y), [bx]"v"(b.x), [by]"v"(b.y),
          [ka]"s"(kA), [kb]"s"(kB)
        : "vcc");
    a = na; b = nb;
}
// xor2 exchange, quad_perm:[2,3,0,1]; keepA = lanes where (L&2)==0.
__device__ __forceinline__ void xchg_x2(v2f& a, v2f& b,
                                        unsigned long long kA, unsigned long long kB) {
    v2f na, nb;
    asm("s_mov_b64 vcc, %[ka]\n\t"
        "s_nop 0\n\t"
        "v_cndmask_b32_dpp %[nax], %[bx], %[ax], vcc quad_perm:[2,3,0,1] row_mask:0xf bank_mask:0xf\n\t"
        "v_cndmask_b32_dpp %[nay], %[by], %[ay], vcc quad_perm:[2,3,0,1] row_mask:0xf bank_mask:0xf\n\t"
        "s_mov_b64 vcc, %[kb]\n\t"
        "s_nop 0\n\t"
        "v_cndmask_b32_dpp %[nbx], %[ax], %[bx], vcc quad_perm:[2,3,0,1] row_mask:0xf bank_mask:0xf\n\t"
        "v_cndmask_b32_dpp %[nby], %[ay], %[by], vcc quad_perm:[2,3,0,1] row_mask:0xf bank_mask:0xf"
        : [nax]"=&v"(na.x), [nay]"=&v"(na.y), [nbx]"=&v"(nb.x), [nby]"=&v"(nb.y)
        : [ax]"v"(a.x), [ay]"v"(a.y), [bx]"v"(b.x), [by]"v"(b.y),
          [ka]"s"(kA), [kb]"s"(kB)
        : "vcc");
    a = na; b = nb;
}

// xor4 exchange via ds_swizzle, select-last form (LDS pipe has headroom)
__device__ __forceinline__ void xchg_swz4(v2f& a, v2f& b, bool bit) {
    float dbx = swzx4(b.x);
    float dby = swzx4(b.y);
    float dax = swzx4(a.x);
    float day = swzx4(a.y);
    a.x = bit ? dbx : a.x;   a.y = bit ? dby : a.y;
    b.x = bit ? b.x : dax;   b.y = bit ? b.y : day;
}

// xor8 exchange via masked-merge DPP: row_ror:8 == lane^8 within each 16-lane row;
// bank_mask 0xC writes only lanes with (lane&8)!=0, 0x3 only (lane&8)==0. No cndmasks.
#if __has_builtin(__builtin_amdgcn_update_dpp)
__device__ __forceinline__ void xchg8(v2f& a, v2f& b, bool /*bit*/) {
    int ax = __float_as_int(a.x), ay = __float_as_int(a.y);
    int bx = __float_as_int(b.x), by = __float_as_int(b.y);
    a.x = __int_as_float(__builtin_amdgcn_update_dpp(ax, bx, 0x128, 0xF, 0xC, false));
    a.y = __int_as_float(__builtin_amdgcn_update_dpp(ay, by, 0x128, 0xF, 0xC, false));
    b.x = __int_as_float(__builtin_amdgcn_update_dpp(bx, ax, 0x128, 0xF, 0x3, false));
    b.y = __int_as_float(__builtin_amdgcn_update_dpp(by, ay, 0x128, 0xF, 0x3, false));
}
#else
__device__ __forceinline__ void xchg8(v2f& a, v2f& b, bool bit) {
    float dbx = dppx<0x128>(b.x);
    float dby = dppx<0x128>(b.y);
    float dax = dppx<0x128>(a.x);
    float day = dppx<0x128>(a.y);
    a.x = bit ? dbx : a.x;   a.y = bit ? dby : a.y;
    b.x = bit ? b.x : dax;   b.y = bit ? b.y : day;
}
#endif

#if __has_builtin(__builtin_amdgcn_permlane16_swap)
__device__ __forceinline__ void pl16x(v2f& a, v2f& b) {
    v2u rx = __builtin_amdgcn_permlane16_swap(__float_as_uint(a.x), __float_as_uint(b.x), false, false);
    a.x = __uint_as_float(rx.x); b.x = __uint_as_float(rx.y);
    v2u ry = __builtin_amdgcn_permlane16_swap(__float_as_uint(a.y), __float_as_uint(b.y), false, false);
    a.y = __uint_as_float(ry.x); b.y = __uint_as_float(ry.y);
}
#else
__device__ __forceinline__ void pl16x(v2f& a, v2f& b) {
    bool bit = (threadIdx.x & 16) != 0;
    float sx = bit ? a.x : b.x, sy = bit ? a.y : b.y;
    float tx = __shfl_xor(sx, 16), ty = __shfl_xor(sy, 16);
    a.x = bit ? tx : a.x; a.y = bit ? ty : a.y;
    b.x = bit ? b.x : tx; b.y = bit ? b.y : ty;
}
#endif

#if __has_builtin(__builtin_amdgcn_permlane32_swap)
__device__ __forceinline__ void pl32x(v2f& a, v2f& b) {
    v2u rx = __builtin_amdgcn_permlane32_swap(__float_as_uint(a.x), __float_as_uint(b.x), false, false);
    a.x = __uint_as_float(rx.x); b.x = __uint_as_float(rx.y);
    v2u ry = __builtin_amdgcn_permlane32_swap(__float_as_uint(a.y), __float_as_uint(b.y), false, false);
    a.y = __uint_as_float(ry.x); b.y = __uint_as_float(ry.y);
}
#else
__device__ __forceinline__ void pl32x(v2f& a, v2f& b) {
    bool bit = (threadIdx.x & 32) != 0;
    float sx = bit ? a.x : b.x, sy = bit ? a.y : b.y;
    float tx = __shfl_xor(sx, 32), ty = __shfl_xor(sy, 32);
    a.x = bit ? tx : a.x; a.y = bit ? ty : a.y;
    b.x = bit ? b.x : tx; b.y = bit ? b.y : ty;
}
#endif

// hot-loop step: in-register 512-pt inverse DFT (8x8x8 four-step; transposes via
// permlane/DPP/swizzle), publish G2..G5 to this step's parity buffer, ONE barrier, gather.
// awBase/ldsBase carry the parity offset (0 or 32) folded in by the caller.
__device__ __forceinline__ void fft_sample(
    const v2f y[8], const v2f tA[8], const v2f tB[8],
    bool b2, bool b3,
    char* awBase, const char* ldsBase, int spos, const v2f ph[RPB], bool active,
    float* pA)
{
    const unsigned long long K1A = 0x5555555555555555ULL;  // (L&1)==0
    const unsigned long long K1B = 0xAAAAAAAAAAAAAAAAULL;
    const unsigned long long K2A = 0x3333333333333333ULL;  // (L&2)==0
    const unsigned long long K2B = 0xCCCCCCCCCCCCCCCCULL;
    v2f G[8];
    dft8p(y, G);                                   // DFT over q2 (reg digit) -> v0
#pragma unroll
    for (int k1 = 1; k1 < 8; ++k1) G[k1] = cmulv(G[k1], tA[k1]);   // W512^{L*v0}
    // T1: reg digit (v0) <-> lane-high digit (q1)
    xchg8(G[0], G[1], b3);  xchg8(G[2], G[3], b3);                       // xor8 (merge-DPP)
    xchg8(G[4], G[5], b3);  xchg8(G[6], G[7], b3);
    pl16x(G[0], G[2]);  pl16x(G[1], G[3]);  pl16x(G[4], G[6]);  pl16x(G[5], G[7]);   // xor16
    pl32x(G[0], G[4]);  pl32x(G[1], G[5]);  pl32x(G[2], G[6]);  pl32x(G[3], G[7]);   // xor32
    dft8p_ip(G);                                   // DFT over q1 -> v1
#pragma unroll
    for (int m1 = 1; m1 < 8; ++m1) G[m1] = cmulv(G[m1], tB[m1]);   // W512^{8*q0*v1}
    // T2: reg digit (v1) <-> lane-low digit (q0)
    xchg_x1(G[0], G[1], K1A, K1B);  xchg_x1(G[2], G[3], K1A, K1B);       // cndmask_dpp xor1
    xchg_x1(G[4], G[5], K1A, K1B);  xchg_x1(G[6], G[7], K1A, K1B);
    xchg_x2(G[0], G[2], K2A, K2B);  xchg_x2(G[1], G[3], K2A, K2B);       // cndmask_dpp xor2
    xchg_x2(G[4], G[6], K2A, K2B);  xchg_x2(G[5], G[7], K2A, K2B);
    xchg_swz4(G[0], G[4], b2);  xchg_swz4(G[1], G[5], b2);               // ds_swizzle xor4
    xchg_swz4(G[2], G[6], b2);  xchg_swz4(G[3], G[7], b2);
    v2f o[4];
    dft8p_mid4(G, o);                              // DFT over q0 -> v2 (only outputs 2..5)
    *(v4f*)(awBase +  0) = v4f{o[0].x, o[0].y, o[1].x, o[1].y};   // G2,G3
    *(v4f*)(awBase + 16) = v4f{o[2].x, o[2].y, o[3].x, o[3].y};   // G4,G5
    __syncthreads();   // single barrier: publish visible; orders prev gather vs buffer reuse
    if (active) {
        v2f accv = v2f{0.0f, 0.0f};
#pragma unroll
        for (int ww = 0; ww < RPB; ++ww) {
            v2f q = *(const v2f*)(ldsBase + ww * WREG + spos);
            // accv += {q.x*ph.x, -q.y*ph.y}
            asm("v_pk_fma_f32 %0, %1, %2, %0 neg_hi:[1,0,0]" : "+v"(accv) : "v"(q), "v"(ph[ww]));
        }
        pA[0] = accv.x + accv.y;
    }
}

// ---------------- init kernels (run once, shuffle FFT; cold path stays scalar) -------------------
__device__ __forceinline__ void cbfly(float& ar, float& ai, float& br, float& bi,
                                      float wr, float wi) {
    float dr = ar - br, di = ai - bi;
    ar = ar + br; ai = ai + bi;
    br = fmaf(dr, wr, -di * wi);
    bi = fmaf(dr, wi,  di * wr);
}

__device__ __forceinline__ void init_trig(float2* trig, int tid) {
    if (tid < 256) {
        float ang = (float)tid * (6.283185307179586f / 512.0f);
        float s, c;
        sincosf(ang, &s, &c);
        trig[tid] = make_float2(c, s);
    }
}

__device__ __forceinline__ void fft512_inv_lds(float* xr, float* xi, const float2* trig, int L) {
#pragma unroll
    for (int r = 0; r < 4; ++r) {
        float2 w = trig[(r << 6) + L];
        cbfly(xr[r], xi[r], xr[r + 4], xi[r + 4], w.x, w.y);
    }
    {
        float2 w0 = trig[L << 1];
        float2 w1 = trig[(64 + L) << 1];
        cbfly(xr[0], xi[0], xr[2], xi[2], w0.x, w0.y);
        cbfly(xr[1], xi[1], xr[3], xi[3], w1.x, w1.y);
        cbfly(xr[4], xi[4], xr[6], xi[6], w0.x, w0.y);
        cbfly(xr[5], xi[5], xr[7], xi[7], w1.x, w1.y);
    }
    {
        float2 w = trig[L << 2];
        cbfly(xr[0], xi[0], xr[1], xi[1], w.x, w.y);
        cbfly(xr[2], xi[2], xr[3], xi[3], w.x, w.y);
        cbfly(xr[4], xi[4], xr[5], xi[5], w.x, w.y);
        cbfly(xr[6], xi[6], xr[7], xi[7], w.x, w.y);
    }
#pragma unroll
    for (int s = 3; s <= 8; ++s) {
        const int half = 512 >> (s + 1);
        const int ex = (L & (half - 1)) << s;
        float2 w = trig[ex];
        const bool hi = (L & half) != 0;
        float wr = hi ? w.x : 1.0f;
        float wi = hi ? w.y : 0.0f;
        float sg = hi ? -1.0f : 1.0f;
#pragma unroll
        for (int r = 0; r < 8; ++r) {
            float orv = __shfl_xor(xr[r], half);
            float oiv = __shfl_xor(xi[r], half);
            float tr = fmaf(sg, xr[r], orv);
            float ti = fmaf(sg, xi[r], oiv);
            xr[r] = fmaf(tr, wr, -ti * wi);
            xi[r] = fmaf(tr, wi,  ti * wr);
        }
    }
}

__global__ __launch_bounds__(256) void f1_kernel(const float* __restrict__ f,
                                                 float2* __restrict__ R) {
    __shared__ float2 trig[256];
    const int tid = threadIdx.x;
    init_trig(trig, tid);
    __syncthreads();
    const int w = tid >> 6, L = tid & 63;
    const int x = 128 + blockIdx.x * 4 + w;   // nonzero rows only: [128, 384)
    const int b = blockIdx.y;
    const float* frow = f + ((size_t)b * 256 + (x - 128)) * 256;
    float xr[8], xi[8];
#pragma unroll
    for (int r = 0; r < 8; ++r) {
        int e = r * 64 + L;
        xr[r] = (e >= 128 && e < 384) ? frow[e - 128] : 0.0f;
        xi[r] = 0.0f;
    }
    fft512_inv_lds(xr, xi, trig, L);
    float2* Rrow = R + ((size_t)b * NOUT + x) * NOUT;
#pragma unroll
    for (int r = 0; r < 8; ++r) {
        int e = r * 64 + L;
        int k = __brev((unsigned)e) >> 23;
        Rrow[k] = make_float2(xr[r], -xi[r]);
    }
}

// f2: rows x outside [128,384) of R were never written (and are not zeroed) — treat as 0.
// e = r*64 + L is in [128,384) exactly for r in [2,6).
__global__ __launch_bounds__(256) void f2_kernel(const float2* __restrict__ R,
                                                 float2* __restrict__ A0) {
    __shared__ float2 trig[256];
    const int tid = threadIdx.x;
    init_trig(trig, tid);
    __syncthreads();
    const int w = tid >> 6, L = tid & 63;
    const int q = blockIdx.x * 4 + w;
    const int b = blockIdx.y;
    float xr[8], xi[8];
#pragma unroll
    for (int r = 0; r < 8; ++r) {
        if (r >= 2 && r < 6) {
            int e = r * 64 + L;
            float2 v = R[((size_t)b * NOUT + e) * NOUT + q];
            xr[r] = v.x;
            xi[r] = -v.y;
        } else {
            xr[r] = 0.0f;
            xi[r] = 0.0f;
        }
    }
    fft512_inv_lds(xr, xi, trig, L);
#pragma unroll
    for (int r = 0; r < 8; ++r) {
        int e = r * 64 + L;
        int p = __brev((unsigned)e) >> 23;
        A0[((size_t)b * NOUT + p) * NOUT + q] = make_float2(xr[r], -xi[r]);
    }
}

// ---------------- time-chunk simulation ----------------------------------------------------------
// block = (row group g of RPB rows, batch b); wave w owns row p = RPB*g + w, p in 0..257.
// Threads 0..255 each own one sensor, summing the block's RPB rows after the step barrier.
__global__ __launch_bounds__(384, 4) void sim_kernel(
    const float* __restrict__ fil,
    const int* __restrict__ idx0, const int* __restrict__ idx1,
    float2* __restrict__ stateCur, float2* __restrict__ statePrev,
    float* __restrict__ partial, int Tc, int firstChunk, int lastChunk)
{
    __shared__ __align__(16) char waveMem[RPB * WREG];   // 31104 B
    __shared__ float2 trig[256];                         //  2048 B -> 33152 B total

    const int tid = threadIdx.x;              // 0..383
    const int w = tid >> 6, L = tid & 63;
    const int g = blockIdx.x, b = blockIdx.y;
    const int p = g * RPB + w;                // 0..257

    if (tid < 256) {
        float ang = (float)tid * (6.283185307179586f / 512.0f);
        float s, c;
        sincosf(ang, &s, &c);
        trig[tid] = make_float2(c, s);
    }
    __syncthreads();

    // --- per-lane constant twiddles ---
    v2f tA[8], tB[8];
#pragma unroll
    for (int k1 = 1; k1 < 8; ++k1) tA[k1] = wlookup(trig, L * k1);
#pragma unroll
    for (int m1 = 1; m1 < 8; ++m1) tB[m1] = wlookup(trig, 8 * (L & 7) * m1);

    // --- transpose predicates (loop-invariant; land in SGPR masks) ---
    const bool b2 = (L & 4) != 0;
    const bool b3 = (L & 8) != 0;

    // --- sensor constants: thread tid<256 owns sensor j=tid ---
    const bool active = tid < 256;
    int spos = 0;
    v2f ph[RPB];
    if (active) {
        int u = idx0[tid];
        int v = idx1[tid];
        // published regs are v>>6 in {2..5} at lane-local offsets 0,8,16,24 (parity 0)
        spos = ((v & 7) * 8 + ((v >> 3) & 7)) * 80 + ((v >> 6) * 8 - 16);
        // Hermitian fold phase: p==0 -> 1, p==256 -> (-1)^u, p==257 -> 0, else 2*W512^{pu}
#pragma unroll
        for (int ww = 0; ww < RPB; ++ww) {
            int prow = g * RPB + ww;
            v2f a0;
            if (prow == 0)        a0 = v2f{1.0f, 0.0f};
            else if (prow == 256) a0 = v2f{(u & 1) ? -1.0f : 1.0f, 0.0f};
            else if (prow == 257) a0 = v2f{0.0f, 0.0f};
            else                  a0 = 2.0f * wlookup(trig, prow * u);
            ph[ww] = a0;
        }
    } else {
#pragma unroll
        for (int ww = 0; ww < RPB; ++ww) ph[ww] = v2f{0.0f, 0.0f};
    }

    // --- per-lane LDS publish base; parity buffer offsets 0 / 32 within the pitch-80 slot ---
    char* myA    = waveMem + w * WREG;
    char* awBase = myA + L * 80;

    // --- load state + filter into registers ---
    v2f a[8], bb[8];
    float C[8];
    {
        const size_t rowBase = ((size_t)b * NOUT + p) * NOUT;
        const float* filRow = fil + (size_t)p * NOUT;
#pragma unroll
        for (int r = 0; r < 8; ++r) {
            int e = r * 64 + L;
            float2 a0 = stateCur[rowBase + e];
            a[r] = v2f{a0.x, a0.y};
            if (firstChunk) {
                bb[r] = a[r];
            } else {
                float2 a1 = statePrev[rowBase + e];
                bb[r] = v2f{a1.x, a1.y};
            }
            C[r] = fmaf(-4.0f, filRow[e], 2.0f);
        }
    }

    float* pOut = partial + ((size_t)g * Tc * NB + b) * NPHI + tid;

    for (int tl = 0; tl < Tc; tl += 2) {
        // step A (parity 0): bb becomes A_{t+1}
#pragma unroll
        for (int r = 0; r < 8; ++r) bb[r] = v2f{C[r], C[r]} * a[r] - bb[r];
        fft_sample(bb, tA, tB, b2, b3, awBase, waveMem,
                   spos, ph, active, pOut);
        pOut += NB * NPHI;
        // step B (parity 1): a becomes A_{t+2}
#pragma unroll
        for (int r = 0; r < 8; ++r) a[r] = v2f{C[r], C[r]} * bb[r] - a[r];
        fft_sample(a, tA, tB, b2, b3, awBase + 32, waveMem + 32,
                   spos, ph, active, pOut);
        pOut += NB * NPHI;
    }

    // --- save state for the next chunk (skipped when this is the last chunk) ---
    if (!lastChunk) {
        const size_t rowBase = ((size_t)b * NOUT + p) * NOUT;
#pragma unroll
        for (int r = 0; r < 8; ++r) {
            int e = r * 64 + L;
            stateCur[rowBase + e]  = make_float2(a[r].x, a[r].y);
            statePrev[rowBase + e] = make_float2(bb[r].x, bb[r].y);
        }
    }
}

// ---------------- reduce NGRP row-group partials -> out[b][j][t] ----------------------------------
__global__ __launch_bounds__(256) void reduce_kernel(const float* __restrict__ partial,
                                                     float* __restrict__ out,
                                                     int Tc, int tStart) {
    int id = blockIdx.x * 256 + threadIdx.x;   // over Tc*16*256, exact
    int j = id & 255;
    int b = (id >> 8) & 15;
    int tl = id >> 12;
    float s = 0.0f;
#pragma unroll
    for (int gg = 0; gg < NGRP; ++gg)
        s += partial[(((size_t)gg * Tc + tl) * NB + b) * NPHI + j];
    out[((size_t)b * NPHI + j) * NT + (tStart + tl)] = s * (1.0f / (512.0f * 512.0f));
}

extern "C" void kernel_launch(void* const* d_in, const int* in_sizes, int n_in,
                              void* d_out, int out_size, void* d_ws, size_t ws_size,
                              hipStream_t stream) {
    (void)in_sizes; (void)n_in; (void)out_size;
    const float* f   = (const float*)d_in[0];   // [16,1,256,256]
    const float* fil = (const float*)d_in[1];   // [512,512]
    const int* idx0  = (const int*)d_in[2];     // [256]
    const int* idx1  = (const int*)d_in[3];     // [256]
    float* out = (float*)d_out;                 // [16,1,256,240]

    char* ws = (char*)d_ws;
    const size_t stateBytes = (size_t)NB * NOUT * NOUT * sizeof(float2);  // 33.55 MB
    float2* stateCur  = (float2*)ws;
    float2* statePrev = (float2*)(ws + stateBytes);   // also reused as R scratch for f1/f2
    float*  partial   = (float*)(ws + 2 * stateBytes);
    size_t remain = (ws_size > 2 * stateBytes) ? ws_size - 2 * stateBytes : 0;

    // largest even time chunk whose partial buffer fits (even: the sim loop is 2-step unrolled)
    static const int tcs[] = {240, 120, 80, 60, 48, 40, 30, 24, 20, 16, 12, 10, 8, 6, 4, 2};
    int Tc = 2;
    for (int i = 0; i < 16; ++i) {
        size_t need = (size_t)NGRP * tcs[i] * NB * NPHI * sizeof(float);
        if (need <= remain) { Tc = tcs[i]; break; }
    }

    // no memset: f1 writes rows [128,384) of the R scratch; f2 skips the rest as known-zero
    f1_kernel<<<dim3(64, NB), 256, 0, stream>>>(f, statePrev);        // rows x in [128,384)
    f2_kernel<<<dim3(128, NB), 256, 0, stream>>>(statePrev, stateCur);
    for (int t0 = 0; t0 < NT; t0 += Tc) {
        int last = (t0 + Tc) >= NT ? 1 : 0;
        sim_kernel<<<dim3(NGRP, NB), RPB * 64, 0, stream>>>(fil, idx0, idx1, stateCur, statePrev,
                                                            partial, Tc, t0 == 0 ? 1 : 0, last);
        reduce_kernel<<<dim3(Tc * NB), 256, 0, stream>>>(partial, out, Tc, t0);
    }
}

// Round 11
// 782.724 us; speedup vs baseline: 1.4009x; 1.0019x over previous
//
#include <hip/hip_runtime.h>
#include <hip/hip_bf16.h>

// WaveOperator: Fourier-domain 3-term recurrence + per-row inverse FFT sampling.
// A_{t+1}(p,q) = (2-4*fil(p,q)) * A_t - A_{t-1};  y[b,j,t] = Re(ifft2(A_{t+1})[u_j,v_j])
// R27 = R26 with the xor4 DPP ROTATE DIRECTION FIXED. R26 failed absmax 3.98: row_ror:N makes
// dst lane i read src lane (i-N) mod 16 (AMD prefix-scan convention: row_shr:1 reads the lane
// below) -- NOT (i+N) as R26 assumed. xchg8 never exposed this (rotate-by-8 is self-inverse);
// rotate 4 vs 12 differ, so R26's a'/b' routings were swapped. Corrected:
//   a' (banks 1,3 = L&4!=0, need b[L-4]): row_ror:4  (0x124, dst i reads i-4);  4->0, 12->8 OK
//   b' (banks 0,2 = L&4==0, need a[L+4]): row_ror:12 (0x12C, dst i reads i+4);  0->4, 8->12 OK
// Bank masks unchanged (0xA / 0x5). Everything else identical to R26 (= R25 + xor4 off LDS).
// History: VGPR=64 allocator-pinned. Register-neutral VALU/LDS-stream cuts are the only
// working lever: R23 +4%, R24 +11% (VOP3P), R25 +6% (cndmask_dpp). R25 = 728us sim fallback.

#define NOUT 512
#define NB 16
#define NPHI 256
#define NT 240
#define RPB 6             // rows per block (= waves per block)
#define NGRP 43           // row groups: 43*6 = 258 = rows 0..257 (257 gets zero phase)

#define WREG 5184         // per-wave LDS publish region (pitch 80; lane uses 2x32B parity bufs)

typedef float v2f __attribute__((ext_vector_type(2)));
typedef float v4f __attribute__((ext_vector_type(4)));
typedef unsigned int v2u __attribute__((ext_vector_type(2)));

// ---- VOP3P packed-fp32 primitives (register-neutral; modifiers do the swizzles) -----------------
__device__ __forceinline__ v2f pkadd(v2f a, v2f b) {
    v2f d; asm("v_pk_add_f32 %0, %1, %2" : "=v"(d) : "v"(a), "v"(b)); return d;
}
__device__ __forceinline__ v2f pksub(v2f a, v2f b) {
    v2f d; asm("v_pk_add_f32 %0, %1, %2 neg_lo:[0,1] neg_hi:[0,1]" : "=v"(d) : "v"(a), "v"(b)); return d;
}
// a + i*w = {a.x - w.y, a.y + w.x}
__device__ __forceinline__ v2f pkaddi(v2f a, v2f w) {
    v2f d; asm("v_pk_add_f32 %0, %1, %2 op_sel:[0,1] op_sel_hi:[1,0] neg_lo:[0,1]"
               : "=v"(d) : "v"(a), "v"(w)); return d;
}
// a - i*w = {a.x + w.y, a.y - w.x}
__device__ __forceinline__ v2f pksubi(v2f a, v2f w) {
    v2f d; asm("v_pk_add_f32 %0, %1, %2 op_sel:[0,1] op_sel_hi:[1,0] neg_hi:[0,1]"
               : "=v"(d) : "v"(a), "v"(w)); return d;
}
// s * {a.x - a.y, a.x + a.y}   (w8 twiddle)
__device__ __forceinline__ v2f pkw8(v2f a) {
    v2f d; asm("v_pk_add_f32 %0, %1, %1 op_sel:[0,1] op_sel_hi:[0,1] neg_lo:[0,1]"
               : "=v"(d) : "v"(a));
    const float s = 0.70710678118654752f;
    return v2f{s * d.x, s * d.y};
}
// {-s*(a.x + a.y), s*(a.x - a.y)}   (w8^3 twiddle)
__device__ __forceinline__ v2f pkw83(v2f a) {
    v2f d; asm("v_pk_add_f32 %0, %1, %1 op_sel:[0,1] op_sel_hi:[0,1] neg_hi:[0,1]"
               : "=v"(d) : "v"(a));
    const float s = 0.70710678118654752f;
    return v2f{-s * d.x, s * d.y};
}
// complex mul g*t: {g.x*t.x - g.y*t.y, g.x*t.y + g.y*t.x} in 2 VOP3P ops
__device__ __forceinline__ v2f cmulv(v2f g, v2f t) {
    v2f p, d;
    asm("v_pk_mul_f32 %0, %1, %2 op_sel:[0,0] op_sel_hi:[0,1]" : "=v"(p) : "v"(g), "v"(t));
    // p = {g.x*t.x, g.x*t.y}
    asm("v_pk_fma_f32 %0, %1, %2, %3 op_sel:[1,1,0] op_sel_hi:[1,0,1] neg_lo:[1,0,0]"
        : "=v"(d) : "v"(g), "v"(t), "v"(p));
    // d = {-g.y*t.y + p.x, g.y*t.x + p.y}
    return d;
}

// 8-pt DFT, positive exponent: Y[k] = sum_r y[r] * exp(+2pi i rk/8)  (packed form)
__device__ __forceinline__ void dft8p(const v2f y[8], v2f Y[8]) {
    v2f t0 = pkadd(y[0], y[4]), t4 = pksub(y[0], y[4]);
    v2f t1 = pkadd(y[1], y[5]), t5 = pkw8(pksub(y[1], y[5]));
    v2f t2 = pkadd(y[2], y[6]), d26 = pksub(y[2], y[6]);   // t6 = i*d26 folded into consumers
    v2f t3 = pkadd(y[3], y[7]), t7 = pkw83(pksub(y[3], y[7]));
    v2f u0 = pkadd(t0, t2), u2 = pksub(t0, t2);
    v2f u1 = pkadd(t1, t3), w13 = pksub(t1, t3);           // u3 = i*w13 folded
    Y[0] = pkadd(u0, u1); Y[4] = pksub(u0, u1);
    Y[2] = pkaddi(u2, w13); Y[6] = pksubi(u2, w13);
    v2f v0 = pkaddi(t4, d26), v2 = pksubi(t4, d26);        // t4 +- i*d26
    v2f v1 = pkadd(t5, t7), w57 = pksub(t5, t7);           // v3 = i*w57 folded
    Y[1] = pkadd(v0, v1); Y[5] = pksub(v0, v1);
    Y[3] = pkaddi(v2, w57); Y[7] = pksubi(v2, w57);
}

// in-place variant (reads of y[] only in the t-layer; all writes after)
__device__ __forceinline__ void dft8p_ip(v2f y[8]) {
    v2f t0 = pkadd(y[0], y[4]), t4 = pksub(y[0], y[4]);
    v2f t1 = pkadd(y[1], y[5]), t5 = pkw8(pksub(y[1], y[5]));
    v2f t2 = pkadd(y[2], y[6]), d26 = pksub(y[2], y[6]);
    v2f t3 = pkadd(y[3], y[7]), t7 = pkw83(pksub(y[3], y[7]));
    v2f u0 = pkadd(t0, t2), u2 = pksub(t0, t2);
    v2f u1 = pkadd(t1, t3), w13 = pksub(t1, t3);
    y[0] = pkadd(u0, u1); y[4] = pksub(u0, u1);
    y[2] = pkaddi(u2, w13); y[6] = pksubi(u2, w13);
    v2f v0 = pkaddi(t4, d26), v2 = pksubi(t4, d26);
    v2f v1 = pkadd(t5, t7), w57 = pksub(t5, t7);
    y[1] = pkadd(v0, v1); y[5] = pksub(v0, v1);
    y[3] = pkaddi(v2, w57); y[7] = pksubi(v2, w57);
}

// final-layer DFT producing only outputs Y2,Y3,Y4,Y5 (the sensor v>>6 range)
__device__ __forceinline__ void dft8p_mid4(const v2f y[8], v2f o[4]) {
    v2f t0 = pkadd(y[0], y[4]), t4 = pksub(y[0], y[4]);
    v2f t1 = pkadd(y[1], y[5]), t5 = pkw8(pksub(y[1], y[5]));
    v2f t2 = pkadd(y[2], y[6]), d26 = pksub(y[2], y[6]);
    v2f t3 = pkadd(y[3], y[7]), t7 = pkw83(pksub(y[3], y[7]));
    v2f u0 = pkadd(t0, t2), u2 = pksub(t0, t2);
    v2f u1 = pkadd(t1, t3), w13 = pksub(t1, t3);
    v2f v0 = pkaddi(t4, d26), v2 = pksubi(t4, d26);
    v2f v1 = pkadd(t5, t7), w57 = pksub(t5, t7);
    o[0] = pkaddi(u2, w13);    // Y2
    o[1] = pkaddi(v2, w57);    // Y3
    o[2] = pksub(u0, u1);      // Y4
    o[3] = pksub(v0, v1);      // Y5
}

// W512^m from half-table
__device__ __forceinline__ v2f wlookup(const float2* trig, int m) {
    m &= 511;
    float2 ph = trig[m & 255];
    return (m & 256) ? v2f{-ph.x, -ph.y} : v2f{ph.x, ph.y};
}

// ---- in-register lane exchanges (transpose building blocks) -------------------------------------
template<int CTRL>
__device__ __forceinline__ float dppx(float x) {
    return __int_as_float(__builtin_amdgcn_mov_dpp(__float_as_int(x), CTRL, 0xF, 0xF, true));
}
__device__ __forceinline__ float swzx4(float x) {
    // BitMode swizzle: and=0x1F, or=0, xor=4  -> lane ^ 4
    return __int_as_float(__builtin_amdgcn_ds_swizzle(__float_as_int(x), 0x101F));
}

// xor1 exchange via fused v_cndmask_b32_dpp (dst = vcc ? src1 : dpp(src0)); constant lane
// masks in vcc via SALU. keepA = lanes where (L&1)==0, keepB = complement.
// Hazard: s_mov + s_nop 0 = 2 wait states before the first DPP (covers external VALU write).
__device__ __forceinline__ void xchg_x1(v2f& a, v2f& b,
                                        unsigned long long kA, unsigned long long kB) {
    v2f na, nb;
    asm("s_mov_b64 vcc, %[ka]\n\t"
        "s_nop 0\n\t"
        "v_cndmask_b32_dpp %[nax], %[bx], %[ax], vcc quad_perm:[1,0,3,2] row_mask:0xf bank_mask:0xf\n\t"
        "v_cndmask_b32_dpp %[nay], %[by], %[ay], vcc quad_perm:[1,0,3,2] row_mask:0xf bank_mask:0xf\n\t"
        "s_mov_b64 vcc, %[kb]\n\t"
        "s_nop 0\n\t"
        "v_cndmask_b32_dpp %[nbx], %[ax], %[bx], vcc quad_perm:[1,0,3,2] row_mask:0xf bank_mask:0xf\n\t"
        "v_cndmask_b32_dpp %[nby], %[ay], %[by], vcc quad_perm:[1,0,3,2] row_mask:0xf bank_mask:0xf"
        : [nax]"=&v"(na.x), [nay]"=&v"(na.y), [nbx]"=&v"(nb.x), [nby]"=&v"(nb.y)
        : [ax]"v"(a.x), [ay]"v"(a.y), [bx]"v"(b.x), [by]"v"(b.y),
          [ka]"s"(kA), [kb]"s"(kB)
        : "vcc");
    a = na; b = nb;
}
// xor2 exchange, quad_perm:[2,3,0,1]; keepA = lanes where (L&2)==0.
__device__ __forceinline__ void xchg_x2(v2f& a, v2f& b,
                                        unsigned long long kA, unsigned long long kB) {
    v2f na, nb;
    asm("s_mov_b64 vcc, %[ka]\n\t"
        "s_nop 0\n\t"
        "v_cndmask_b32_dpp %[nax], %[bx], %[ax], vcc quad_perm:[2,3,0,1] row_mask:0xf bank_mask:0xf\n\t"
        "v_cndmask_b32_dpp %[nay], %[by], %[ay], vcc quad_perm:[2,3,0,1] row_mask:0xf bank_mask:0xf\n\t"
        "s_mov_b64 vcc, %[kb]\n\t"
        "s_nop 0\n\t"
        "v_cndmask_b32_dpp %[nbx], %[ax], %[bx], vcc quad_perm:[2,3,0,1] row_mask:0xf bank_mask:0xf\n\t"
        "v_cndmask_b32_dpp %[nby], %[ay], %[by], vcc quad_perm:[2,3,0,1] row_mask:0xf bank_mask:0xf"
        : [nax]"=&v"(na.x), [nay]"=&v"(na.y), [nbx]"=&v"(nb.x), [nby]"=&v"(nb.y)
        : [ax]"v"(a.x), [ay]"v"(a.y), [bx]"v"(b.x), [by]"v"(b.y),
          [ka]"s"(kA), [kb]"s"(kB)
        : "vcc");
    a = na; b = nb;
}

#if __has_builtin(__builtin_amdgcn_update_dpp)
// xor4 exchange via masked-merge DPP (lane^4 stays within a 16-lane row).
// Convention (verified vs AMD prefix-scan idiom): row_ror:N -> dst lane i reads src (i-N)%16.
//   a' : banks 1,3 (L&4!=0) need b[L-4] -> row_ror:4  (0x124), bank_mask 0xA
//   b' : banks 0,2 (L&4==0) need a[L+4] -> row_ror:12 (0x12C), bank_mask 0x5
__device__ __forceinline__ void xchg4(v2f& a, v2f& b, bool /*bit*/) {
    int ax = __float_as_int(a.x), ay = __float_as_int(a.y);
    int bx = __float_as_int(b.x), by = __float_as_int(b.y);
    a.x = __int_as_float(__builtin_amdgcn_update_dpp(ax, bx, 0x124, 0xF, 0xA, false));
    a.y = __int_as_float(__builtin_amdgcn_update_dpp(ay, by, 0x124, 0xF, 0xA, false));
    b.x = __int_as_float(__builtin_amdgcn_update_dpp(bx, ax, 0x12C, 0xF, 0x5, false));
    b.y = __int_as_float(__builtin_amdgcn_update_dpp(by, ay, 0x12C, 0xF, 0x5, false));
}
// xor8 exchange via masked-merge DPP: row_ror:8 (self-inverse, direction-agnostic);
// bank_mask 0xC = lanes (L&8)!=0, 0x3 = rest. HW-validated since R21.
__device__ __forceinline__ void xchg8(v2f& a, v2f& b, bool /*bit*/) {
    int ax = __float_as_int(a.x), ay = __float_as_int(a.y);
    int bx = __float_as_int(b.x), by = __float_as_int(b.y);
    a.x = __int_as_float(__builtin_amdgcn_update_dpp(ax, bx, 0x128, 0xF, 0xC, false));
    a.y = __int_as_float(__builtin_amdgcn_update_dpp(ay, by, 0x128, 0xF, 0xC, false));
    b.x = __int_as_float(__builtin_amdgcn_update_dpp(bx, ax, 0x128, 0xF, 0x3, false));
    b.y = __int_as_float(__builtin_amdgcn_update_dpp(by, ay, 0x128, 0xF, 0x3, false));
}
#else
__device__ __forceinline__ void xchg4(v2f& a, v2f& b, bool bit) {
    float dbx = swzx4(b.x);
    float dby = swzx4(b.y);
    float dax = swzx4(a.x);
    float day = swzx4(a.y);
    a.x = bit ? dbx : a.x;   a.y = bit ? dby : a.y;
    b.x = bit ? b.x : dax;   b.y = bit ? b.y : day;
}
__device__ __forceinline__ void xchg8(v2f& a, v2f& b, bool bit) {
    float dbx = dppx<0x128>(b.x);
    float dby = dppx<0x128>(b.y);
    float dax = dppx<0x128>(a.x);
    float day = dppx<0x128>(a.y);
    a.x = bit ? dbx : a.x;   a.y = bit ? dby : a.y;
    b.x = bit ? b.x : dax;   b.y = bit ? b.y : day;
}
#endif

#if __has_builtin(__builtin_amdgcn_permlane16_swap)
__device__ __forceinline__ void pl16x(v2f& a, v2f& b) {
    v2u rx = __builtin_amdgcn_permlane16_swap(__float_as_uint(a.x), __float_as_uint(b.x), false, false);
    a.x = __uint_as_float(rx.x); b.x = __uint_as_float(rx.y);
    v2u ry = __builtin_amdgcn_permlane16_swap(__float_as_uint(a.y), __float_as_uint(b.y), false, false);
    a.y = __uint_as_float(ry.x); b.y = __uint_as_float(ry.y);
}
#else
__device__ __forceinline__ void pl16x(v2f& a, v2f& b) {
    bool bit = (threadIdx.x & 16) != 0;
    float sx = bit ? a.x : b.x, sy = bit ? a.y : b.y;
    float tx = __shfl_xor(sx, 16), ty = __shfl_xor(sy, 16);
    a.x = bit ? tx : a.x; a.y = bit ? ty : a.y;
    b.x = bit ? b.x : tx; b.y = bit ? b.y : ty;
}
#endif

#if __has_builtin(__builtin_amdgcn_permlane32_swap)
__device__ __forceinline__ void pl32x(v2f& a, v2f& b) {
    v2u rx = __builtin_amdgcn_permlane32_swap(__float_as_uint(a.x), __float_as_uint(b.x), false, false);
    a.x = __uint_as_float(rx.x); b.x = __uint_as_float(rx.y);
    v2u ry = __builtin_amdgcn_permlane32_swap(__float_as_uint(a.y), __float_as_uint(b.y), false, false);
    a.y = __uint_as_float(ry.x); b.y = __uint_as_float(ry.y);
}
#else
__device__ __forceinline__ void pl32x(v2f& a, v2f& b) {
    bool bit = (threadIdx.x & 32) != 0;
    float sx = bit ? a.x : b.x, sy = bit ? a.y : b.y;
    float tx = __shfl_xor(sx, 32), ty = __shfl_xor(sy, 32);
    a.x = bit ? tx : a.x; a.y = bit ? ty : a.y;
    b.x = bit ? b.x : tx; b.y = bit ? b.y : ty;
}
#endif

// hot-loop step: in-register 512-pt inverse DFT (8x8x8 four-step; transposes via
// permlane/DPP), publish G2..G5 to this step's parity buffer, ONE barrier, gather.
// awBase/ldsBase carry the parity offset (0 or 32) folded in by the caller.
__device__ __forceinline__ void fft_sample(
    const v2f y[8], const v2f tA[8], const v2f tB[8],
    bool b2, bool b3,
    char* awBase, const char* ldsBase, int spos, const v2f ph[RPB], bool active,
    float* pA)
{
    const unsigned long long K1A = 0x5555555555555555ULL;  // (L&1)==0
    const unsigned long long K1B = 0xAAAAAAAAAAAAAAAAULL;
    const unsigned long long K2A = 0x3333333333333333ULL;  // (L&2)==0
    const unsigned long long K2B = 0xCCCCCCCCCCCCCCCCULL;
    v2f G[8];
    dft8p(y, G);                                   // DFT over q2 (reg digit) -> v0
#pragma unroll
    for (int k1 = 1; k1 < 8; ++k1) G[k1] = cmulv(G[k1], tA[k1]);   // W512^{L*v0}
    // T1: reg digit (v0) <-> lane-high digit (q1)
    xchg8(G[0], G[1], b3);  xchg8(G[2], G[3], b3);                       // xor8 (merge-DPP)
    xchg8(G[4], G[5], b3);  xchg8(G[6], G[7], b3);
    pl16x(G[0], G[2]);  pl16x(G[1], G[3]);  pl16x(G[4], G[6]);  pl16x(G[5], G[7]);   // xor16
    pl32x(G[0], G[4]);  pl32x(G[1], G[5]);  pl32x(G[2], G[6]);  pl32x(G[3], G[7]);   // xor32
    dft8p_ip(G);                                   // DFT over q1 -> v1
#pragma unroll
    for (int m1 = 1; m1 < 8; ++m1) G[m1] = cmulv(G[m1], tB[m1]);   // W512^{8*q0*v1}
    // T2: reg digit (v1) <-> lane-low digit (q0)
    xchg_x1(G[0], G[1], K1A, K1B);  xchg_x1(G[2], G[3], K1A, K1B);       // cndmask_dpp xor1
    xchg_x1(G[4], G[5], K1A, K1B);  xchg_x1(G[6], G[7], K1A, K1B);
    xchg_x2(G[0], G[2], K2A, K2B);  xchg_x2(G[1], G[3], K2A, K2B);       // cndmask_dpp xor2
    xchg_x2(G[4], G[6], K2A, K2B);  xchg_x2(G[5], G[7], K2A, K2B);
    xchg4(G[0], G[4], b2);  xchg4(G[1], G[5], b2);                       // xor4 (merge-DPP)
    xchg4(G[2], G[6], b2);  xchg4(G[3], G[7], b2);
    v2f o[4];
    dft8p_mid4(G, o);                              // DFT over q0 -> v2 (only outputs 2..5)
    *(v4f*)(awBase +  0) = v4f{o[0].x, o[0].y, o[1].x, o[1].y};   // G2,G3
    *(v4f*)(awBase + 16) = v4f{o[2].x, o[2].y, o[3].x, o[3].y};   // G4,G5
    __syncthreads();   // single barrier: publish visible; orders prev gather vs buffer reuse
    if (active) {
        v2f accv = v2f{0.0f, 0.0f};
#pragma unroll
        for (int ww = 0; ww < RPB; ++ww) {
            v2f q = *(const v2f*)(ldsBase + ww * WREG + spos);
            // accv += {q.x*ph.x, -q.y*ph.y}
            asm("v_pk_fma_f32 %0, %1, %2, %0 neg_hi:[1,0,0]" : "+v"(accv) : "v"(q), "v"(ph[ww]));
        }
        pA[0] = accv.x + accv.y;
    }
}

// ---------------- init kernels (run once, shuffle FFT; cold path stays scalar) -------------------
__device__ __forceinline__ void cbfly(float& ar, float& ai, float& br, float& bi,
                                      float wr, float wi) {
    float dr = ar - br, di = ai - bi;
    ar = ar + br; ai = ai + bi;
    br = fmaf(dr, wr, -di * wi);
    bi = fmaf(dr, wi,  di * wr);
}

__device__ __forceinline__ void init_trig(float2* trig, int tid) {
    if (tid < 256) {
        float ang = (float)tid * (6.283185307179586f / 512.0f);
        float s, c;
        sincosf(ang, &s, &c);
        trig[tid] = make_float2(c, s);
    }
}

__device__ __forceinline__ void fft512_inv_lds(float* xr, float* xi, const float2* trig, int L) {
#pragma unroll
    for (int r = 0; r < 4; ++r) {
        float2 w = trig[(r << 6) + L];
        cbfly(xr[r], xi[r], xr[r + 4], xi[r + 4], w.x, w.y);
    }
    {
        float2 w0 = trig[L << 1];
        float2 w1 = trig[(64 + L) << 1];
        cbfly(xr[0], xi[0], xr[2], xi[2], w0.x, w0.y);
        cbfly(xr[1], xi[1], xr[3], xi[3], w1.x, w1.y);
        cbfly(xr[4], xi[4], xr[6], xi[6], w0.x, w0.y);
        cbfly(xr[5], xi[5], xr[7], xi[7], w1.x, w1.y);
    }
    {
        float2 w = trig[L << 2];
        cbfly(xr[0], xi[0], xr[1], xi[1], w.x, w.y);
        cbfly(xr[2], xi[2], xr[3], xi[3], w.x, w.y);
        cbfly(xr[4], xi[4], xr[5], xi[5], w.x, w.y);
        cbfly(xr[6], xi[6], xr[7], xi[7], w.x, w.y);
    }
#pragma unroll
    for (int s = 3; s <= 8; ++s) {
        const int half = 512 >> (s + 1);
        const int ex = (L & (half - 1)) << s;
        float2 w = trig[ex];
        const bool hi = (L & half) != 0;
        float wr = hi ? w.x : 1.0f;
        float wi = hi ? w.y : 0.0f;
        float sg = hi ? -1.0f : 1.0f;
#pragma unroll
        for (int r = 0; r < 8; ++r) {
            float orv = __shfl_xor(xr[r], half);
            float oiv = __shfl_xor(xi[r], half);
            float tr = fmaf(sg, xr[r], orv);
            float ti = fmaf(sg, xi[r], oiv);
            xr[r] = fmaf(tr, wr, -ti * wi);
            xi[r] = fmaf(tr, wi,  ti * wr);
        }
    }
}

__global__ __launch_bounds__(256) void f1_kernel(const float* __restrict__ f,
                                                 float2* __restrict__ R) {
    __shared__ float2 trig[256];
    const int tid = threadIdx.x;
    init_trig(trig, tid);
    __syncthreads();
    const int w = tid >> 6, L = tid & 63;
    const int x = 128 + blockIdx.x * 4 + w;   // nonzero rows only: [128, 384)
    const int b = blockIdx.y;
    const float* frow = f + ((size_t)b * 256 + (x - 128)) * 256;
    float xr[8], xi[8];
#pragma unroll
    for (int r = 0; r < 8; ++r) {
        int e = r * 64 + L;
        xr[r] = (e >= 128 && e < 384) ? frow[e - 128] : 0.0f;
        xi[r] = 0.0f;
    }
    fft512_inv_lds(xr, xi, trig, L);
    float2* Rrow = R + ((size_t)b * NOUT + x) * NOUT;
#pragma unroll
    for (int r = 0; r < 8; ++r) {
        int e = r * 64 + L;
        int k = __brev((unsigned)e) >> 23;
        Rrow[k] = make_float2(xr[r], -xi[r]);
    }
}

// f2: rows x outside [128,384) of R were never written (and are not zeroed) — treat as 0.
// e = r*64 + L is in [128,384) exactly for r in [2,6).
__global__ __launch_bounds__(256) void f2_kernel(const float2* __restrict__ R,
                                                 float2* __restrict__ A0) {
    __shared__ float2 trig[256];
    const int tid = threadIdx.x;
    init_trig(trig, tid);
    __syncthreads();
    const int w = tid >> 6, L = tid & 63;
    const int q = blockIdx.x * 4 + w;
    const int b = blockIdx.y;
    float xr[8], xi[8];
#pragma unroll
    for (int r = 0; r < 8; ++r) {
        if (r >= 2 && r < 6) {
            int e = r * 64 + L;
            float2 v = R[((size_t)b * NOUT + e) * NOUT + q];
            xr[r] = v.x;
            xi[r] = -v.y;
        } else {
            xr[r] = 0.0f;
            xi[r] = 0.0f;
        }
    }
    fft512_inv_lds(xr, xi, trig, L);
#pragma unroll
    for (int r = 0; r < 8; ++r) {
        int e = r * 64 + L;
        int p = __brev((unsigned)e) >> 23;
        A0[((size_t)b * NOUT + p) * NOUT + q] = make_float2(xr[r], -xi[r]);
    }
}

// ---------------- time-chunk simulation ----------------------------------------------------------
// block = (row group g of RPB rows, batch b); wave w owns row p = RPB*g + w, p in 0..257.
// Threads 0..255 each own one sensor, summing the block's RPB rows after the step barrier.
__global__ __launch_bounds__(384, 4) void sim_kernel(
    const float* __restrict__ fil,
    const int* __restrict__ idx0, const int* __restrict__ idx1,
    float2* __restrict__ stateCur, float2* __restrict__ statePrev,
    float* __restrict__ partial, int Tc, int firstChunk, int lastChunk)
{
    __shared__ __align__(16) char waveMem[RPB * WREG];   // 31104 B
    __shared__ float2 trig[256];                         //  2048 B -> 33152 B total

    const int tid = threadIdx.x;              // 0..383
    const int w = tid >> 6, L = tid & 63;
    const int g = blockIdx.x, b = blockIdx.y;
    const int p = g * RPB + w;                // 0..257

    if (tid < 256) {
        float ang = (float)tid * (6.283185307179586f / 512.0f);
        float s, c;
        sincosf(ang, &s, &c);
        trig[tid] = make_float2(c, s);
    }
    __syncthreads();

    // --- per-lane constant twiddles ---
    v2f tA[8], tB[8];
#pragma unroll
    for (int k1 = 1; k1 < 8; ++k1) tA[k1] = wlookup(trig, L * k1);
#pragma unroll
    for (int m1 = 1; m1 < 8; ++m1) tB[m1] = wlookup(trig, 8 * (L & 7) * m1);

    // --- transpose predicates (loop-invariant; used by fallback paths) ---
    const bool b2 = (L & 4) != 0;
    const bool b3 = (L & 8) != 0;

    // --- sensor constants: thread tid<256 owns sensor j=tid ---
    const bool active = tid < 256;
    int spos = 0;
    v2f ph[RPB];
    if (active) {
        int u = idx0[tid];
        int v = idx1[tid];
        // published regs are v>>6 in {2..5} at lane-local offsets 0,8,16,24 (parity 0)
        spos = ((v & 7) * 8 + ((v >> 3) & 7)) * 80 + ((v >> 6) * 8 - 16);
        // Hermitian fold phase: p==0 -> 1, p==256 -> (-1)^u, p==257 -> 0, else 2*W512^{pu}
#pragma unroll
        for (int ww = 0; ww < RPB; ++ww) {
            int prow = g * RPB + ww;
            v2f a0;
            if (prow == 0)        a0 = v2f{1.0f, 0.0f};
            else if (prow == 256) a0 = v2f{(u & 1) ? -1.0f : 1.0f, 0.0f};
            else if (prow == 257) a0 = v2f{0.0f, 0.0f};
            else                  a0 = 2.0f * wlookup(trig, prow * u);
            ph[ww] = a0;
        }
    } else {
#pragma unroll
        for (int ww = 0; ww < RPB; ++ww) ph[ww] = v2f{0.0f, 0.0f};
    }

    // --- per-lane LDS publish base; parity buffer offsets 0 / 32 within the pitch-80 slot ---
    char* myA    = waveMem + w * WREG;
    char* awBase = myA + L * 80;

    // --- load state + filter into registers ---
    v2f a[8], bb[8];
    float C[8];
    {
        const size_t rowBase = ((size_t)b * NOUT + p) * NOUT;
        const float* filRow = fil + (size_t)p * NOUT;
#pragma unroll
        for (int r = 0; r < 8; ++r) {
            int e = r * 64 + L;
            float2 a0 = stateCur[rowBase + e];
            a[r] = v2f{a0.x, a0.y};
            if (firstChunk) {
                bb[r] = a[r];
            } else {
                float2 a1 = statePrev[rowBase + e];
                bb[r] = v2f{a1.x, a1.y};
            }
            C[r] = fmaf(-4.0f, filRow[e], 2.0f);
        }
    }

    float* pOut = partial + ((size_t)g * Tc * NB + b) * NPHI + tid;

    for (int tl = 0; tl < Tc; tl += 2) {
        // step A (parity 0): bb becomes A_{t+1}
#pragma unroll
        for (int r = 0; r < 8; ++r) bb[r] = v2f{C[r], C[r]} * a[r] - bb[r];
        fft_sample(bb, tA, tB, b2, b3, awBase, waveMem,
                   spos, ph, active, pOut);
        pOut += NB * NPHI;
        // step B (parity 1): a becomes A_{t+2}
#pragma unroll
        for (int r = 0; r < 8; ++r) a[r] = v2f{C[r], C[r]} * bb[r] - a[r];
        fft_sample(a, tA, tB, b2, b3, awBase + 32, waveMem + 32,
                   spos, ph, active, pOut);
        pOut += NB * NPHI;
    }

    // --- save state for the next chunk (skipped when this is the last chunk) ---
    if (!lastChunk) {
        const size_t rowBase = ((size_t)b * NOUT + p) * NOUT;
#pragma unroll
        for (int r = 0; r < 8; ++r) {
            int e = r * 64 + L;
            stateCur[rowBase + e]  = make_float2(a[r].x, a[r].y);
            statePrev[rowBase + e] = make_float2(bb[r].x, bb[r].y);
        }
    }
}

// ---------------- reduce NGRP row-group partials -> out[b][j][t] ----------------------------------
__global__ __launch_bounds__(256) void reduce_kernel(const float* __restrict__ partial,
                                                     float* __restrict__ out,
                                                     int Tc, int tStart) {
    int id = blockIdx.x * 256 + threadIdx.x;   // over Tc*16*256, exact
    int j = id & 255;
    int b = (id >> 8) & 15;
    int tl = id >> 12;
    float s = 0.0f;
#pragma unroll
    for (int gg = 0; gg < NGRP; ++gg)
        s += partial[(((size_t)gg * Tc + tl) * NB + b) * NPHI + j];
    out[((size_t)b * NPHI + j) * NT + (tStart + tl)] = s * (1.0f / (512.0f * 512.0f));
}

extern "C" void kernel_launch(void* const* d_in, const int* in_sizes, int n_in,
                              void* d_out, int out_size, void* d_ws, size_t ws_size,
                              hipStream_t stream) {
    (void)in_sizes; (void)n_in; (void)out_size;
    const float* f   = (const float*)d_in[0];   // [16,1,256,256]
    const float* fil = (const float*)d_in[1];   // [512,512]
    const int* idx0  = (const int*)d_in[2];     // [256]
    const int* idx1  = (const int*)d_in[3];     // [256]
    float* out = (float*)d_out;                 // [16,1,256,240]

    char* ws = (char*)d_ws;
    const size_t stateBytes = (size_t)NB * NOUT * NOUT * sizeof(float2);  // 33.55 MB
    float2* stateCur  = (float2*)ws;
    float2* statePrev = (float2*)(ws + stateBytes);   // also reused as R scratch for f1/f2
    float*  partial   = (float*)(ws + 2 * stateBytes);
    size_t remain = (ws_size > 2 * stateBytes) ? ws_size - 2 * stateBytes : 0;

    // largest even time chunk whose partial buffer fits (even: the sim loop is 2-step unrolled)
    static const int tcs[] = {240, 120, 80, 60, 48, 40, 30, 24, 20, 16, 12, 10, 8, 6, 4, 2};
    int Tc = 2;
    for (int i = 0; i < 16; ++i) {
        size_t need = (size_t)NGRP * tcs[i] * NB * NPHI * sizeof(float);
        if (need <= remain) { Tc = tcs[i]; break; }
    }

    // no memset: f1 writes rows [128,384) of the R scratch; f2 skips the rest as known-zero
    f1_kernel<<<dim3(64, NB), 256, 0, stream>>>(f, statePrev);        // rows x in [128,384)
    f2_kernel<<<dim3(128, NB), 256, 0, stream>>>(statePrev, stateCur);
    for (int t0 = 0; t0 < NT; t0 += Tc) {
        int last = (t0 + Tc) >= NT ? 1 : 0;
        sim_kernel<<<dim3(NGRP, NB), RPB * 64, 0, stream>>>(fil, idx0, idx1, stateCur, statePrev,
                                                            partial, Tc, t0 == 0 ? 1 : 0, last);
        reduce_kernel<<<dim3(Tc * NB), 256, 0, stream>>>(partial, out, Tc, t0);
    }
}